// Round 1
// baseline (720.266 us; speedup 1.0000x reference)
//
#include <hip/hip_runtime.h>

// Problem constants
// a: (256,128,128)  b: (4,256,64,400)  E=256 NH=8 DH=32  B=400 Lq=128 Lk=64
#define PIX 16384          // 128*128
#define MS 51200           // H1*W2 samples
#define MB 25600           // H2*W2

typedef __attribute__((ext_vector_type(8))) short short8;
typedef __attribute__((ext_vector_type(4))) float floatx4;

__device__ inline ushort f2b(float x) {
  uint u = __float_as_uint(x);
  return (ushort)((u + 0x7fffu + ((u >> 16) & 1u)) >> 16);
}
__device__ inline float b2f(ushort u) {
  return __uint_as_float(((uint)u) << 16);
}

// ===================== coords: x,y, scatter idx, counts =====================
__global__ __launch_bounds__(256) void coords_kernel(
    const float* __restrict__ rots, const float* __restrict__ fxs,
    const float* __restrict__ cxs, int j,
    float* __restrict__ xarr, float* __restrict__ yarr,
    int* __restrict__ idxarr, float* __restrict__ cnt)
{
  int s = blockIdx.x * 256 + threadIdx.x;      // 0..51199, s = h*400 + w
  int h = s / 400;
  int w = s - h * 400;
  float fx = fxs[j], cx = cxs[j];
  const float* R = rots + j * 9;
  float cr = R[3];        // rots[1][0]
  float sr = -R[0];       // -rots[0][0]
  float t = (2.0f * (float)w + 1.0f - cx) / fx;      // tan(ang)
  float inv = 1.0f / sqrtf(1.0f + t * t);            // cos(ang)
  float ca = (cr + sr * t) * inv;                    // cr*cos + sr*sin
  float sa = (cr * t - sr) * inv;                    // -sr*cos + cr*sin
  float rad = ((float)h * (1.0f / 127.0f)) * 90.50966799187808f;
  float x = 64.0f + rad * ca;
  float y = 64.0f - rad * sa;
  xarr[s] = x;
  yarr[s] = y;
  int xi = (int)fminf(fmaxf(rintf(x), 0.0f), 127.0f);
  int yi = (int)fminf(fmaxf(rintf(y), 0.0f), 127.0f);
  int pix = yi * 128 + xi;
  idxarr[s] = pix;
  atomicAdd(&cnt[pix], 1.0f);
}

// ===================== prefix scan over pixel counts =====================
__global__ __launch_bounds__(256) void prefix_kernel(
    const float* __restrict__ cnt, int* __restrict__ offsets)
{
  __shared__ int sh[256];
  int t = threadIdx.x;
  int base = t * 64;
  int sum = 0;
  for (int i = 0; i < 64; ++i) sum += (int)cnt[base + i];
  sh[t] = sum;
  __syncthreads();
  for (int d = 1; d < 256; d <<= 1) {
    int v = (t >= d) ? sh[t - d] : 0;
    __syncthreads();
    sh[t] += v;
    __syncthreads();
  }
  int run = sh[t] - sum;   // exclusive prefix for this thread's chunk
  for (int i = 0; i < 64; ++i) {
    offsets[base + i] = run;
    run += (int)cnt[base + i];
  }
}

// ===================== fill sorted sample lists =====================
__global__ __launch_bounds__(256) void fill_kernel(
    const int* __restrict__ idxarr, const int* __restrict__ offsets,
    int* __restrict__ cursor, int* __restrict__ order, int* __restrict__ pixs)
{
  int s = blockIdx.x * 256 + threadIdx.x;
  int pix = idxarr[s];
  int pos = offsets[pix] + atomicAdd(&cursor[pix], 1);
  // store the attention-output row index m = w*128 + h  (s = h*400 + w)
  order[pos] = (s % 400) * 128 + (s / 400);
  pixs[pos] = pix;
}

// ===================== transpose: fp32 [256][16384] -> bf16 [16384][256] ===
__global__ __launch_bounds__(256) void transpose_kernel(
    const float* __restrict__ src, ushort* __restrict__ dst)
{
  __shared__ float tile[64][65];   // [p_local][c_local]
  int p0 = blockIdx.x * 64;
  int c0 = blockIdx.y * 64;
  int t = threadIdx.x;
  int pr = (t & 15) * 4;           // p offset
  int cr = t >> 4;                 // c row 0..15
#pragma unroll
  for (int q = 0; q < 4; ++q) {
    int c = cr + q * 16;
    float4 v = *(const float4*)(src + (size_t)(c0 + c) * PIX + p0 + pr);
    tile[pr + 0][c] = v.x;
    tile[pr + 1][c] = v.y;
    tile[pr + 2][c] = v.z;
    tile[pr + 3][c] = v.w;
  }
  __syncthreads();
  int p = t >> 2;
  int ch = (t & 3) * 16;
  ushort tmp[16];
#pragma unroll
  for (int i = 0; i < 16; ++i) tmp[i] = f2b(tile[p][ch + i]);
  ushort* d = dst + (size_t)(p0 + p) * 256 + c0 + ch;
  *(uint4*)(d) = *(uint4*)tmp;
  *(uint4*)(d + 8) = *(uint4*)(tmp + 8);
}

// ===================== bilinear sampler v2: wave=sample, lanes=channels ====
// aT[p][256] bf16 -> a_rects[s][256] bf16. Coalesced corner-row reads.
__global__ __launch_bounds__(256) void sample2_kernel(
    const ushort* __restrict__ aT, const float* __restrict__ xarr,
    const float* __restrict__ yarr, ushort* __restrict__ a_rects)
{
  int s = blockIdx.x * 4 + (threadIdx.x >> 6);
  int c0 = (threadIdx.x & 63) * 4;
  float x = fminf(fmaxf(xarr[s], 0.0f), 127.0f);
  float y = fminf(fmaxf(yarr[s], 0.0f), 127.0f);
  float x0f = floorf(x), y0f = floorf(y);
  int x0 = (int)x0f, y0 = (int)y0f;
  int x1 = min(x0 + 1, 127), y1 = min(y0 + 1, 127);
  float wx = x - x0f, wy = y - y0f;
  float w00 = (1.0f - wx) * (1.0f - wy);
  float w01 = wx * (1.0f - wy);
  float w10 = (1.0f - wx) * wy;
  float w11 = wx * wy;
  ushort4 v00 = *(const ushort4*)(aT + (size_t)(y0 * 128 + x0) * 256 + c0);
  ushort4 v01 = *(const ushort4*)(aT + (size_t)(y0 * 128 + x1) * 256 + c0);
  ushort4 v10 = *(const ushort4*)(aT + (size_t)(y1 * 128 + x0) * 256 + c0);
  ushort4 v11 = *(const ushort4*)(aT + (size_t)(y1 * 128 + x1) * 256 + c0);
  ushort4 o;
  o.x = f2b(w00 * b2f(v00.x) + w01 * b2f(v01.x) + w10 * b2f(v10.x) + w11 * b2f(v11.x));
  o.y = f2b(w00 * b2f(v00.y) + w01 * b2f(v01.y) + w10 * b2f(v10.y) + w11 * b2f(v11.y));
  o.z = f2b(w00 * b2f(v00.z) + w01 * b2f(v01.z) + w10 * b2f(v10.z) + w11 * b2f(v11.z));
  o.w = f2b(w00 * b2f(v00.w) + w01 * b2f(v01.w) + w10 * b2f(v10.w) + w11 * b2f(v11.w));
  *(ushort4*)(a_rects + (size_t)s * 256 + c0) = o;
}

// ===================== f32 -> bf16 bulk convert (float4-wide) ==============
__global__ __launch_bounds__(256) void f2b_kernel(
    const float* __restrict__ in, ushort* __restrict__ out)
{
  int t = blockIdx.x * 256 + threadIdx.x;
  float4 v = ((const float4*)in)[t];
  ushort4 o;
  o.x = f2b(v.x); o.y = f2b(v.y); o.z = f2b(v.z); o.w = f2b(v.w);
  ((ushort4*)out)[t] = o;
}

// ===================== MFMA proj (row-major feat, no LDS) ==================
// feat[s][k] bf16, Wh[f][k] bf16, bias[h][256] f32 ->
// Couth[(w*128+h)*256 + f] bf16   (s = h*400 + w)
__global__ __launch_bounds__(256) void mfma_projS_kernel(
    const ushort* __restrict__ feat, const ushort* __restrict__ Wh,
    const float* __restrict__ bias, ushort* __restrict__ Couth)
{
  int s0 = blockIdx.x * 64;
  int lane = threadIdx.x & 63;
  int wave = threadIdx.x >> 6;
  int col = lane & 15, quad = lane >> 4;
  int fw = wave * 64;
  floatx4 acc[4][4];   // [ts(s)][tf(f)]
#pragma unroll
  for (int i = 0; i < 4; ++i)
#pragma unroll
    for (int jx = 0; jx < 4; ++jx) acc[i][jx] = (floatx4){0.f, 0.f, 0.f, 0.f};

  for (int kb = 0; kb < 256; kb += 32) {
    short8 aop[4], bop[4];
#pragma unroll
    for (int tf = 0; tf < 4; ++tf)
      aop[tf] = *(const short8*)(Wh + (size_t)(fw + tf * 16 + col) * 256 + kb + quad * 8);
#pragma unroll
    for (int ts = 0; ts < 4; ++ts)
      bop[ts] = *(const short8*)(feat + (size_t)(s0 + ts * 16 + col) * 256 + kb + quad * 8);
#pragma unroll
    for (int ts = 0; ts < 4; ++ts)
#pragma unroll
      for (int tf = 0; tf < 4; ++tf)
        acc[ts][tf] = __builtin_amdgcn_mfma_f32_16x16x32_bf16(
            aop[tf], bop[ts], acc[ts][tf], 0, 0, 0);
  }
  // D: col -> s, row=quad*4+r -> f
#pragma unroll
  for (int ts = 0; ts < 4; ++ts) {
    int s = s0 + ts * 16 + col;
    int h = s / 400;
    int w = s - h * 400;
    size_t obase = (size_t)(w * 128 + h) * 256;
#pragma unroll
    for (int tf = 0; tf < 4; ++tf) {
      int f = fw + tf * 16 + quad * 4;
      float4 bv = *(const float4*)(bias + h * 256 + f);
      ushort4 ov;
      ov.x = f2b(acc[ts][tf][0] + bv.x);
      ov.y = f2b(acc[ts][tf][1] + bv.y);
      ov.z = f2b(acc[ts][tf][2] + bv.z);
      ov.w = f2b(acc[ts][tf][3] + bv.w);
      *(ushort4*)(Couth + obase + f) = ov;
    }
  }
}

// ===================== MFMA GEMM: C = A^T(K-major bf16) @ W^T(bf16) ========
// (kept for K/V projections; b features are K-major [k][m])
#define BKP 144   // LDS A row stride in halfs
#define WKP 40    // LDS W row stride in halfs
__global__ __launch_bounds__(256) void mfma_gemmT_kernel(
    const ushort* __restrict__ Ah, int Astride,
    const ushort* __restrict__ Wh, const float* __restrict__ bias,
    ushort* __restrict__ Couth, int Hdim)
{
  __shared__ ushort lA[32 * BKP];
  __shared__ ushort lW[128 * WKP];
  int m0 = blockIdx.x * 128;
  int n0 = blockIdx.y * 128;
  int tid = threadIdx.x;
  int lane = tid & 63;
  int wave = tid >> 6;
  int col = lane & 15;
  int quad = lane >> 4;
  int sw = (wave & 1) * 64;
  int fw = (wave >> 1) * 64;
  floatx4 acc[4][4];
#pragma unroll
  for (int i = 0; i < 4; ++i)
#pragma unroll
    for (int jx = 0; jx < 4; ++jx) acc[i][jx] = (floatx4){0.f, 0.f, 0.f, 0.f};

  for (int kb = 0; kb < 256; kb += 32) {
#pragma unroll
    for (int half = 0; half < 2; ++half) {
      int L = tid + half * 256;
      int r = L >> 4;
      int c = L & 15;
      uint4 v = *(const uint4*)(Ah + (size_t)(kb + r) * Astride + m0 + c * 8);
      int mp = (c * 8) ^ ((r >> 3) * 16);
      *(uint4*)&lA[r * BKP + mp] = v;
    }
#pragma unroll
    for (int half = 0; half < 2; ++half) {
      int L = tid + half * 256;
      int f = L >> 2;
      int seg = L & 3;
      uint4 v = *(const uint4*)(Wh + (size_t)(n0 + f) * 256 + kb + seg * 8);
      *(uint4*)&lW[f * WKP + seg * 8] = v;
    }
    __syncthreads();
    short8 aop[4];
#pragma unroll
    for (int tf = 0; tf < 4; ++tf) {
      int fr = fw + tf * 16 + col;
      aop[tf] = *(const short8*)&lW[fr * WKP + quad * 8];
    }
#pragma unroll
    for (int ts = 0; ts < 4; ++ts) {
      int mi = sw + ts * 16 + col;
      int mp = mi ^ (quad * 16);
      short8 bop;
#pragma unroll
      for (int jx = 0; jx < 8; ++jx)
        bop[jx] = (short)lA[(quad * 8 + jx) * BKP + mp];
#pragma unroll
      for (int tf = 0; tf < 4; ++tf)
        acc[ts][tf] = __builtin_amdgcn_mfma_f32_16x16x32_bf16(
            aop[tf], bop, acc[ts][tf], 0, 0, 0);
    }
    __syncthreads();
  }
#pragma unroll
  for (int ts = 0; ts < 4; ++ts) {
    int m = m0 + sw + ts * 16 + col;
    int h = m / 400;
    int w = m - h * 400;
    size_t obase = (size_t)(w * Hdim + h) * 256;
#pragma unroll
    for (int tf = 0; tf < 4; ++tf) {
      int f = n0 + fw + tf * 16 + quad * 4;
      float4 bv = *(const float4*)(bias + h * 256 + f);
      ushort4 ov;
      ov.x = f2b(acc[ts][tf][0] + bv.x);
      ov.y = f2b(acc[ts][tf][1] + bv.y);
      ov.z = f2b(acc[ts][tf][2] + bv.z);
      ov.w = f2b(acc[ts][tf][3] + bv.w);
      *(ushort4*)(Couth + obase + f) = ov;
    }
  }
}

// ===================== MFMA flash attention =====================
#define KP 40
#define VP 72
#define PP 72
__global__ __launch_bounds__(256) void attn_mfma_kernel(
    const ushort* __restrict__ qh, const ushort* __restrict__ kh,
    const ushort* __restrict__ vh, ushort* __restrict__ obuf)
{
  __shared__ ushort lK[4][64 * KP];
  __shared__ ushort lV[4][32 * VP];
  __shared__ ushort lP[4][16 * PP];
  int b = blockIdx.x;
  int wave = threadIdx.x >> 6;
  int lane = threadIdx.x & 63;
  int head = blockIdx.y * 4 + wave;
  int col = lane & 15, quad = lane >> 4;
  ushort* Kw = lK[wave];
  ushort* Vw = lV[wave];
  ushort* Pw = lP[wave];

  {
    const ushort* ksrc = kh + ((size_t)(b * 64 + lane)) * 256 + head * 32;
    uint4 k0 = *(const uint4*)(ksrc);
    uint4 k1 = *(const uint4*)(ksrc + 8);
    uint4 k2 = *(const uint4*)(ksrc + 16);
    uint4 k3 = *(const uint4*)(ksrc + 24);
    ushort* kd = Kw + lane * KP;
    *(uint4*)(kd) = k0; *(uint4*)(kd + 8) = k1;
    *(uint4*)(kd + 16) = k2; *(uint4*)(kd + 24) = k3;
    const ushort* vsrc = vh + ((size_t)(b * 64 + lane)) * 256 + head * 32;
    ushort vr[32];
    *(uint4*)(vr) = *(const uint4*)(vsrc);
    *(uint4*)(vr + 8) = *(const uint4*)(vsrc + 8);
    *(uint4*)(vr + 16) = *(const uint4*)(vsrc + 16);
    *(uint4*)(vr + 24) = *(const uint4*)(vsrc + 24);
#pragma unroll
    for (int d = 0; d < 32; ++d) Vw[d * VP + lane] = vr[d];
  }
  __syncthreads();

  const float scl = 0.17677669529663687f;   // 1/sqrt(32)
  for (int qt = 0; qt < 8; ++qt) {
    short8 aq = *(const short8*)(qh +
        ((size_t)(b * 128 + qt * 16 + col)) * 256 + head * 32 + quad * 8);
    floatx4 s0 = {0.f,0.f,0.f,0.f}, s1 = s0, s2 = s0, s3 = s0;
    {
      short8 b0 = *(const short8*)(Kw + (0 * 16 + col) * KP + quad * 8);
      short8 b1 = *(const short8*)(Kw + (1 * 16 + col) * KP + quad * 8);
      short8 b2 = *(const short8*)(Kw + (2 * 16 + col) * KP + quad * 8);
      short8 b3 = *(const short8*)(Kw + (3 * 16 + col) * KP + quad * 8);
      s0 = __builtin_amdgcn_mfma_f32_16x16x32_bf16(aq, b0, s0, 0, 0, 0);
      s1 = __builtin_amdgcn_mfma_f32_16x16x32_bf16(aq, b1, s1, 0, 0, 0);
      s2 = __builtin_amdgcn_mfma_f32_16x16x32_bf16(aq, b2, s2, 0, 0, 0);
      s3 = __builtin_amdgcn_mfma_f32_16x16x32_bf16(aq, b3, s3, 0, 0, 0);
    }
    float e[4][4], mr[4], sm[4];
#pragma unroll
    for (int r = 0; r < 4; ++r) {
      float v0 = s0[r] * scl, v1 = s1[r] * scl;
      float v2 = s2[r] * scl, v3 = s3[r] * scl;
      e[0][r] = v0; e[1][r] = v1; e[2][r] = v2; e[3][r] = v3;
      mr[r] = fmaxf(fmaxf(v0, v1), fmaxf(v2, v3));
    }
#pragma unroll
    for (int mask = 1; mask <= 8; mask <<= 1)
#pragma unroll
      for (int r = 0; r < 4; ++r)
        mr[r] = fmaxf(mr[r], __shfl_xor(mr[r], mask, 64));
#pragma unroll
    for (int r = 0; r < 4; ++r) {
      float acc = 0.f;
#pragma unroll
      for (int t = 0; t < 4; ++t) {
        float ev = __expf(e[t][r] - mr[r]);
        e[t][r] = ev;
        acc += ev;
      }
      sm[r] = acc;
    }
#pragma unroll
    for (int mask = 1; mask <= 8; mask <<= 1)
#pragma unroll
      for (int r = 0; r < 4; ++r)
        sm[r] += __shfl_xor(sm[r], mask, 64);
#pragma unroll
    for (int t = 0; t < 4; ++t)
#pragma unroll
      for (int r = 0; r < 4; ++r)
        Pw[(quad * 4 + r) * PP + t * 16 + col] = f2b(e[t][r]);
    __syncthreads();
    floatx4 o0 = {0.f,0.f,0.f,0.f}, o1 = o0;
#pragma unroll
    for (int c = 0; c < 2; ++c) {
      short8 ap = *(const short8*)(Pw + col * PP + c * 32 + quad * 8);
      short8 v0 = *(const short8*)(Vw + col * VP + c * 32 + quad * 8);
      short8 v1 = *(const short8*)(Vw + (16 + col) * VP + c * 32 + quad * 8);
      o0 = __builtin_amdgcn_mfma_f32_16x16x32_bf16(ap, v0, o0, 0, 0, 0);
      o1 = __builtin_amdgcn_mfma_f32_16x16x32_bf16(ap, v1, o1, 0, 0, 0);
    }
#pragma unroll
    for (int r = 0; r < 4; ++r) {
      float iv = 1.0f / sm[r];
      size_t row = (size_t)(b * 128 + qt * 16 + quad * 4 + r) * 256 + head * 32;
      obuf[row + col] = f2b(o0[r] * iv);
      obuf[row + 16 + col] = f2b(o1[r] * iv);
    }
    __syncthreads();
  }
}

// ===================== GEMM (A M-major fp32): C = A * W^T + biasf ==========
__global__ __launch_bounds__(256) void gemmN_kernel(
    const float* __restrict__ A, const float* __restrict__ Wt,
    const float* __restrict__ biasf, float* __restrict__ Cout, int mode)
{
  __shared__ float As[64][17];
  __shared__ float Ws[16][65];
  int m0 = blockIdx.x * 64;
  int n0 = blockIdx.y * 64;
  int tid = threadIdx.x;
  int tx = tid & 15, ty = tid >> 4;
  float acc[4][4] = {};
  for (int k0 = 0; k0 < 256; k0 += 16) {
    {
      int m = tid >> 2;
      int kq = (tid & 3) << 2;
      float4 v = *(const float4*)(A + (size_t)(m0 + m) * 256 + k0 + kq);
      As[m][kq + 0] = v.x; As[m][kq + 1] = v.y;
      As[m][kq + 2] = v.z; As[m][kq + 3] = v.w;
    }
    {
      int f = tid >> 2;
      int kq = (tid & 3) << 2;
      float4 v = *(const float4*)(Wt + (size_t)(n0 + f) * 256 + k0 + kq);
      Ws[kq + 0][f] = v.x; Ws[kq + 1][f] = v.y;
      Ws[kq + 2][f] = v.z; Ws[kq + 3][f] = v.w;
    }
    __syncthreads();
#pragma unroll
    for (int kk = 0; kk < 16; ++kk) {
      float a[4], b[4];
#pragma unroll
      for (int i = 0; i < 4; ++i) a[i] = As[ty * 4 + i][kk];
#pragma unroll
      for (int jj = 0; jj < 4; ++jj) b[jj] = Ws[kk][tx * 4 + jj];
#pragma unroll
      for (int i = 0; i < 4; ++i)
#pragma unroll
        for (int jj = 0; jj < 4; ++jj) acc[i][jj] += a[i] * b[jj];
    }
    __syncthreads();
  }
#pragma unroll
  for (int i = 0; i < 4; ++i) {
    int m = m0 + ty * 4 + i;
    int f = n0 + tx * 4;
    float4 ov;
    if (mode == 0) {
      float4 bv = *(const float4*)(biasf + f);
      ov.x = acc[i][0] + bv.x; ov.y = acc[i][1] + bv.y;
      ov.z = acc[i][2] + bv.z; ov.w = acc[i][3] + bv.w;
    } else {
      ov.x = acc[i][0]; ov.y = acc[i][1];
      ov.z = acc[i][2]; ov.w = acc[i][3];
    }
    *(float4*)(Cout + (size_t)m * 256 + f) = ov;
  }
}

// ===================== GEMM A[m][k] * B[k][n] (effective weights) ==========
__global__ __launch_bounds__(256) void gemm_ab_kernel(
    const float* __restrict__ in_w, const float* __restrict__ Wq,
    const float* __restrict__ Wk, const float* __restrict__ Wv,
    float* __restrict__ weff)
{
  int z = blockIdx.z;
  const float* A = in_w + (size_t)z * 65536;
  const float* B = (z == 0) ? Wq : ((z == 1) ? Wk : Wv);
  float* C = weff + (size_t)z * 65536;
  __shared__ float As[64][17];
  __shared__ float Bs[16][64];
  int m0 = blockIdx.x * 64;
  int n0 = blockIdx.y * 64;
  int tid = threadIdx.x;
  int tx = tid & 15, ty = tid >> 4;
  float acc[4][4] = {};
  for (int k0 = 0; k0 < 256; k0 += 16) {
    {
      int m = tid >> 2;
      int kq = (tid & 3) << 2;
      float4 v = *(const float4*)(A + (size_t)(m0 + m) * 256 + k0 + kq);
      As[m][kq + 0] = v.x; As[m][kq + 1] = v.y;
      As[m][kq + 2] = v.z; As[m][kq + 3] = v.w;
    }
    {
      int k = tid >> 4;
      int nq = (tid & 15) << 2;
      float4 v = *(const float4*)(B + (size_t)(k0 + k) * 256 + n0 + nq);
      *(float4*)(&Bs[k][nq]) = v;
    }
    __syncthreads();
#pragma unroll
    for (int kk = 0; kk < 16; ++kk) {
      float a[4], b[4];
#pragma unroll
      for (int i = 0; i < 4; ++i) a[i] = As[ty * 4 + i][kk];
#pragma unroll
      for (int jj = 0; jj < 4; ++jj) b[jj] = Bs[kk][tx * 4 + jj];
#pragma unroll
      for (int i = 0; i < 4; ++i)
#pragma unroll
        for (int jj = 0; jj < 4; ++jj) acc[i][jj] += a[i] * b[jj];
    }
    __syncthreads();
  }
#pragma unroll
  for (int i = 0; i < 4; ++i) {
    int m = m0 + ty * 4 + i;
    *(float4*)(C + (size_t)m * 256 + n0 + tx * 4) = *(float4*)&acc[i][0];
  }
}

// ===================== effective biases =====================
__global__ void beff_kernel(const float* __restrict__ in_w, const float* __restrict__ in_b,
                            const float* __restrict__ bq, const float* __restrict__ bk,
                            const float* __restrict__ bv, float* __restrict__ beff)
{
  int z = blockIdx.x;
  int f = threadIdx.x;
  const float* bsrc = (z == 0) ? bq : ((z == 1) ? bk : bv);
  const float* row = in_w + (size_t)(z * 256 + f) * 256;
  float acc = in_b[z * 256 + f];
  for (int e = 0; e < 256; ++e) acc += row[e] * bsrc[e];
  beff[z * 256 + f] = acc;
}

// ===================== segmented reduction over sorted samples =============
#define CH 64
__global__ __launch_bounds__(256) void segred_kernel(
    const ushort* __restrict__ obuf, const int* __restrict__ order,
    const int* __restrict__ pixs, float* __restrict__ osum)
{
  __shared__ int lm[CH];
  __shared__ int lp[CH + 2];
  int s0 = blockIdx.x * CH;
  int t = threadIdx.x;
  if (t < CH) {
    lm[t] = order[s0 + t];
    lp[t + 1] = pixs[s0 + t];
  } else if (t == CH) {
    lp[0] = (s0 > 0) ? pixs[s0 - 1] : -1;
  } else if (t == CH + 1) {
    lp[CH + 1] = (s0 + CH < MS) ? pixs[s0 + CH] : -2;
  }
  __syncthreads();
  int c = t;
  float va[8];
#pragma unroll
  for (int k = 0; k < 8; ++k)
    va[k] = b2f(obuf[(size_t)lm[k] * 256 + c]);
  float acc = 0.0f;
  int runBegin = 0;
#pragma unroll
  for (int i = 0; i < CH; ++i) {
    float v = va[i & 7];
    if (i + 8 < CH) va[i & 7] = b2f(obuf[(size_t)lm[i + 8] * 256 + c]);
    acc += v;
    int p = lp[i + 1];
    bool last = (i == CH - 1);
    if (last || p != lp[i + 2]) {
      bool pBeg = (runBegin == 0) && (p == lp[0]);
      bool pEnd = last && (p == lp[CH + 1]);
      float* dst = osum + (size_t)p * 256 + c;
      if (pBeg || pEnd) atomicAdd(dst, acc);
      else *dst = acc;
      acc = 0.0f;
      runBegin = i + 1;
    }
  }
}

// ===================== MFMA out-proj: enhT = out_w @ osum^T ================
__global__ __launch_bounds__(256) void mfma_outproj_kernel(
    const float* __restrict__ osum, const ushort* __restrict__ out_wh,
    float* __restrict__ enhT)
{
  int p0 = blockIdx.x * 64;
  int lane = threadIdx.x & 63;
  int wave = threadIdx.x >> 6;
  int col = lane & 15, quad = lane >> 4;
  int fw = wave * 64;
  floatx4 acc[4][4];
#pragma unroll
  for (int i = 0; i < 4; ++i)
#pragma unroll
    for (int jx = 0; jx < 4; ++jx) acc[i][jx] = (floatx4){0.f, 0.f, 0.f, 0.f};

  for (int kb = 0; kb < 256; kb += 32) {
    short8 aop[4], bop[4];
#pragma unroll
    for (int tf = 0; tf < 4; ++tf)
      aop[tf] = *(const short8*)(out_wh +
          (size_t)(fw + tf * 16 + col) * 256 + kb + quad * 8);
#pragma unroll
    for (int ts = 0; ts < 4; ++ts) {
      const float* brow = osum + (size_t)(p0 + ts * 16 + col) * 256 + kb + quad * 8;
      float4 f0 = *(const float4*)brow;
      float4 f1 = *(const float4*)(brow + 4);
      short8 bv;
      bv[0] = (short)f2b(f0.x); bv[1] = (short)f2b(f0.y);
      bv[2] = (short)f2b(f0.z); bv[3] = (short)f2b(f0.w);
      bv[4] = (short)f2b(f1.x); bv[5] = (short)f2b(f1.y);
      bv[6] = (short)f2b(f1.z); bv[7] = (short)f2b(f1.w);
      bop[ts] = bv;
    }
#pragma unroll
    for (int ts = 0; ts < 4; ++ts)
#pragma unroll
      for (int tf = 0; tf < 4; ++tf)
        acc[ts][tf] = __builtin_amdgcn_mfma_f32_16x16x32_bf16(
            aop[tf], bop[ts], acc[ts][tf], 0, 0, 0);
  }
#pragma unroll
  for (int ts = 0; ts < 4; ++ts) {
    int p = p0 + ts * 16 + col;
#pragma unroll
    for (int tf = 0; tf < 4; ++tf) {
      int f = fw + tf * 16 + quad * 4;
#pragma unroll
      for (int r = 0; r < 4; ++r)
        enhT[(size_t)(f + r) * PIX + p] = acc[ts][tf][r];
    }
  }
}

// ===================== residual update / final (elementwise, [c][p]) =======
__global__ __launch_bounds__(256) void update_kernel(
    const float* __restrict__ asrc, float* __restrict__ adst,
    const float* __restrict__ enhT, const float* __restrict__ cnt,
    const float* __restrict__ out_b, float scale)
{
  int t = blockIdx.x * 256 + threadIdx.x;
  int base = t * 4;
  int c = base >> 14;
  int p = base & (PIX - 1);
  float ob = out_b[c];
  float4 e = ((const float4*)enhT)[t];
  float4 cn = *(const float4*)(cnt + p);
  float4 a = ((const float4*)asrc)[t];
  float4 o;
  o.x = a.x + scale * (e.x + cn.x * ob) / fmaxf(cn.x, 1.0f);
  o.y = a.y + scale * (e.y + cn.y * ob) / fmaxf(cn.y, 1.0f);
  o.z = a.z + scale * (e.z + cn.z * ob) / fmaxf(cn.z, 1.0f);
  o.w = a.w + scale * (e.w + cn.w * ob) / fmaxf(cn.w, 1.0f);
  ((float4*)adst)[t] = o;
}

// ===================== launch =====================
extern "C" void kernel_launch(void* const* d_in, const int* in_sizes, int n_in,
                              void* d_out, int out_size, void* d_ws, size_t ws_size,
                              hipStream_t stream) {
  const float* list_a = (const float*)d_in[0];
  const float* list_b = (const float*)d_in[1];
  const float* rots   = (const float*)d_in[3];
  const float* fxs    = (const float*)d_in[5];
  const float* cxs    = (const float*)d_in[6];
  const float* pos_a  = (const float*)d_in[7];
  const float* pos_b  = (const float*)d_in[8];
  const float* Wq     = (const float*)d_in[9];
  const float* bq     = (const float*)d_in[10];
  const float* Wk     = (const float*)d_in[11];
  const float* bk     = (const float*)d_in[12];
  const float* Wv     = (const float*)d_in[13];
  const float* bv     = (const float*)d_in[14];
  const float* in_w   = (const float*)d_in[15];
  const float* in_b   = (const float*)d_in[16];
  const float* out_w  = (const float*)d_in[17];
  const float* out_b  = (const float*)d_in[18];

  float* ws      = (float*)d_ws;
  float* weff    = ws;                          // 196608 f
  float* beff    = weff + 196608;               // 768 f
  float* qpos    = beff + 768;                  // 32768 f
  float* kpos    = qpos + 32768;                // 16384 f
  float* vpos    = kpos + 16384;                // 16384 f
  float* a_cur   = vpos + 16384;                // 4194304 f
  float* xarr    = a_cur + 4194304;             // 51200 f
  float* yarr    = xarr + 51200;                // 51200 f
  int*   idxarr  = (int*)(yarr + 51200);        // 51200
  float* cnt     = (float*)(idxarr + 51200);    // 16384 f
  int*   cursor  = (int*)(cnt + 16384);         // 16384
  int*   offs    = cursor + 16384;              // 16384
  int*   order   = offs + 16384;                // 51200
  int*   pixs    = order + 51200;               // 51200
  float* osum    = (float*)(pixs + 51200);      // 4194304 f
  ushort* weffh  = (ushort*)(osum + 4194304);   // 196608 h
  ushort* out_wh = weffh + 196608;              // 65536 h
  ushort* a_rects = out_wh + 65536;             // 13107200 h (obuf alias)
  ushort* bh     = a_rects + 13107200;          // 6553600 h
  ushort* qh     = bh + 6553600;                // 13107200 h
  ushort* kh     = qh + 13107200;               // 6553600 h (enhT alias ->)
  ushort* vh     = kh + 6553600;                // 6553600 h
  ushort* aT     = vh + 6553600;                // 4194304 h
  ushort* obufh  = a_rects;                     // alias: a_rects dead after Q-proj
  float* enhT    = (float*)kh;                  // alias: kh+vh dead after attn

  // effective weights + biases (tiny)
  gemm_ab_kernel<<<dim3(4, 4, 3), 256, 0, stream>>>(in_w, Wq, Wk, Wv, weff);
  beff_kernel<<<3, 256, 0, stream>>>(in_w, in_b, bq, bk, bv, beff);
  f2b_kernel<<<192, 256, 0, stream>>>(weff, weffh);
  f2b_kernel<<<64, 256, 0, stream>>>(out_w, out_wh);

  // positional bias tables: pos @ Weff^T + beff
  gemmN_kernel<<<dim3(2, 4), 256, 0, stream>>>(pos_a, weff, beff, qpos, 0);
  gemmN_kernel<<<dim3(1, 4), 256, 0, stream>>>(pos_b, weff + 65536, beff + 256, kpos, 0);
  gemmN_kernel<<<dim3(1, 4), 256, 0, stream>>>(pos_b, weff + 131072, beff + 512, vpos, 0);

  for (int jj = 0; jj < 2; ++jj) {
    int j = jj ? 3 : 0;
    const float* asrc = jj ? a_cur : list_a;
    hipMemsetAsync(cnt, 0, (size_t)2 * 16384 * sizeof(float), stream);  // cnt + cursor
    hipMemsetAsync(osum, 0, (size_t)4194304 * sizeof(float), stream);
    coords_kernel<<<200, 256, 0, stream>>>(rots, fxs, cxs, j, xarr, yarr, idxarr, cnt);
    prefix_kernel<<<1, 256, 0, stream>>>(cnt, offs);
    fill_kernel<<<200, 256, 0, stream>>>(idxarr, offs, cursor, order, pixs);
    // image -> pixel-major bf16, then wave-per-sample bilinear
    transpose_kernel<<<dim3(256, 4), 256, 0, stream>>>(asrc, aT);
    sample2_kernel<<<12800, 256, 0, stream>>>(aT, xarr, yarr, a_rects);
    const float* bsrc = list_b + (size_t)j * 6553600;
    f2b_kernel<<<6400, 256, 0, stream>>>(bsrc, bh);
    // Q projection: direct row-major MFMA (no LDS)
    mfma_projS_kernel<<<800, 256, 0, stream>>>(a_rects, weffh, qpos, qh);
    // K/V projections from K-major b
    mfma_gemmT_kernel<<<dim3(200, 2), 256, 0, stream>>>(bh, MB, weffh + 65536, kpos, kh, 64);
    mfma_gemmT_kernel<<<dim3(200, 2), 256, 0, stream>>>(bh, MB, weffh + 131072, vpos, vh, 64);
    // MFMA flash attention (O bf16 into obufh = a_rects region)
    attn_mfma_kernel<<<dim3(400, 2), 256, 0, stream>>>(qh, kh, vh, obufh);
    // segmented reduction of O over sorted samples -> osum fp32
    segred_kernel<<<800, 256, 0, stream>>>(obufh, order, pixs, osum);
    // MFMA out-proj directly into transposed layout [c][p]
    mfma_outproj_kernel<<<256, 256, 0, stream>>>(osum, out_wh, enhT);
    update_kernel<<<4096, 256, 0, stream>>>(asrc, jj ? (float*)d_out : a_cur,
                                            enhT, cnt, out_b, jj ? 2.0f : 1.0f);
  }
}

// Round 2
// 697.439 us; speedup vs baseline: 1.0327x; 1.0327x over previous
//
#include <hip/hip_runtime.h>

// Problem constants
// a: (256,128,128)  b: (4,256,64,400)  E=256 NH=8 DH=32  B=400 Lq=128 Lk=64
#define PIX 16384          // 128*128
#define MS 51200           // H1*W2 samples
#define MB 25600           // H2*W2

typedef __attribute__((ext_vector_type(8))) short short8;
typedef __attribute__((ext_vector_type(4))) float floatx4;

__device__ inline ushort f2b(float x) {
  uint u = __float_as_uint(x);
  return (ushort)((u + 0x7fffu + ((u >> 16) & 1u)) >> 16);
}
__device__ inline float b2f(ushort u) {
  return __uint_as_float(((uint)u) << 16);
}

// ===================== coords: x,y, scatter idx, counts =====================
__global__ __launch_bounds__(256) void coords_kernel(
    const float* __restrict__ rots, const float* __restrict__ fxs,
    const float* __restrict__ cxs, int j,
    float* __restrict__ xarr, float* __restrict__ yarr,
    int* __restrict__ idxarr, float* __restrict__ cnt)
{
  int s = blockIdx.x * 256 + threadIdx.x;      // 0..51199, s = h*400 + w
  int h = s / 400;
  int w = s - h * 400;
  float fx = fxs[j], cx = cxs[j];
  const float* R = rots + j * 9;
  float cr = R[3];        // rots[1][0]
  float sr = -R[0];       // -rots[0][0]
  float t = (2.0f * (float)w + 1.0f - cx) / fx;      // tan(ang)
  float inv = 1.0f / sqrtf(1.0f + t * t);            // cos(ang)
  float ca = (cr + sr * t) * inv;                    // cr*cos + sr*sin
  float sa = (cr * t - sr) * inv;                    // -sr*cos + cr*sin
  float rad = ((float)h * (1.0f / 127.0f)) * 90.50966799187808f;
  float x = 64.0f + rad * ca;
  float y = 64.0f - rad * sa;
  xarr[s] = x;
  yarr[s] = y;
  int xi = (int)fminf(fmaxf(rintf(x), 0.0f), 127.0f);
  int yi = (int)fminf(fmaxf(rintf(y), 0.0f), 127.0f);
  int pix = yi * 128 + xi;
  idxarr[s] = pix;
  atomicAdd(&cnt[pix], 1.0f);
}

// ===================== prefix scan over pixel counts (vectorized) ==========
__global__ __launch_bounds__(256) void prefix_kernel(
    const float* __restrict__ cnt, int* __restrict__ offsets)
{
  __shared__ int sh[256];
  int t = threadIdx.x;
  int base = t * 64;
  const float4* cp = (const float4*)(cnt + base);
  int sum = 0;
#pragma unroll
  for (int i = 0; i < 16; ++i) {
    float4 v = cp[i];
    sum += (int)v.x + (int)v.y + (int)v.z + (int)v.w;
  }
  sh[t] = sum;
  __syncthreads();
  for (int d = 1; d < 256; d <<= 1) {
    int v = (t >= d) ? sh[t - d] : 0;
    __syncthreads();
    sh[t] += v;
    __syncthreads();
  }
  int run = sh[t] - sum;   // exclusive prefix for this thread's chunk
  int4* op = (int4*)(offsets + base);
#pragma unroll
  for (int i = 0; i < 16; ++i) {
    float4 v = cp[i];
    int a0 = (int)v.x, a1 = (int)v.y, a2 = (int)v.z, a3 = (int)v.w;
    int4 o;
    o.x = run; o.y = run + a0; o.z = run + a0 + a1; o.w = run + a0 + a1 + a2;
    op[i] = o;
    run += a0 + a1 + a2 + a3;
  }
}

// ===================== fill sorted sample lists =====================
__global__ __launch_bounds__(256) void fill_kernel(
    const int* __restrict__ idxarr, const int* __restrict__ offsets,
    int* __restrict__ cursor, int* __restrict__ order, int* __restrict__ pixs)
{
  int s = blockIdx.x * 256 + threadIdx.x;
  int pix = idxarr[s];
  int pos = offsets[pix] + atomicAdd(&cursor[pix], 1);
  // store the attention-output row index m = w*128 + h  (s = h*400 + w)
  order[pos] = (s % 400) * 128 + (s / 400);
  pixs[pos] = pix;
}

// ===================== transpose: fp32 [256][W] -> bf16 [W][256] ===========
// W = 16384 (a image) or 25600 (b features)
__global__ __launch_bounds__(256) void transpose_kernel(
    const float* __restrict__ src, ushort* __restrict__ dst, int W)
{
  __shared__ float tile[64][65];   // [p_local][c_local]
  int p0 = blockIdx.x * 64;
  int c0 = blockIdx.y * 64;
  int t = threadIdx.x;
  int pr = (t & 15) * 4;           // p offset
  int cr = t >> 4;                 // c row 0..15
#pragma unroll
  for (int q = 0; q < 4; ++q) {
    int c = cr + q * 16;
    float4 v = *(const float4*)(src + (size_t)(c0 + c) * W + p0 + pr);
    tile[pr + 0][c] = v.x;
    tile[pr + 1][c] = v.y;
    tile[pr + 2][c] = v.z;
    tile[pr + 3][c] = v.w;
  }
  __syncthreads();
  int p = t >> 2;
  int ch = (t & 3) * 16;
  ushort tmp[16];
#pragma unroll
  for (int i = 0; i < 16; ++i) tmp[i] = f2b(tile[p][ch + i]);
  ushort* d = dst + (size_t)(p0 + p) * 256 + c0 + ch;
  *(uint4*)(d) = *(uint4*)tmp;
  *(uint4*)(d + 8) = *(uint4*)(tmp + 8);
}

// ===================== f32 -> bf16 bulk convert (float4-wide) ==============
__global__ __launch_bounds__(256) void f2b_kernel(
    const float* __restrict__ in, ushort* __restrict__ out)
{
  int t = blockIdx.x * 256 + threadIdx.x;
  float4 v = ((const float4*)in)[t];
  ushort4 o;
  o.x = f2b(v.x); o.y = f2b(v.y); o.z = f2b(v.z); o.w = f2b(v.w);
  ((ushort4*)out)[t] = o;
}

// ===================== fused bilinear sample + Q projection ================
// aT[p][256] bf16 -> (LDS feat tile) -> qh[(w*128+h)*256+f] bf16
#define LFP 264   // LDS feat row stride in halfs (528B: 16B-aligned, 2-way banks)
__global__ __launch_bounds__(256) void sampleproj_kernel(
    const ushort* __restrict__ aT, const float* __restrict__ xarr,
    const float* __restrict__ yarr, const ushort* __restrict__ Wh,
    const float* __restrict__ bias, ushort* __restrict__ qh)
{
  __shared__ ushort lf[64 * LFP];
  int s0 = blockIdx.x * 64;
  int tid = threadIdx.x;
  int lane = tid & 63;
  int wave = tid >> 6;
  int col = lane & 15, quad = lane >> 4;
  int c0 = lane * 4;

  // gather phase: each wave computes 16 samples (all 256 channels)
#pragma unroll 4
  for (int i = 0; i < 16; ++i) {
    int sl = wave * 16 + i;
    int s = s0 + sl;
    float x = fminf(fmaxf(xarr[s], 0.0f), 127.0f);
    float y = fminf(fmaxf(yarr[s], 0.0f), 127.0f);
    float x0f = floorf(x), y0f = floorf(y);
    int x0 = (int)x0f, y0 = (int)y0f;
    int x1 = min(x0 + 1, 127), y1 = min(y0 + 1, 127);
    float wx = x - x0f, wy = y - y0f;
    float w00 = (1.0f - wx) * (1.0f - wy);
    float w01 = wx * (1.0f - wy);
    float w10 = (1.0f - wx) * wy;
    float w11 = wx * wy;
    ushort4 v00 = *(const ushort4*)(aT + (size_t)(y0 * 128 + x0) * 256 + c0);
    ushort4 v01 = *(const ushort4*)(aT + (size_t)(y0 * 128 + x1) * 256 + c0);
    ushort4 v10 = *(const ushort4*)(aT + (size_t)(y1 * 128 + x0) * 256 + c0);
    ushort4 v11 = *(const ushort4*)(aT + (size_t)(y1 * 128 + x1) * 256 + c0);
    ushort4 o;
    o.x = f2b(w00 * b2f(v00.x) + w01 * b2f(v01.x) + w10 * b2f(v10.x) + w11 * b2f(v11.x));
    o.y = f2b(w00 * b2f(v00.y) + w01 * b2f(v01.y) + w10 * b2f(v10.y) + w11 * b2f(v11.y));
    o.z = f2b(w00 * b2f(v00.z) + w01 * b2f(v01.z) + w10 * b2f(v10.z) + w11 * b2f(v11.z));
    o.w = f2b(w00 * b2f(v00.w) + w01 * b2f(v01.w) + w10 * b2f(v10.w) + w11 * b2f(v11.w));
    *(ushort4*)&lf[sl * LFP + c0] = o;
  }
  __syncthreads();

  // projection phase: identical to projS but B-operand from LDS
  int fw = wave * 64;
  floatx4 acc[4][4];
#pragma unroll
  for (int i = 0; i < 4; ++i)
#pragma unroll
    for (int jx = 0; jx < 4; ++jx) acc[i][jx] = (floatx4){0.f, 0.f, 0.f, 0.f};

  for (int kb = 0; kb < 256; kb += 32) {
    short8 aop[4], bop[4];
#pragma unroll
    for (int tf = 0; tf < 4; ++tf)
      aop[tf] = *(const short8*)(Wh + (size_t)(fw + tf * 16 + col) * 256 + kb + quad * 8);
#pragma unroll
    for (int ts = 0; ts < 4; ++ts)
      bop[ts] = *(const short8*)&lf[(ts * 16 + col) * LFP + kb + quad * 8];
#pragma unroll
    for (int ts = 0; ts < 4; ++ts)
#pragma unroll
      for (int tf = 0; tf < 4; ++tf)
        acc[ts][tf] = __builtin_amdgcn_mfma_f32_16x16x32_bf16(
            aop[tf], bop[ts], acc[ts][tf], 0, 0, 0);
  }
  // D: col -> s, row=quad*4+r -> f
#pragma unroll
  for (int ts = 0; ts < 4; ++ts) {
    int s = s0 + ts * 16 + col;
    int h = s / 400;
    int w = s - h * 400;
    size_t obase = (size_t)(w * 128 + h) * 256;
#pragma unroll
    for (int tf = 0; tf < 4; ++tf) {
      int f = fw + tf * 16 + quad * 4;
      float4 bv = *(const float4*)(bias + h * 256 + f);
      ushort4 ov;
      ov.x = f2b(acc[ts][tf][0] + bv.x);
      ov.y = f2b(acc[ts][tf][1] + bv.y);
      ov.z = f2b(acc[ts][tf][2] + bv.z);
      ov.w = f2b(acc[ts][tf][3] + bv.w);
      *(ushort4*)(qh + obase + f) = ov;
    }
  }
}

// ===================== fused K+V projection (m-major bf16 feat, no LDS) ====
// featB[m][256] bf16 (m = h2*400 + w2), outputs kh/vh[(w2*64+h2)*256+f]
__global__ __launch_bounds__(256) void projKV_kernel(
    const ushort* __restrict__ featB,
    const ushort* __restrict__ WhK, const ushort* __restrict__ WhV,
    const float* __restrict__ biasK, const float* __restrict__ biasV,
    ushort* __restrict__ kh, ushort* __restrict__ vh)
{
  int m0 = blockIdx.x * 64;
  int lane = threadIdx.x & 63;
  int wave = threadIdx.x >> 6;
  int col = lane & 15, quad = lane >> 4;
  int fw = wave * 64;

  for (int z = 0; z < 2; ++z) {
    const ushort* Wh = z ? WhV : WhK;
    const float* bias = z ? biasV : biasK;
    ushort* out = z ? vh : kh;
    floatx4 acc[4][4];
#pragma unroll
    for (int i = 0; i < 4; ++i)
#pragma unroll
      for (int jx = 0; jx < 4; ++jx) acc[i][jx] = (floatx4){0.f, 0.f, 0.f, 0.f};

    for (int kb = 0; kb < 256; kb += 32) {
      short8 aop[4], bop[4];
#pragma unroll
      for (int tf = 0; tf < 4; ++tf)
        aop[tf] = *(const short8*)(Wh + (size_t)(fw + tf * 16 + col) * 256 + kb + quad * 8);
#pragma unroll
      for (int ts = 0; ts < 4; ++ts)
        bop[ts] = *(const short8*)(featB + (size_t)(m0 + ts * 16 + col) * 256 + kb + quad * 8);
#pragma unroll
      for (int ts = 0; ts < 4; ++ts)
#pragma unroll
        for (int tf = 0; tf < 4; ++tf)
          acc[ts][tf] = __builtin_amdgcn_mfma_f32_16x16x32_bf16(
              aop[tf], bop[ts], acc[ts][tf], 0, 0, 0);
    }
#pragma unroll
    for (int ts = 0; ts < 4; ++ts) {
      int m = m0 + ts * 16 + col;
      int h = m / 400;            // h2
      int w = m - h * 400;        // w2
      size_t obase = (size_t)(w * 64 + h) * 256;
#pragma unroll
      for (int tf = 0; tf < 4; ++tf) {
        int f = fw + tf * 16 + quad * 4;
        float4 bv = *(const float4*)(bias + h * 256 + f);
        ushort4 ov;
        ov.x = f2b(acc[ts][tf][0] + bv.x);
        ov.y = f2b(acc[ts][tf][1] + bv.y);
        ov.z = f2b(acc[ts][tf][2] + bv.z);
        ov.w = f2b(acc[ts][tf][3] + bv.w);
        *(ushort4*)(out + obase + f) = ov;
      }
    }
  }
}

// ===================== MFMA flash attention =====================
#define KP 40
#define VP 72
#define PP 72
__global__ __launch_bounds__(256) void attn_mfma_kernel(
    const ushort* __restrict__ qh, const ushort* __restrict__ kh,
    const ushort* __restrict__ vh, ushort* __restrict__ obuf)
{
  __shared__ ushort lK[4][64 * KP];
  __shared__ ushort lV[4][32 * VP];
  __shared__ ushort lP[4][16 * PP];
  int b = blockIdx.x;
  int wave = threadIdx.x >> 6;
  int lane = threadIdx.x & 63;
  int head = blockIdx.y * 4 + wave;
  int col = lane & 15, quad = lane >> 4;
  ushort* Kw = lK[wave];
  ushort* Vw = lV[wave];
  ushort* Pw = lP[wave];

  {
    const ushort* ksrc = kh + ((size_t)(b * 64 + lane)) * 256 + head * 32;
    uint4 k0 = *(const uint4*)(ksrc);
    uint4 k1 = *(const uint4*)(ksrc + 8);
    uint4 k2 = *(const uint4*)(ksrc + 16);
    uint4 k3 = *(const uint4*)(ksrc + 24);
    ushort* kd = Kw + lane * KP;
    *(uint4*)(kd) = k0; *(uint4*)(kd + 8) = k1;
    *(uint4*)(kd + 16) = k2; *(uint4*)(kd + 24) = k3;
    const ushort* vsrc = vh + ((size_t)(b * 64 + lane)) * 256 + head * 32;
    ushort vr[32];
    *(uint4*)(vr) = *(const uint4*)(vsrc);
    *(uint4*)(vr + 8) = *(const uint4*)(vsrc + 8);
    *(uint4*)(vr + 16) = *(const uint4*)(vsrc + 16);
    *(uint4*)(vr + 24) = *(const uint4*)(vsrc + 24);
#pragma unroll
    for (int d = 0; d < 32; ++d) Vw[d * VP + lane] = vr[d];
  }
  __syncthreads();

  const float scl = 0.17677669529663687f;   // 1/sqrt(32)
  for (int qt = 0; qt < 8; ++qt) {
    short8 aq = *(const short8*)(qh +
        ((size_t)(b * 128 + qt * 16 + col)) * 256 + head * 32 + quad * 8);
    floatx4 s0 = {0.f,0.f,0.f,0.f}, s1 = s0, s2 = s0, s3 = s0;
    {
      short8 b0 = *(const short8*)(Kw + (0 * 16 + col) * KP + quad * 8);
      short8 b1 = *(const short8*)(Kw + (1 * 16 + col) * KP + quad * 8);
      short8 b2 = *(const short8*)(Kw + (2 * 16 + col) * KP + quad * 8);
      short8 b3 = *(const short8*)(Kw + (3 * 16 + col) * KP + quad * 8);
      s0 = __builtin_amdgcn_mfma_f32_16x16x32_bf16(aq, b0, s0, 0, 0, 0);
      s1 = __builtin_amdgcn_mfma_f32_16x16x32_bf16(aq, b1, s1, 0, 0, 0);
      s2 = __builtin_amdgcn_mfma_f32_16x16x32_bf16(aq, b2, s2, 0, 0, 0);
      s3 = __builtin_amdgcn_mfma_f32_16x16x32_bf16(aq, b3, s3, 0, 0, 0);
    }
    float e[4][4], mr[4], sm[4];
#pragma unroll
    for (int r = 0; r < 4; ++r) {
      float v0 = s0[r] * scl, v1 = s1[r] * scl;
      float v2 = s2[r] * scl, v3 = s3[r] * scl;
      e[0][r] = v0; e[1][r] = v1; e[2][r] = v2; e[3][r] = v3;
      mr[r] = fmaxf(fmaxf(v0, v1), fmaxf(v2, v3));
    }
#pragma unroll
    for (int mask = 1; mask <= 8; mask <<= 1)
#pragma unroll
      for (int r = 0; r < 4; ++r)
        mr[r] = fmaxf(mr[r], __shfl_xor(mr[r], mask, 64));
#pragma unroll
    for (int r = 0; r < 4; ++r) {
      float acc = 0.f;
#pragma unroll
      for (int t = 0; t < 4; ++t) {
        float ev = __expf(e[t][r] - mr[r]);
        e[t][r] = ev;
        acc += ev;
      }
      sm[r] = acc;
    }
#pragma unroll
    for (int mask = 1; mask <= 8; mask <<= 1)
#pragma unroll
      for (int r = 0; r < 4; ++r)
        sm[r] += __shfl_xor(sm[r], mask, 64);
#pragma unroll
    for (int t = 0; t < 4; ++t)
#pragma unroll
      for (int r = 0; r < 4; ++r)
        Pw[(quad * 4 + r) * PP + t * 16 + col] = f2b(e[t][r]);
    __syncthreads();
    floatx4 o0 = {0.f,0.f,0.f,0.f}, o1 = o0;
#pragma unroll
    for (int c = 0; c < 2; ++c) {
      short8 ap = *(const short8*)(Pw + col * PP + c * 32 + quad * 8);
      short8 v0 = *(const short8*)(Vw + col * VP + c * 32 + quad * 8);
      short8 v1 = *(const short8*)(Vw + (16 + col) * VP + c * 32 + quad * 8);
      o0 = __builtin_amdgcn_mfma_f32_16x16x32_bf16(ap, v0, o0, 0, 0, 0);
      o1 = __builtin_amdgcn_mfma_f32_16x16x32_bf16(ap, v1, o1, 0, 0, 0);
    }
#pragma unroll
    for (int r = 0; r < 4; ++r) {
      float iv = 1.0f / sm[r];
      size_t row = (size_t)(b * 128 + qt * 16 + quad * 4 + r) * 256 + head * 32;
      obuf[row + col] = f2b(o0[r] * iv);
      obuf[row + 16 + col] = f2b(o1[r] * iv);
    }
    __syncthreads();
  }
}

// ===================== GEMM (A M-major fp32): C = A * W^T + biasf ==========
__global__ __launch_bounds__(256) void gemmN_kernel(
    const float* __restrict__ A, const float* __restrict__ Wt,
    const float* __restrict__ biasf, float* __restrict__ Cout, int mode)
{
  __shared__ float As[64][17];
  __shared__ float Ws[16][65];
  int m0 = blockIdx.x * 64;
  int n0 = blockIdx.y * 64;
  int tid = threadIdx.x;
  int tx = tid & 15, ty = tid >> 4;
  float acc[4][4] = {};
  for (int k0 = 0; k0 < 256; k0 += 16) {
    {
      int m = tid >> 2;
      int kq = (tid & 3) << 2;
      float4 v = *(const float4*)(A + (size_t)(m0 + m) * 256 + k0 + kq);
      As[m][kq + 0] = v.x; As[m][kq + 1] = v.y;
      As[m][kq + 2] = v.z; As[m][kq + 3] = v.w;
    }
    {
      int f = tid >> 2;
      int kq = (tid & 3) << 2;
      float4 v = *(const float4*)(Wt + (size_t)(n0 + f) * 256 + k0 + kq);
      Ws[kq + 0][f] = v.x; Ws[kq + 1][f] = v.y;
      Ws[kq + 2][f] = v.z; Ws[kq + 3][f] = v.w;
    }
    __syncthreads();
#pragma unroll
    for (int kk = 0; kk < 16; ++kk) {
      float a[4], b[4];
#pragma unroll
      for (int i = 0; i < 4; ++i) a[i] = As[ty * 4 + i][kk];
#pragma unroll
      for (int jj = 0; jj < 4; ++jj) b[jj] = Ws[kk][tx * 4 + jj];
#pragma unroll
      for (int i = 0; i < 4; ++i)
#pragma unroll
        for (int jj = 0; jj < 4; ++jj) acc[i][jj] += a[i] * b[jj];
    }
    __syncthreads();
  }
#pragma unroll
  for (int i = 0; i < 4; ++i) {
    int m = m0 + ty * 4 + i;
    int f = n0 + tx * 4;
    float4 ov;
    if (mode == 0) {
      float4 bv = *(const float4*)(biasf + f);
      ov.x = acc[i][0] + bv.x; ov.y = acc[i][1] + bv.y;
      ov.z = acc[i][2] + bv.z; ov.w = acc[i][3] + bv.w;
    } else {
      ov.x = acc[i][0]; ov.y = acc[i][1];
      ov.z = acc[i][2]; ov.w = acc[i][3];
    }
    *(float4*)(Cout + (size_t)m * 256 + f) = ov;
  }
}

// ===================== GEMM A[m][k] * B[k][n] (effective weights) ==========
__global__ __launch_bounds__(256) void gemm_ab_kernel(
    const float* __restrict__ in_w, const float* __restrict__ Wq,
    const float* __restrict__ Wk, const float* __restrict__ Wv,
    float* __restrict__ weff)
{
  int z = blockIdx.z;
  const float* A = in_w + (size_t)z * 65536;
  const float* B = (z == 0) ? Wq : ((z == 1) ? Wk : Wv);
  float* C = weff + (size_t)z * 65536;
  __shared__ float As[64][17];
  __shared__ float Bs[16][64];
  int m0 = blockIdx.x * 64;
  int n0 = blockIdx.y * 64;
  int tid = threadIdx.x;
  int tx = tid & 15, ty = tid >> 4;
  float acc[4][4] = {};
  for (int k0 = 0; k0 < 256; k0 += 16) {
    {
      int m = tid >> 2;
      int kq = (tid & 3) << 2;
      float4 v = *(const float4*)(A + (size_t)(m0 + m) * 256 + k0 + kq);
      As[m][kq + 0] = v.x; As[m][kq + 1] = v.y;
      As[m][kq + 2] = v.z; As[m][kq + 3] = v.w;
    }
    {
      int k = tid >> 4;
      int nq = (tid & 15) << 2;
      float4 v = *(const float4*)(B + (size_t)(k0 + k) * 256 + n0 + nq);
      *(float4*)(&Bs[k][nq]) = v;
    }
    __syncthreads();
#pragma unroll
    for (int kk = 0; kk < 16; ++kk) {
      float a[4], b[4];
#pragma unroll
      for (int i = 0; i < 4; ++i) a[i] = As[ty * 4 + i][kk];
#pragma unroll
      for (int jj = 0; jj < 4; ++jj) b[jj] = Bs[kk][tx * 4 + jj];
#pragma unroll
      for (int i = 0; i < 4; ++i)
#pragma unroll
        for (int jj = 0; jj < 4; ++jj) acc[i][jj] += a[i] * b[jj];
    }
    __syncthreads();
  }
#pragma unroll
  for (int i = 0; i < 4; ++i) {
    int m = m0 + ty * 4 + i;
    *(float4*)(C + (size_t)m * 256 + n0 + tx * 4) = *(float4*)&acc[i][0];
  }
}

// ===================== effective biases =====================
__global__ void beff_kernel(const float* __restrict__ in_w, const float* __restrict__ in_b,
                            const float* __restrict__ bq, const float* __restrict__ bk,
                            const float* __restrict__ bv, float* __restrict__ beff)
{
  int z = blockIdx.x;
  int f = threadIdx.x;
  const float* bsrc = (z == 0) ? bq : ((z == 1) ? bk : bv);
  const float* row = in_w + (size_t)(z * 256 + f) * 256;
  float acc = in_b[z * 256 + f];
  for (int e = 0; e < 256; ++e) acc += row[e] * bsrc[e];
  beff[z * 256 + f] = acc;
}

// ===================== segmented reduction over sorted samples =============
#define CH 64
__global__ __launch_bounds__(256) void segred_kernel(
    const ushort* __restrict__ obuf, const int* __restrict__ order,
    const int* __restrict__ pixs, float* __restrict__ osum)
{
  __shared__ int lm[CH];
  __shared__ int lp[CH + 2];
  int s0 = blockIdx.x * CH;
  int t = threadIdx.x;
  if (t < CH) {
    lm[t] = order[s0 + t];
    lp[t + 1] = pixs[s0 + t];
  } else if (t == CH) {
    lp[0] = (s0 > 0) ? pixs[s0 - 1] : -1;
  } else if (t == CH + 1) {
    lp[CH + 1] = (s0 + CH < MS) ? pixs[s0 + CH] : -2;
  }
  __syncthreads();
  int c = t;
  float va[8];
#pragma unroll
  for (int k = 0; k < 8; ++k)
    va[k] = b2f(obuf[(size_t)lm[k] * 256 + c]);
  float acc = 0.0f;
  int runBegin = 0;
#pragma unroll
  for (int i = 0; i < CH; ++i) {
    float v = va[i & 7];
    if (i + 8 < CH) va[i & 7] = b2f(obuf[(size_t)lm[i + 8] * 256 + c]);
    acc += v;
    int p = lp[i + 1];
    bool last = (i == CH - 1);
    if (last || p != lp[i + 2]) {
      bool pBeg = (runBegin == 0) && (p == lp[0]);
      bool pEnd = last && (p == lp[CH + 1]);
      float* dst = osum + (size_t)p * 256 + c;
      if (pBeg || pEnd) atomicAdd(dst, acc);
      else *dst = acc;
      acc = 0.0f;
      runBegin = i + 1;
    }
  }
}

// ===================== fused out-proj + residual update ====================
// osum[p][256] f32 -> (out_w proj) -> adst[c][p] = asrc + scale*(e+cn*ob)/max(cn,1)
__global__ __launch_bounds__(256) void outproj_update_kernel(
    const float* __restrict__ osum, const ushort* __restrict__ out_wh,
    const float* __restrict__ asrc, float* __restrict__ adst,
    const float* __restrict__ cnt, const float* __restrict__ out_b,
    float scale)
{
  int p0 = blockIdx.x * 64;
  int lane = threadIdx.x & 63;
  int wave = threadIdx.x >> 6;
  int col = lane & 15, quad = lane >> 4;
  int fw = wave * 64;
  floatx4 acc[4][4];
#pragma unroll
  for (int i = 0; i < 4; ++i)
#pragma unroll
    for (int jx = 0; jx < 4; ++jx) acc[i][jx] = (floatx4){0.f, 0.f, 0.f, 0.f};

  for (int kb = 0; kb < 256; kb += 32) {
    short8 aop[4], bop[4];
#pragma unroll
    for (int tf = 0; tf < 4; ++tf)
      aop[tf] = *(const short8*)(out_wh +
          (size_t)(fw + tf * 16 + col) * 256 + kb + quad * 8);
#pragma unroll
    for (int ts = 0; ts < 4; ++ts) {
      const float* brow = osum + (size_t)(p0 + ts * 16 + col) * 256 + kb + quad * 8;
      float4 f0 = *(const float4*)brow;
      float4 f1 = *(const float4*)(brow + 4);
      short8 bv;
      bv[0] = (short)f2b(f0.x); bv[1] = (short)f2b(f0.y);
      bv[2] = (short)f2b(f0.z); bv[3] = (short)f2b(f0.w);
      bv[4] = (short)f2b(f1.x); bv[5] = (short)f2b(f1.y);
      bv[6] = (short)f2b(f1.z); bv[7] = (short)f2b(f1.w);
      bop[ts] = bv;
    }
#pragma unroll
    for (int ts = 0; ts < 4; ++ts)
#pragma unroll
      for (int tf = 0; tf < 4; ++tf)
        acc[ts][tf] = __builtin_amdgcn_mfma_f32_16x16x32_bf16(
            aop[tf], bop[ts], acc[ts][tf], 0, 0, 0);
  }
  // epilogue: acc[ts][tf][r] = enh(f=fw+tf*16+quad*4+r, p=p0+ts*16+col)
#pragma unroll
  for (int ts = 0; ts < 4; ++ts) {
    int p = p0 + ts * 16 + col;
    float cn = cnt[p];
    float rs = scale / fmaxf(cn, 1.0f);
#pragma unroll
    for (int tf = 0; tf < 4; ++tf) {
      int f = fw + tf * 16 + quad * 4;
      float4 ob = *(const float4*)(out_b + f);
      adst[(size_t)(f + 0) * PIX + p] = asrc[(size_t)(f + 0) * PIX + p] + (acc[ts][tf][0] + cn * ob.x) * rs;
      adst[(size_t)(f + 1) * PIX + p] = asrc[(size_t)(f + 1) * PIX + p] + (acc[ts][tf][1] + cn * ob.y) * rs;
      adst[(size_t)(f + 2) * PIX + p] = asrc[(size_t)(f + 2) * PIX + p] + (acc[ts][tf][2] + cn * ob.z) * rs;
      adst[(size_t)(f + 3) * PIX + p] = asrc[(size_t)(f + 3) * PIX + p] + (acc[ts][tf][3] + cn * ob.w) * rs;
    }
  }
}

// ===================== launch =====================
extern "C" void kernel_launch(void* const* d_in, const int* in_sizes, int n_in,
                              void* d_out, int out_size, void* d_ws, size_t ws_size,
                              hipStream_t stream) {
  const float* list_a = (const float*)d_in[0];
  const float* list_b = (const float*)d_in[1];
  const float* rots   = (const float*)d_in[3];
  const float* fxs    = (const float*)d_in[5];
  const float* cxs    = (const float*)d_in[6];
  const float* pos_a  = (const float*)d_in[7];
  const float* pos_b  = (const float*)d_in[8];
  const float* Wq     = (const float*)d_in[9];
  const float* bq     = (const float*)d_in[10];
  const float* Wk     = (const float*)d_in[11];
  const float* bk     = (const float*)d_in[12];
  const float* Wv     = (const float*)d_in[13];
  const float* bv     = (const float*)d_in[14];
  const float* in_w   = (const float*)d_in[15];
  const float* in_b   = (const float*)d_in[16];
  const float* out_w  = (const float*)d_in[17];
  const float* out_b  = (const float*)d_in[18];

  float* ws      = (float*)d_ws;
  float* weff    = ws;                          // 196608 f
  float* beff    = weff + 196608;               // 768 f
  float* qpos    = beff + 768;                  // 32768 f
  float* kpos    = qpos + 32768;                // 16384 f
  float* vpos    = kpos + 16384;                // 16384 f
  float* a_cur   = vpos + 16384;                // 4194304 f
  float* xarr    = a_cur + 4194304;             // 51200 f
  float* yarr    = xarr + 51200;                // 51200 f
  int*   idxarr  = (int*)(yarr + 51200);        // 51200
  float* cnt     = (float*)(idxarr + 51200);    // 16384 f
  int*   cursor  = (int*)(cnt + 16384);         // 16384
  int*   offs    = cursor + 16384;              // 16384
  int*   order   = offs + 16384;                // 51200
  int*   pixs    = order + 51200;               // 51200
  float* osum    = (float*)(pixs + 51200);      // 4194304 f
  ushort* weffh  = (ushort*)(osum + 4194304);   // 196608 h
  ushort* out_wh = weffh + 196608;              // 65536 h
  ushort* obufh  = out_wh + 65536;              // 13107200 h
  ushort* bhT    = obufh + 13107200;            // 6553600 h (m-major b feat)
  ushort* qh     = bhT + 6553600;               // 13107200 h
  ushort* kh     = qh + 13107200;               // 6553600 h
  ushort* vh     = kh + 6553600;                // 6553600 h
  ushort* aT     = vh + 6553600;                // 4194304 h

  // effective weights + biases (tiny)
  gemm_ab_kernel<<<dim3(4, 4, 3), 256, 0, stream>>>(in_w, Wq, Wk, Wv, weff);
  beff_kernel<<<3, 256, 0, stream>>>(in_w, in_b, bq, bk, bv, beff);
  f2b_kernel<<<192, 256, 0, stream>>>(weff, weffh);
  f2b_kernel<<<64, 256, 0, stream>>>(out_w, out_wh);

  // positional bias tables: pos @ Weff^T + beff
  gemmN_kernel<<<dim3(2, 4), 256, 0, stream>>>(pos_a, weff, beff, qpos, 0);
  gemmN_kernel<<<dim3(1, 4), 256, 0, stream>>>(pos_b, weff + 65536, beff + 256, kpos, 0);
  gemmN_kernel<<<dim3(1, 4), 256, 0, stream>>>(pos_b, weff + 131072, beff + 512, vpos, 0);

  for (int jj = 0; jj < 2; ++jj) {
    int j = jj ? 3 : 0;
    const float* asrc = jj ? a_cur : list_a;
    hipMemsetAsync(cnt, 0, (size_t)2 * 16384 * sizeof(float), stream);  // cnt + cursor
    hipMemsetAsync(osum, 0, (size_t)4194304 * sizeof(float), stream);
    coords_kernel<<<200, 256, 0, stream>>>(rots, fxs, cxs, j, xarr, yarr, idxarr, cnt);
    prefix_kernel<<<1, 256, 0, stream>>>(cnt, offs);
    fill_kernel<<<200, 256, 0, stream>>>(idxarr, offs, cursor, order, pixs);
    // image -> pixel-major bf16; b -> m-major bf16
    transpose_kernel<<<dim3(256, 4), 256, 0, stream>>>(asrc, aT, PIX);
    const float* bsrc = list_b + (size_t)j * 6553600;
    transpose_kernel<<<dim3(400, 4), 256, 0, stream>>>(bsrc, bhT, MB);
    // fused bilinear sample + Q projection
    sampleproj_kernel<<<800, 256, 0, stream>>>(aT, xarr, yarr, weffh, qpos, qh);
    // fused K+V projections from m-major b
    projKV_kernel<<<400, 256, 0, stream>>>(bhT, weffh + 65536, weffh + 131072,
                                           kpos, vpos, kh, vh);
    // MFMA flash attention
    attn_mfma_kernel<<<dim3(400, 2), 256, 0, stream>>>(qh, kh, vh, obufh);
    // segmented reduction of O over sorted samples -> osum fp32
    segred_kernel<<<800, 256, 0, stream>>>(obufh, order, pixs, osum);
    // fused out-proj + residual update
    outproj_update_kernel<<<256, 256, 0, stream>>>(osum, out_wh, asrc,
                                                   jj ? (float*)d_out : a_cur,
                                                   cnt, out_b, jj ? 2.0f : 1.0f);
  }
}

// Round 3
// 676.917 us; speedup vs baseline: 1.0640x; 1.0303x over previous
//
#include <hip/hip_runtime.h>

// Problem constants
// a: (256,128,128)  b: (4,256,64,400)  E=256 NH=8 DH=32  B=400 Lq=128 Lk=64
#define PIX 16384          // 128*128
#define MS 51200           // H1*W2 samples
#define MB 25600           // H2*W2

typedef __attribute__((ext_vector_type(8))) short short8;
typedef __attribute__((ext_vector_type(4))) float floatx4;

__device__ inline ushort f2b(float x) {
  uint u = __float_as_uint(x);
  return (ushort)((u + 0x7fffu + ((u >> 16) & 1u)) >> 16);
}
__device__ inline float b2f(ushort u) {
  return __uint_as_float(((uint)u) << 16);
}

// ===================== coords: x,y, scatter idx, counts =====================
__global__ __launch_bounds__(256) void coords_kernel(
    const float* __restrict__ rots, const float* __restrict__ fxs,
    const float* __restrict__ cxs, int j,
    float* __restrict__ xarr, float* __restrict__ yarr,
    int* __restrict__ idxarr, float* __restrict__ cnt)
{
  int s = blockIdx.x * 256 + threadIdx.x;      // 0..51199, s = h*400 + w
  int h = s / 400;
  int w = s - h * 400;
  float fx = fxs[j], cx = cxs[j];
  const float* R = rots + j * 9;
  float cr = R[3];        // rots[1][0]
  float sr = -R[0];       // -rots[0][0]
  float t = (2.0f * (float)w + 1.0f - cx) / fx;      // tan(ang)
  float inv = 1.0f / sqrtf(1.0f + t * t);            // cos(ang)
  float ca = (cr + sr * t) * inv;                    // cr*cos + sr*sin
  float sa = (cr * t - sr) * inv;                    // -sr*cos + cr*sin
  float rad = ((float)h * (1.0f / 127.0f)) * 90.50966799187808f;
  float x = 64.0f + rad * ca;
  float y = 64.0f - rad * sa;
  xarr[s] = x;
  yarr[s] = y;
  int xi = (int)fminf(fmaxf(rintf(x), 0.0f), 127.0f);
  int yi = (int)fminf(fmaxf(rintf(y), 0.0f), 127.0f);
  int pix = yi * 128 + xi;
  idxarr[s] = pix;
  atomicAdd(&cnt[pix], 1.0f);
}

// ===================== prefix scan over pixel counts (vectorized) ==========
__global__ __launch_bounds__(256) void prefix_kernel(
    const float* __restrict__ cnt, int* __restrict__ offsets)
{
  __shared__ int sh[256];
  int t = threadIdx.x;
  int base = t * 64;
  const float4* cp = (const float4*)(cnt + base);
  int sum = 0;
#pragma unroll
  for (int i = 0; i < 16; ++i) {
    float4 v = cp[i];
    sum += (int)v.x + (int)v.y + (int)v.z + (int)v.w;
  }
  sh[t] = sum;
  __syncthreads();
  for (int d = 1; d < 256; d <<= 1) {
    int v = (t >= d) ? sh[t - d] : 0;
    __syncthreads();
    sh[t] += v;
    __syncthreads();
  }
  int run = sh[t] - sum;   // exclusive prefix for this thread's chunk
  int4* op = (int4*)(offsets + base);
#pragma unroll
  for (int i = 0; i < 16; ++i) {
    float4 v = cp[i];
    int a0 = (int)v.x, a1 = (int)v.y, a2 = (int)v.z, a3 = (int)v.w;
    int4 o;
    o.x = run; o.y = run + a0; o.z = run + a0 + a1; o.w = run + a0 + a1 + a2;
    op[i] = o;
    run += a0 + a1 + a2 + a3;
  }
}

// ===================== fill sorted sample lists =====================
__global__ __launch_bounds__(256) void fill_kernel(
    const int* __restrict__ idxarr, const int* __restrict__ offsets,
    int* __restrict__ cursor, int* __restrict__ order, int* __restrict__ pixs)
{
  int s = blockIdx.x * 256 + threadIdx.x;
  int pix = idxarr[s];
  int pos = offsets[pix] + atomicAdd(&cursor[pix], 1);
  // store the attention-output row index m = w*128 + h  (s = h*400 + w)
  order[pos] = (s % 400) * 128 + (s / 400);
  pixs[pos] = pix;
}

// ===================== transpose: fp32 [256][W] -> bf16 [W][256] ===========
// W = 16384 (a image) or 25600 (b features)
__global__ __launch_bounds__(256) void transpose_kernel(
    const float* __restrict__ src, ushort* __restrict__ dst, int W)
{
  __shared__ float tile[64][65];   // [p_local][c_local]
  int p0 = blockIdx.x * 64;
  int c0 = blockIdx.y * 64;
  int t = threadIdx.x;
  int pr = (t & 15) * 4;           // p offset
  int cr = t >> 4;                 // c row 0..15
#pragma unroll
  for (int q = 0; q < 4; ++q) {
    int c = cr + q * 16;
    float4 v = *(const float4*)(src + (size_t)(c0 + c) * W + p0 + pr);
    tile[pr + 0][c] = v.x;
    tile[pr + 1][c] = v.y;
    tile[pr + 2][c] = v.z;
    tile[pr + 3][c] = v.w;
  }
  __syncthreads();
  int p = t >> 2;
  int ch = (t & 3) * 16;
  ushort tmp[16];
#pragma unroll
  for (int i = 0; i < 16; ++i) tmp[i] = f2b(tile[p][ch + i]);
  ushort* d = dst + (size_t)(p0 + p) * 256 + c0 + ch;
  *(uint4*)(d) = *(uint4*)tmp;
  *(uint4*)(d + 8) = *(uint4*)(tmp + 8);
}

// ===================== f32 -> bf16 bulk convert (float4-wide) ==============
__global__ __launch_bounds__(256) void f2b_kernel(
    const float* __restrict__ in, ushort* __restrict__ out)
{
  int t = blockIdx.x * 256 + threadIdx.x;
  float4 v = ((const float4*)in)[t];
  ushort4 o;
  o.x = f2b(v.x); o.y = f2b(v.y); o.z = f2b(v.z); o.w = f2b(v.w);
  ((ushort4*)out)[t] = o;
}

// ===================== fused bilinear sample + Q projection ================
// aT[p][256] bf16 -> (LDS feat tile) -> qh[(w*128+h)*256+f] bf16
#define LFP 264   // LDS feat row stride in halfs (528B: 16B-aligned, 2-way banks)
__global__ __launch_bounds__(256) void sampleproj_kernel(
    const ushort* __restrict__ aT, const float* __restrict__ xarr,
    const float* __restrict__ yarr, const ushort* __restrict__ Wh,
    const float* __restrict__ bias, ushort* __restrict__ qh)
{
  __shared__ ushort lf[64 * LFP];
  int s0 = blockIdx.x * 64;
  int tid = threadIdx.x;
  int lane = tid & 63;
  int wave = tid >> 6;
  int col = lane & 15, quad = lane >> 4;
  int c0 = lane * 4;

  // gather phase: each wave computes 16 samples (all 256 channels)
#pragma unroll 4
  for (int i = 0; i < 16; ++i) {
    int sl = wave * 16 + i;
    int s = s0 + sl;
    float x = fminf(fmaxf(xarr[s], 0.0f), 127.0f);
    float y = fminf(fmaxf(yarr[s], 0.0f), 127.0f);
    float x0f = floorf(x), y0f = floorf(y);
    int x0 = (int)x0f, y0 = (int)y0f;
    int x1 = min(x0 + 1, 127), y1 = min(y0 + 1, 127);
    float wx = x - x0f, wy = y - y0f;
    float w00 = (1.0f - wx) * (1.0f - wy);
    float w01 = wx * (1.0f - wy);
    float w10 = (1.0f - wx) * wy;
    float w11 = wx * wy;
    ushort4 v00 = *(const ushort4*)(aT + (size_t)(y0 * 128 + x0) * 256 + c0);
    ushort4 v01 = *(const ushort4*)(aT + (size_t)(y0 * 128 + x1) * 256 + c0);
    ushort4 v10 = *(const ushort4*)(aT + (size_t)(y1 * 128 + x0) * 256 + c0);
    ushort4 v11 = *(const ushort4*)(aT + (size_t)(y1 * 128 + x1) * 256 + c0);
    ushort4 o;
    o.x = f2b(w00 * b2f(v00.x) + w01 * b2f(v01.x) + w10 * b2f(v10.x) + w11 * b2f(v11.x));
    o.y = f2b(w00 * b2f(v00.y) + w01 * b2f(v01.y) + w10 * b2f(v10.y) + w11 * b2f(v11.y));
    o.z = f2b(w00 * b2f(v00.z) + w01 * b2f(v01.z) + w10 * b2f(v10.z) + w11 * b2f(v11.z));
    o.w = f2b(w00 * b2f(v00.w) + w01 * b2f(v01.w) + w10 * b2f(v10.w) + w11 * b2f(v11.w));
    *(ushort4*)&lf[sl * LFP + c0] = o;
  }
  __syncthreads();

  // projection phase: identical to projS but B-operand from LDS
  int fw = wave * 64;
  floatx4 acc[4][4];
#pragma unroll
  for (int i = 0; i < 4; ++i)
#pragma unroll
    for (int jx = 0; jx < 4; ++jx) acc[i][jx] = (floatx4){0.f, 0.f, 0.f, 0.f};

  for (int kb = 0; kb < 256; kb += 32) {
    short8 aop[4], bop[4];
#pragma unroll
    for (int tf = 0; tf < 4; ++tf)
      aop[tf] = *(const short8*)(Wh + (size_t)(fw + tf * 16 + col) * 256 + kb + quad * 8);
#pragma unroll
    for (int ts = 0; ts < 4; ++ts)
      bop[ts] = *(const short8*)&lf[(ts * 16 + col) * LFP + kb + quad * 8];
#pragma unroll
    for (int ts = 0; ts < 4; ++ts)
#pragma unroll
      for (int tf = 0; tf < 4; ++tf)
        acc[ts][tf] = __builtin_amdgcn_mfma_f32_16x16x32_bf16(
            aop[tf], bop[ts], acc[ts][tf], 0, 0, 0);
  }
  // D: col -> s, row=quad*4+r -> f
#pragma unroll
  for (int ts = 0; ts < 4; ++ts) {
    int s = s0 + ts * 16 + col;
    int h = s / 400;
    int w = s - h * 400;
    size_t obase = (size_t)(w * 128 + h) * 256;
#pragma unroll
    for (int tf = 0; tf < 4; ++tf) {
      int f = fw + tf * 16 + quad * 4;
      float4 bv = *(const float4*)(bias + h * 256 + f);
      ushort4 ov;
      ov.x = f2b(acc[ts][tf][0] + bv.x);
      ov.y = f2b(acc[ts][tf][1] + bv.y);
      ov.z = f2b(acc[ts][tf][2] + bv.z);
      ov.w = f2b(acc[ts][tf][3] + bv.w);
      *(ushort4*)(qh + obase + f) = ov;
    }
  }
}

// ===================== fused K+V projection, single featB pass =============
// featB[m][256] bf16 (m = h2*400 + w2), outputs kh/vh[(w2*64+h2)*256+f]
__global__ __launch_bounds__(256) void projKV_kernel(
    const ushort* __restrict__ featB,
    const ushort* __restrict__ WhK, const ushort* __restrict__ WhV,
    const float* __restrict__ biasK, const float* __restrict__ biasV,
    ushort* __restrict__ kh, ushort* __restrict__ vh)
{
  int m0 = blockIdx.x * 64;
  int lane = threadIdx.x & 63;
  int wave = threadIdx.x >> 6;
  int col = lane & 15, quad = lane >> 4;
  int fw = wave * 64;

  floatx4 accK[4][4], accV[4][4];
#pragma unroll
  for (int i = 0; i < 4; ++i)
#pragma unroll
    for (int jx = 0; jx < 4; ++jx) {
      accK[i][jx] = (floatx4){0.f, 0.f, 0.f, 0.f};
      accV[i][jx] = (floatx4){0.f, 0.f, 0.f, 0.f};
    }

  for (int kb = 0; kb < 256; kb += 32) {
    short8 bop[4];
#pragma unroll
    for (int ts = 0; ts < 4; ++ts)
      bop[ts] = *(const short8*)(featB + (size_t)(m0 + ts * 16 + col) * 256 + kb + quad * 8);
    short8 aK[4];
#pragma unroll
    for (int tf = 0; tf < 4; ++tf)
      aK[tf] = *(const short8*)(WhK + (size_t)(fw + tf * 16 + col) * 256 + kb + quad * 8);
#pragma unroll
    for (int ts = 0; ts < 4; ++ts)
#pragma unroll
      for (int tf = 0; tf < 4; ++tf)
        accK[ts][tf] = __builtin_amdgcn_mfma_f32_16x16x32_bf16(
            aK[tf], bop[ts], accK[ts][tf], 0, 0, 0);
    short8 aV[4];
#pragma unroll
    for (int tf = 0; tf < 4; ++tf)
      aV[tf] = *(const short8*)(WhV + (size_t)(fw + tf * 16 + col) * 256 + kb + quad * 8);
#pragma unroll
    for (int ts = 0; ts < 4; ++ts)
#pragma unroll
      for (int tf = 0; tf < 4; ++tf)
        accV[ts][tf] = __builtin_amdgcn_mfma_f32_16x16x32_bf16(
            aV[tf], bop[ts], accV[ts][tf], 0, 0, 0);
  }
#pragma unroll
  for (int ts = 0; ts < 4; ++ts) {
    int m = m0 + ts * 16 + col;
    int h = m / 400;            // h2
    int w = m - h * 400;        // w2
    size_t obase = (size_t)(w * 64 + h) * 256;
#pragma unroll
    for (int tf = 0; tf < 4; ++tf) {
      int f = fw + tf * 16 + quad * 4;
      float4 bvK = *(const float4*)(biasK + h * 256 + f);
      ushort4 ovK;
      ovK.x = f2b(accK[ts][tf][0] + bvK.x);
      ovK.y = f2b(accK[ts][tf][1] + bvK.y);
      ovK.z = f2b(accK[ts][tf][2] + bvK.z);
      ovK.w = f2b(accK[ts][tf][3] + bvK.w);
      *(ushort4*)(kh + obase + f) = ovK;
      float4 bvV = *(const float4*)(biasV + h * 256 + f);
      ushort4 ovV;
      ovV.x = f2b(accV[ts][tf][0] + bvV.x);
      ovV.y = f2b(accV[ts][tf][1] + bvV.y);
      ovV.z = f2b(accV[ts][tf][2] + bvV.z);
      ovV.w = f2b(accV[ts][tf][3] + bvV.w);
      *(ushort4*)(vh + obase + f) = ovV;
    }
  }
}

// ===================== MFMA flash attention (barrier-free, per-wave LDS) ===
// All LDS is wave-private; per-wave DS ops are in-order, so no __syncthreads.
#define VP 72
#define PP 72
__global__ __launch_bounds__(256) void attn_mfma_kernel(
    const ushort* __restrict__ qh, const ushort* __restrict__ kh,
    const ushort* __restrict__ vh, ushort* __restrict__ obuf)
{
  __shared__ ushort lV[4][32 * VP];
  __shared__ ushort lP[4][16 * PP];
  int b = blockIdx.x;
  int wave = threadIdx.x >> 6;
  int lane = threadIdx.x & 63;
  int head = blockIdx.y * 4 + wave;
  int col = lane & 15, quad = lane >> 4;
  ushort* Vw = lV[wave];
  ushort* Pw = lP[wave];

  // K fragments direct from global (qt-invariant): row kt*16+col, dims head*32+quad*8..
  short8 bk0 = *(const short8*)(kh + ((size_t)(b * 64 +  0 + col)) * 256 + head * 32 + quad * 8);
  short8 bk1 = *(const short8*)(kh + ((size_t)(b * 64 + 16 + col)) * 256 + head * 32 + quad * 8);
  short8 bk2 = *(const short8*)(kh + ((size_t)(b * 64 + 32 + col)) * 256 + head * 32 + quad * 8);
  short8 bk3 = *(const short8*)(kh + ((size_t)(b * 64 + 48 + col)) * 256 + head * 32 + quad * 8);

  // V staged to LDS (d-major transpose), then hoist the 4 qt-invariant fragments
  {
    const ushort* vsrc = vh + ((size_t)(b * 64 + lane)) * 256 + head * 32;
    ushort vr[32];
    *(uint4*)(vr) = *(const uint4*)(vsrc);
    *(uint4*)(vr + 8) = *(const uint4*)(vsrc + 8);
    *(uint4*)(vr + 16) = *(const uint4*)(vsrc + 16);
    *(uint4*)(vr + 24) = *(const uint4*)(vsrc + 24);
#pragma unroll
    for (int d = 0; d < 32; ++d) Vw[d * VP + lane] = vr[d];
  }
  short8 vA0 = *(const short8*)(Vw + (col) * VP + 0 * 32 + quad * 8);
  short8 vB0 = *(const short8*)(Vw + (16 + col) * VP + 0 * 32 + quad * 8);
  short8 vA1 = *(const short8*)(Vw + (col) * VP + 1 * 32 + quad * 8);
  short8 vB1 = *(const short8*)(Vw + (16 + col) * VP + 1 * 32 + quad * 8);

  const float scl = 0.17677669529663687f;   // 1/sqrt(32)
  for (int qt = 0; qt < 8; ++qt) {
    short8 aq = *(const short8*)(qh +
        ((size_t)(b * 128 + qt * 16 + col)) * 256 + head * 32 + quad * 8);
    floatx4 s0 = {0.f,0.f,0.f,0.f}, s1 = s0, s2 = s0, s3 = s0;
    s0 = __builtin_amdgcn_mfma_f32_16x16x32_bf16(aq, bk0, s0, 0, 0, 0);
    s1 = __builtin_amdgcn_mfma_f32_16x16x32_bf16(aq, bk1, s1, 0, 0, 0);
    s2 = __builtin_amdgcn_mfma_f32_16x16x32_bf16(aq, bk2, s2, 0, 0, 0);
    s3 = __builtin_amdgcn_mfma_f32_16x16x32_bf16(aq, bk3, s3, 0, 0, 0);
    float e[4][4], mr[4], sm[4];
#pragma unroll
    for (int r = 0; r < 4; ++r) {
      float v0 = s0[r] * scl, v1 = s1[r] * scl;
      float v2 = s2[r] * scl, v3 = s3[r] * scl;
      e[0][r] = v0; e[1][r] = v1; e[2][r] = v2; e[3][r] = v3;
      mr[r] = fmaxf(fmaxf(v0, v1), fmaxf(v2, v3));
    }
#pragma unroll
    for (int mask = 1; mask <= 8; mask <<= 1)
#pragma unroll
      for (int r = 0; r < 4; ++r)
        mr[r] = fmaxf(mr[r], __shfl_xor(mr[r], mask, 64));
#pragma unroll
    for (int r = 0; r < 4; ++r) {
      float acc = 0.f;
#pragma unroll
      for (int t = 0; t < 4; ++t) {
        float ev = __expf(e[t][r] - mr[r]);
        e[t][r] = ev;
        acc += ev;
      }
      sm[r] = acc;
    }
#pragma unroll
    for (int mask = 1; mask <= 8; mask <<= 1)
#pragma unroll
      for (int r = 0; r < 4; ++r)
        sm[r] += __shfl_xor(sm[r], mask, 64);
#pragma unroll
    for (int t = 0; t < 4; ++t)
#pragma unroll
      for (int r = 0; r < 4; ++r)
        Pw[(quad * 4 + r) * PP + t * 16 + col] = f2b(e[t][r]);
    // per-wave in-order DS pipe: reads below see the writes above
    floatx4 o0 = {0.f,0.f,0.f,0.f}, o1 = o0;
    {
      short8 ap0 = *(const short8*)(Pw + col * PP + 0 * 32 + quad * 8);
      o0 = __builtin_amdgcn_mfma_f32_16x16x32_bf16(ap0, vA0, o0, 0, 0, 0);
      o1 = __builtin_amdgcn_mfma_f32_16x16x32_bf16(ap0, vB0, o1, 0, 0, 0);
      short8 ap1 = *(const short8*)(Pw + col * PP + 1 * 32 + quad * 8);
      o0 = __builtin_amdgcn_mfma_f32_16x16x32_bf16(ap1, vA1, o0, 0, 0, 0);
      o1 = __builtin_amdgcn_mfma_f32_16x16x32_bf16(ap1, vB1, o1, 0, 0, 0);
    }
#pragma unroll
    for (int r = 0; r < 4; ++r) {
      float iv = 1.0f / sm[r];
      size_t row = (size_t)(b * 128 + qt * 16 + quad * 4 + r) * 256 + head * 32;
      obuf[row + col] = f2b(o0[r] * iv);
      obuf[row + 16 + col] = f2b(o1[r] * iv);
    }
  }
}

// ===================== GEMM (A M-major fp32): C = A * W^T + biasf ==========
__global__ __launch_bounds__(256) void gemmN_kernel(
    const float* __restrict__ A, const float* __restrict__ Wt,
    const float* __restrict__ biasf, float* __restrict__ Cout, int mode)
{
  __shared__ float As[64][17];
  __shared__ float Ws[16][65];
  int m0 = blockIdx.x * 64;
  int n0 = blockIdx.y * 64;
  int tid = threadIdx.x;
  int tx = tid & 15, ty = tid >> 4;
  float acc[4][4] = {};
  for (int k0 = 0; k0 < 256; k0 += 16) {
    {
      int m = tid >> 2;
      int kq = (tid & 3) << 2;
      float4 v = *(const float4*)(A + (size_t)(m0 + m) * 256 + k0 + kq);
      As[m][kq + 0] = v.x; As[m][kq + 1] = v.y;
      As[m][kq + 2] = v.z; As[m][kq + 3] = v.w;
    }
    {
      int f = tid >> 2;
      int kq = (tid & 3) << 2;
      float4 v = *(const float4*)(Wt + (size_t)(n0 + f) * 256 + k0 + kq);
      Ws[kq + 0][f] = v.x; Ws[kq + 1][f] = v.y;
      Ws[kq + 2][f] = v.z; Ws[kq + 3][f] = v.w;
    }
    __syncthreads();
#pragma unroll
    for (int kk = 0; kk < 16; ++kk) {
      float a[4], b[4];
#pragma unroll
      for (int i = 0; i < 4; ++i) a[i] = As[ty * 4 + i][kk];
#pragma unroll
      for (int jj = 0; jj < 4; ++jj) b[jj] = Ws[kk][tx * 4 + jj];
#pragma unroll
      for (int i = 0; i < 4; ++i)
#pragma unroll
        for (int jj = 0; jj < 4; ++jj) acc[i][jj] += a[i] * b[jj];
    }
    __syncthreads();
  }
#pragma unroll
  for (int i = 0; i < 4; ++i) {
    int m = m0 + ty * 4 + i;
    int f = n0 + tx * 4;
    float4 ov;
    if (mode == 0) {
      float4 bv = *(const float4*)(biasf + f);
      ov.x = acc[i][0] + bv.x; ov.y = acc[i][1] + bv.y;
      ov.z = acc[i][2] + bv.z; ov.w = acc[i][3] + bv.w;
    } else {
      ov.x = acc[i][0]; ov.y = acc[i][1];
      ov.z = acc[i][2]; ov.w = acc[i][3];
    }
    *(float4*)(Cout + (size_t)m * 256 + f) = ov;
  }
}

// ===================== GEMM A[m][k] * B[k][n] + bf16 copy ==================
__global__ __launch_bounds__(256) void gemm_ab_kernel(
    const float* __restrict__ in_w, const float* __restrict__ Wq,
    const float* __restrict__ Wk, const float* __restrict__ Wv,
    float* __restrict__ weff, ushort* __restrict__ weffh)
{
  int z = blockIdx.z;
  const float* A = in_w + (size_t)z * 65536;
  const float* B = (z == 0) ? Wq : ((z == 1) ? Wk : Wv);
  float* C = weff + (size_t)z * 65536;
  ushort* Ch = weffh + (size_t)z * 65536;
  __shared__ float As[64][17];
  __shared__ float Bs[16][64];
  int m0 = blockIdx.x * 64;
  int n0 = blockIdx.y * 64;
  int tid = threadIdx.x;
  int tx = tid & 15, ty = tid >> 4;
  float acc[4][4] = {};
  for (int k0 = 0; k0 < 256; k0 += 16) {
    {
      int m = tid >> 2;
      int kq = (tid & 3) << 2;
      float4 v = *(const float4*)(A + (size_t)(m0 + m) * 256 + k0 + kq);
      As[m][kq + 0] = v.x; As[m][kq + 1] = v.y;
      As[m][kq + 2] = v.z; As[m][kq + 3] = v.w;
    }
    {
      int k = tid >> 4;
      int nq = (tid & 15) << 2;
      float4 v = *(const float4*)(B + (size_t)(k0 + k) * 256 + n0 + nq);
      *(float4*)(&Bs[k][nq]) = v;
    }
    __syncthreads();
#pragma unroll
    for (int kk = 0; kk < 16; ++kk) {
      float a[4], b[4];
#pragma unroll
      for (int i = 0; i < 4; ++i) a[i] = As[ty * 4 + i][kk];
#pragma unroll
      for (int jj = 0; jj < 4; ++jj) b[jj] = Bs[kk][tx * 4 + jj];
#pragma unroll
      for (int i = 0; i < 4; ++i)
#pragma unroll
        for (int jj = 0; jj < 4; ++jj) acc[i][jj] += a[i] * b[jj];
    }
    __syncthreads();
  }
#pragma unroll
  for (int i = 0; i < 4; ++i) {
    int m = m0 + ty * 4 + i;
    *(float4*)(C + (size_t)m * 256 + n0 + tx * 4) = *(float4*)&acc[i][0];
    ushort4 hv;
    hv.x = f2b(acc[i][0]); hv.y = f2b(acc[i][1]);
    hv.z = f2b(acc[i][2]); hv.w = f2b(acc[i][3]);
    *(ushort4*)(Ch + (size_t)m * 256 + n0 + tx * 4) = hv;
  }
}

// ===================== effective biases =====================
__global__ void beff_kernel(const float* __restrict__ in_w, const float* __restrict__ in_b,
                            const float* __restrict__ bq, const float* __restrict__ bk,
                            const float* __restrict__ bv, float* __restrict__ beff)
{
  int z = blockIdx.x;
  int f = threadIdx.x;
  const float* bsrc = (z == 0) ? bq : ((z == 1) ? bk : bv);
  const float* row = in_w + (size_t)(z * 256 + f) * 256;
  float acc = in_b[z * 256 + f];
  for (int e = 0; e < 256; ++e) acc += row[e] * bsrc[e];
  beff[z * 256 + f] = acc;
}

// ===================== segmented reduction over sorted samples =============
#define CH 64
__global__ __launch_bounds__(256) void segred_kernel(
    const ushort* __restrict__ obuf, const int* __restrict__ order,
    const int* __restrict__ pixs, float* __restrict__ osum)
{
  __shared__ int lm[CH];
  __shared__ int lp[CH + 2];
  int s0 = blockIdx.x * CH;
  int t = threadIdx.x;
  if (t < CH) {
    lm[t] = order[s0 + t];
    lp[t + 1] = pixs[s0 + t];
  } else if (t == CH) {
    lp[0] = (s0 > 0) ? pixs[s0 - 1] : -1;
  } else if (t == CH + 1) {
    lp[CH + 1] = (s0 + CH < MS) ? pixs[s0 + CH] : -2;
  }
  __syncthreads();
  int c = t;
  float va[8];
#pragma unroll
  for (int k = 0; k < 8; ++k)
    va[k] = b2f(obuf[(size_t)lm[k] * 256 + c]);
  float acc = 0.0f;
  int runBegin = 0;
#pragma unroll
  for (int i = 0; i < CH; ++i) {
    float v = va[i & 7];
    if (i + 8 < CH) va[i & 7] = b2f(obuf[(size_t)lm[i + 8] * 256 + c]);
    acc += v;
    int p = lp[i + 1];
    bool last = (i == CH - 1);
    if (last || p != lp[i + 2]) {
      bool pBeg = (runBegin == 0) && (p == lp[0]);
      bool pEnd = last && (p == lp[CH + 1]);
      float* dst = osum + (size_t)p * 256 + c;
      if (pBeg || pEnd) atomicAdd(dst, acc);
      else *dst = acc;
      acc = 0.0f;
      runBegin = i + 1;
    }
  }
}

// ===================== fused out-proj + residual update ====================
// osum[p][256] f32 -> (out_w proj) -> adst[c][p] = asrc + scale*(e+cn*ob)/max(cn,1)
__global__ __launch_bounds__(256) void outproj_update_kernel(
    const float* __restrict__ osum, const ushort* __restrict__ out_wh,
    const float* __restrict__ asrc, float* __restrict__ adst,
    const float* __restrict__ cnt, const float* __restrict__ out_b,
    float scale)
{
  int p0 = blockIdx.x * 64;
  int lane = threadIdx.x & 63;
  int wave = threadIdx.x >> 6;
  int col = lane & 15, quad = lane >> 4;
  int fw = wave * 64;
  floatx4 acc[4][4];
#pragma unroll
  for (int i = 0; i < 4; ++i)
#pragma unroll
    for (int jx = 0; jx < 4; ++jx) acc[i][jx] = (floatx4){0.f, 0.f, 0.f, 0.f};

  for (int kb = 0; kb < 256; kb += 32) {
    short8 aop[4], bop[4];
#pragma unroll
    for (int tf = 0; tf < 4; ++tf)
      aop[tf] = *(const short8*)(out_wh +
          (size_t)(fw + tf * 16 + col) * 256 + kb + quad * 8);
#pragma unroll
    for (int ts = 0; ts < 4; ++ts) {
      const float* brow = osum + (size_t)(p0 + ts * 16 + col) * 256 + kb + quad * 8;
      float4 f0 = *(const float4*)brow;
      float4 f1 = *(const float4*)(brow + 4);
      short8 bv;
      bv[0] = (short)f2b(f0.x); bv[1] = (short)f2b(f0.y);
      bv[2] = (short)f2b(f0.z); bv[3] = (short)f2b(f0.w);
      bv[4] = (short)f2b(f1.x); bv[5] = (short)f2b(f1.y);
      bv[6] = (short)f2b(f1.z); bv[7] = (short)f2b(f1.w);
      bop[ts] = bv;
    }
#pragma unroll
    for (int ts = 0; ts < 4; ++ts)
#pragma unroll
      for (int tf = 0; tf < 4; ++tf)
        acc[ts][tf] = __builtin_amdgcn_mfma_f32_16x16x32_bf16(
            aop[tf], bop[ts], acc[ts][tf], 0, 0, 0);
  }
  // epilogue: acc[ts][tf][r] = enh(f=fw+tf*16+quad*4+r, p=p0+ts*16+col)
#pragma unroll
  for (int ts = 0; ts < 4; ++ts) {
    int p = p0 + ts * 16 + col;
    float cn = cnt[p];
    float rs = scale / fmaxf(cn, 1.0f);
#pragma unroll
    for (int tf = 0; tf < 4; ++tf) {
      int f = fw + tf * 16 + quad * 4;
      float4 ob = *(const float4*)(out_b + f);
      adst[(size_t)(f + 0) * PIX + p] = asrc[(size_t)(f + 0) * PIX + p] + (acc[ts][tf][0] + cn * ob.x) * rs;
      adst[(size_t)(f + 1) * PIX + p] = asrc[(size_t)(f + 1) * PIX + p] + (acc[ts][tf][1] + cn * ob.y) * rs;
      adst[(size_t)(f + 2) * PIX + p] = asrc[(size_t)(f + 2) * PIX + p] + (acc[ts][tf][2] + cn * ob.z) * rs;
      adst[(size_t)(f + 3) * PIX + p] = asrc[(size_t)(f + 3) * PIX + p] + (acc[ts][tf][3] + cn * ob.w) * rs;
    }
  }
}

// ===================== launch =====================
extern "C" void kernel_launch(void* const* d_in, const int* in_sizes, int n_in,
                              void* d_out, int out_size, void* d_ws, size_t ws_size,
                              hipStream_t stream) {
  const float* list_a = (const float*)d_in[0];
  const float* list_b = (const float*)d_in[1];
  const float* rots   = (const float*)d_in[3];
  const float* fxs    = (const float*)d_in[5];
  const float* cxs    = (const float*)d_in[6];
  const float* pos_a  = (const float*)d_in[7];
  const float* pos_b  = (const float*)d_in[8];
  const float* Wq     = (const float*)d_in[9];
  const float* bq     = (const float*)d_in[10];
  const float* Wk     = (const float*)d_in[11];
  const float* bk     = (const float*)d_in[12];
  const float* Wv     = (const float*)d_in[13];
  const float* bv     = (const float*)d_in[14];
  const float* in_w   = (const float*)d_in[15];
  const float* in_b   = (const float*)d_in[16];
  const float* out_w  = (const float*)d_in[17];
  const float* out_b  = (const float*)d_in[18];

  float* ws      = (float*)d_ws;
  float* weff    = ws;                          // 196608 f
  float* beff    = weff + 196608;               // 768 f
  float* qpos    = beff + 768;                  // 32768 f
  float* kpos    = qpos + 32768;                // 16384 f
  float* vpos    = kpos + 16384;                // 16384 f
  float* a_cur   = vpos + 16384;                // 4194304 f
  float* xarr    = a_cur + 4194304;             // 51200 f
  float* yarr    = xarr + 51200;                // 51200 f
  int*   idxarr  = (int*)(yarr + 51200);        // 51200
  float* cnt     = (float*)(idxarr + 51200);    // 16384 f
  int*   cursor  = (int*)(cnt + 16384);         // 16384
  int*   offs    = cursor + 16384;              // 16384
  int*   order   = offs + 16384;                // 51200
  int*   pixs    = order + 51200;               // 51200
  float* osum    = (float*)(pixs + 51200);      // 4194304 f
  ushort* weffh  = (ushort*)(osum + 4194304);   // 196608 h
  ushort* out_wh = weffh + 196608;              // 65536 h
  ushort* obufh  = out_wh + 65536;              // 13107200 h
  ushort* bhT    = obufh + 13107200;            // 6553600 h (m-major b feat)
  ushort* qh     = bhT + 6553600;               // 13107200 h
  ushort* kh     = qh + 13107200;               // 6553600 h
  ushort* vh     = kh + 6553600;                // 6553600 h
  ushort* aT     = vh + 6553600;                // 4194304 h

  // effective weights + biases (tiny)
  gemm_ab_kernel<<<dim3(4, 4, 3), 256, 0, stream>>>(in_w, Wq, Wk, Wv, weff, weffh);
  beff_kernel<<<3, 256, 0, stream>>>(in_w, in_b, bq, bk, bv, beff);
  f2b_kernel<<<64, 256, 0, stream>>>(out_w, out_wh);

  // positional bias tables: pos @ Weff^T + beff
  gemmN_kernel<<<dim3(2, 4), 256, 0, stream>>>(pos_a, weff, beff, qpos, 0);
  gemmN_kernel<<<dim3(1, 4), 256, 0, stream>>>(pos_b, weff + 65536, beff + 256, kpos, 0);
  gemmN_kernel<<<dim3(1, 4), 256, 0, stream>>>(pos_b, weff + 131072, beff + 512, vpos, 0);

  for (int jj = 0; jj < 2; ++jj) {
    int j = jj ? 3 : 0;
    const float* asrc = jj ? a_cur : list_a;
    hipMemsetAsync(cnt, 0, (size_t)2 * 16384 * sizeof(float), stream);  // cnt + cursor
    hipMemsetAsync(osum, 0, (size_t)4194304 * sizeof(float), stream);
    coords_kernel<<<200, 256, 0, stream>>>(rots, fxs, cxs, j, xarr, yarr, idxarr, cnt);
    prefix_kernel<<<1, 256, 0, stream>>>(cnt, offs);
    fill_kernel<<<200, 256, 0, stream>>>(idxarr, offs, cursor, order, pixs);
    // image -> pixel-major bf16; b -> m-major bf16
    transpose_kernel<<<dim3(256, 4), 256, 0, stream>>>(asrc, aT, PIX);
    const float* bsrc = list_b + (size_t)j * 6553600;
    transpose_kernel<<<dim3(400, 4), 256, 0, stream>>>(bsrc, bhT, MB);
    // fused bilinear sample + Q projection
    sampleproj_kernel<<<800, 256, 0, stream>>>(aT, xarr, yarr, weffh, qpos, qh);
    // fused K+V projections, single featB pass
    projKV_kernel<<<400, 256, 0, stream>>>(bhT, weffh + 65536, weffh + 131072,
                                           kpos, vpos, kh, vh);
    // MFMA flash attention (barrier-free)
    attn_mfma_kernel<<<dim3(400, 2), 256, 0, stream>>>(qh, kh, vh, obufh);
    // segmented reduction of O over sorted samples -> osum fp32
    segred_kernel<<<800, 256, 0, stream>>>(obufh, order, pixs, osum);
    // fused out-proj + residual update
    outproj_update_kernel<<<256, 256, 0, stream>>>(osum, out_wh, asrc,
                                                   jj ? (float*)d_out : a_cur,
                                                   cnt, out_b, jj ? 2.0f : 1.0f);
  }
}

// Round 4
// 560.667 us; speedup vs baseline: 1.2847x; 1.2073x over previous
//
#include <hip/hip_runtime.h>

// Problem constants
// a: (256,128,128)  b: (4,256,64,400)  E=256 NH=8 DH=32  B=400 Lq=128 Lk=64
#define PIX 16384          // 128*128
#define MS 51200           // H1*W2 samples
#define MB 25600           // H2*W2

typedef __attribute__((ext_vector_type(8))) short short8;
typedef __attribute__((ext_vector_type(4))) float floatx4;

__device__ inline ushort f2b(float x) {
  uint u = __float_as_uint(x);
  return (ushort)((u + 0x7fffu + ((u >> 16) & 1u)) >> 16);
}
__device__ inline float b2f(ushort u) {
  return __uint_as_float(((uint)u) << 16);
}

// ===================== coords: x,y, scatter idx, counts (both cams) ========
__global__ __launch_bounds__(256) void coords_kernel(
    const float* __restrict__ rots, const float* __restrict__ fxs,
    const float* __restrict__ cxs,
    float* __restrict__ xarr, float* __restrict__ yarr,
    int* __restrict__ idxarr, float* __restrict__ cnt)
{
  int jz = blockIdx.y;
  int j = jz ? 3 : 0;
  int s = blockIdx.x * 256 + threadIdx.x;      // 0..51199, s = h*400 + w
  int h = s / 400;
  int w = s - h * 400;
  float fx = fxs[j], cx = cxs[j];
  const float* R = rots + j * 9;
  float cr = R[3];        // rots[1][0]
  float sr = -R[0];       // -rots[0][0]
  float t = (2.0f * (float)w + 1.0f - cx) / fx;      // tan(ang)
  float inv = 1.0f / sqrtf(1.0f + t * t);            // cos(ang)
  float ca = (cr + sr * t) * inv;                    // cr*cos + sr*sin
  float sa = (cr * t - sr) * inv;                    // -sr*cos + cr*sin
  float rad = ((float)h * (1.0f / 127.0f)) * 90.50966799187808f;
  float x = 64.0f + rad * ca;
  float y = 64.0f - rad * sa;
  xarr[jz * MS + s] = x;
  yarr[jz * MS + s] = y;
  int xi = (int)fminf(fmaxf(rintf(x), 0.0f), 127.0f);
  int yi = (int)fminf(fmaxf(rintf(y), 0.0f), 127.0f);
  int pix = yi * 128 + xi;
  idxarr[jz * MS + s] = pix;
  atomicAdd(&cnt[jz * PIX + pix], 1.0f);
}

// ===================== prefix scan over pixel counts (per cam) =============
__global__ __launch_bounds__(256) void prefix_kernel(
    const float* __restrict__ cntg, int* __restrict__ offsetsg)
{
  const float* cnt = cntg + blockIdx.x * PIX;
  int* offsets = offsetsg + blockIdx.x * PIX;
  __shared__ int sh[256];
  int t = threadIdx.x;
  int base = t * 64;
  const float4* cp = (const float4*)(cnt + base);
  int sum = 0;
#pragma unroll
  for (int i = 0; i < 16; ++i) {
    float4 v = cp[i];
    sum += (int)v.x + (int)v.y + (int)v.z + (int)v.w;
  }
  sh[t] = sum;
  __syncthreads();
  for (int d = 1; d < 256; d <<= 1) {
    int v = (t >= d) ? sh[t - d] : 0;
    __syncthreads();
    sh[t] += v;
    __syncthreads();
  }
  int run = sh[t] - sum;   // exclusive prefix for this thread's chunk
  int4* op = (int4*)(offsets + base);
#pragma unroll
  for (int i = 0; i < 16; ++i) {
    float4 v = cp[i];
    int a0 = (int)v.x, a1 = (int)v.y, a2 = (int)v.z, a3 = (int)v.w;
    int4 o;
    o.x = run; o.y = run + a0; o.z = run + a0 + a1; o.w = run + a0 + a1 + a2;
    op[i] = o;
    run += a0 + a1 + a2 + a3;
  }
}

// ===================== fill sorted sample lists (both cams) ================
__global__ __launch_bounds__(256) void fill_kernel(
    const int* __restrict__ idxarr, const int* __restrict__ offsets,
    int* __restrict__ cursor, int* __restrict__ order, int* __restrict__ pixs)
{
  int jz = blockIdx.y;
  int s = blockIdx.x * 256 + threadIdx.x;
  int pix = idxarr[jz * MS + s];
  int pos = offsets[jz * PIX + pix] + atomicAdd(&cursor[jz * PIX + pix], 1);
  // store the attention-output row index m = w*128 + h  (s = h*400 + w)
  order[jz * MS + pos] = (s % 400) * 128 + (s / 400);
  pixs[jz * MS + pos] = pix;
}

// ===================== transpose: fp32 [256][PIX] -> bf16 [PIX][256] =======
__global__ __launch_bounds__(256) void transpose_kernel(
    const float* __restrict__ src, ushort* __restrict__ dst)
{
  __shared__ float tile[64][65];   // [p_local][c_local]
  int p0 = blockIdx.x * 64;
  int c0 = blockIdx.y * 64;
  int t = threadIdx.x;
  int pr = (t & 15) * 4;           // p offset
  int cr = t >> 4;                 // c row 0..15
#pragma unroll
  for (int q = 0; q < 4; ++q) {
    int c = cr + q * 16;
    float4 v = *(const float4*)(src + (size_t)(c0 + c) * PIX + p0 + pr);
    tile[pr + 0][c] = v.x;
    tile[pr + 1][c] = v.y;
    tile[pr + 2][c] = v.z;
    tile[pr + 3][c] = v.w;
  }
  __syncthreads();
  int p = t >> 2;
  int ch = (t & 3) * 16;
  ushort tmp[16];
#pragma unroll
  for (int i = 0; i < 16; ++i) tmp[i] = f2b(tile[p][ch + i]);
  ushort* d = dst + (size_t)(p0 + p) * 256 + c0 + ch;
  *(uint4*)(d) = *(uint4*)tmp;
  *(uint4*)(d + 8) = *(uint4*)(tmp + 8);
}

// ===================== f32 -> bf16 bulk convert (float4-wide) ==============
__global__ __launch_bounds__(256) void f2b_kernel(
    const float* __restrict__ in, ushort* __restrict__ out)
{
  int t = blockIdx.x * 256 + threadIdx.x;
  float4 v = ((const float4*)in)[t];
  ushort4 o;
  o.x = f2b(v.x); o.y = f2b(v.y); o.z = f2b(v.z); o.w = f2b(v.w);
  ((ushort4*)out)[t] = o;
}

// ===================== fused bilinear sample + Q projection ================
// aT[p][256] bf16 -> (LDS feat tile) -> qh[(w*128+h)*256+f] bf16
#define LFP 264   // LDS feat row stride in halfs (528B: 16B-aligned)
__global__ __launch_bounds__(256) void sampleproj_kernel(
    const ushort* __restrict__ aT, const float* __restrict__ xarr,
    const float* __restrict__ yarr, const ushort* __restrict__ Wh,
    const float* __restrict__ bias, ushort* __restrict__ qh)
{
  __shared__ ushort lf[64 * LFP];
  int s0 = blockIdx.x * 64;
  int tid = threadIdx.x;
  int lane = tid & 63;
  int wave = tid >> 6;
  int col = lane & 15, quad = lane >> 4;
  int c0 = lane * 4;

  // gather phase: each wave computes 16 samples (all 256 channels)
#pragma unroll 4
  for (int i = 0; i < 16; ++i) {
    int sl = wave * 16 + i;
    int s = s0 + sl;
    float x = fminf(fmaxf(xarr[s], 0.0f), 127.0f);
    float y = fminf(fmaxf(yarr[s], 0.0f), 127.0f);
    float x0f = floorf(x), y0f = floorf(y);
    int x0 = (int)x0f, y0 = (int)y0f;
    int x1 = min(x0 + 1, 127), y1 = min(y0 + 1, 127);
    float wx = x - x0f, wy = y - y0f;
    float w00 = (1.0f - wx) * (1.0f - wy);
    float w01 = wx * (1.0f - wy);
    float w10 = (1.0f - wx) * wy;
    float w11 = wx * wy;
    ushort4 v00 = *(const ushort4*)(aT + (size_t)(y0 * 128 + x0) * 256 + c0);
    ushort4 v01 = *(const ushort4*)(aT + (size_t)(y0 * 128 + x1) * 256 + c0);
    ushort4 v10 = *(const ushort4*)(aT + (size_t)(y1 * 128 + x0) * 256 + c0);
    ushort4 v11 = *(const ushort4*)(aT + (size_t)(y1 * 128 + x1) * 256 + c0);
    ushort4 o;
    o.x = f2b(w00 * b2f(v00.x) + w01 * b2f(v01.x) + w10 * b2f(v10.x) + w11 * b2f(v11.x));
    o.y = f2b(w00 * b2f(v00.y) + w01 * b2f(v01.y) + w10 * b2f(v10.y) + w11 * b2f(v11.y));
    o.z = f2b(w00 * b2f(v00.z) + w01 * b2f(v01.z) + w10 * b2f(v10.z) + w11 * b2f(v11.z));
    o.w = f2b(w00 * b2f(v00.w) + w01 * b2f(v01.w) + w10 * b2f(v10.w) + w11 * b2f(v11.w));
    *(ushort4*)&lf[sl * LFP + c0] = o;
  }
  __syncthreads();

  // projection phase
  int fw = wave * 64;
  floatx4 acc[4][4];
#pragma unroll
  for (int i = 0; i < 4; ++i)
#pragma unroll
    for (int jx = 0; jx < 4; ++jx) acc[i][jx] = (floatx4){0.f, 0.f, 0.f, 0.f};

  for (int kb = 0; kb < 256; kb += 32) {
    short8 aop[4], bop[4];
#pragma unroll
    for (int tf = 0; tf < 4; ++tf)
      aop[tf] = *(const short8*)(Wh + (size_t)(fw + tf * 16 + col) * 256 + kb + quad * 8);
#pragma unroll
    for (int ts = 0; ts < 4; ++ts)
      bop[ts] = *(const short8*)&lf[(ts * 16 + col) * LFP + kb + quad * 8];
#pragma unroll
    for (int ts = 0; ts < 4; ++ts)
#pragma unroll
      for (int tf = 0; tf < 4; ++tf)
        acc[ts][tf] = __builtin_amdgcn_mfma_f32_16x16x32_bf16(
            aop[tf], bop[ts], acc[ts][tf], 0, 0, 0);
  }
  // D: col -> s, row=quad*4+r -> f
#pragma unroll
  for (int ts = 0; ts < 4; ++ts) {
    int s = s0 + ts * 16 + col;
    int h = s / 400;
    int w = s - h * 400;
    size_t obase = (size_t)(w * 128 + h) * 256;
#pragma unroll
    for (int tf = 0; tf < 4; ++tf) {
      int f = fw + tf * 16 + quad * 4;
      float4 bv = *(const float4*)(bias + h * 256 + f);
      ushort4 ov;
      ov.x = f2b(acc[ts][tf][0] + bv.x);
      ov.y = f2b(acc[ts][tf][1] + bv.y);
      ov.z = f2b(acc[ts][tf][2] + bv.z);
      ov.w = f2b(acc[ts][tf][3] + bv.w);
      *(ushort4*)(qh + obase + f) = ov;
    }
  }
}

// ===================== fused b-transpose + K+V projection ==================
// bsrc fp32 [256][25600] -> LDS bf16 [m][c] -> kh/vh[(w2*64+h2)*256+f]
#define LBP 264
__global__ __launch_bounds__(256) void projKV_kernel(
    const float* __restrict__ bsrc,
    const ushort* __restrict__ WhK, const ushort* __restrict__ WhV,
    const float* __restrict__ biasK, const float* __restrict__ biasV,
    ushort* __restrict__ kh, ushort* __restrict__ vh)
{
  __shared__ ushort lb[64 * LBP];
  int m0 = blockIdx.x * 64;
  int tid = threadIdx.x;
  int lane = tid & 63;
  int wave = tid >> 6;
  int col = lane & 15, quad = lane >> 4;
  int fw = wave * 64;

  // stage: fp32 [c][m] tile -> LDS bf16 [m][c]
  int pr = (tid & 15) * 4;
  int cb = tid >> 4;               // 0..15
#pragma unroll 4
  for (int q = 0; q < 16; ++q) {
    int c = cb + q * 16;
    float4 v = *(const float4*)(bsrc + (size_t)c * MB + m0 + pr);
    lb[(pr + 0) * LBP + c] = f2b(v.x);
    lb[(pr + 1) * LBP + c] = f2b(v.y);
    lb[(pr + 2) * LBP + c] = f2b(v.z);
    lb[(pr + 3) * LBP + c] = f2b(v.w);
  }
  __syncthreads();

  floatx4 accK[4][4], accV[4][4];
#pragma unroll
  for (int i = 0; i < 4; ++i)
#pragma unroll
    for (int jx = 0; jx < 4; ++jx) {
      accK[i][jx] = (floatx4){0.f, 0.f, 0.f, 0.f};
      accV[i][jx] = (floatx4){0.f, 0.f, 0.f, 0.f};
    }

  for (int kb = 0; kb < 256; kb += 32) {
    short8 bop[4];
#pragma unroll
    for (int ts = 0; ts < 4; ++ts)
      bop[ts] = *(const short8*)&lb[(ts * 16 + col) * LBP + kb + quad * 8];
    short8 aK[4];
#pragma unroll
    for (int tf = 0; tf < 4; ++tf)
      aK[tf] = *(const short8*)(WhK + (size_t)(fw + tf * 16 + col) * 256 + kb + quad * 8);
#pragma unroll
    for (int ts = 0; ts < 4; ++ts)
#pragma unroll
      for (int tf = 0; tf < 4; ++tf)
        accK[ts][tf] = __builtin_amdgcn_mfma_f32_16x16x32_bf16(
            aK[tf], bop[ts], accK[ts][tf], 0, 0, 0);
    short8 aV[4];
#pragma unroll
    for (int tf = 0; tf < 4; ++tf)
      aV[tf] = *(const short8*)(WhV + (size_t)(fw + tf * 16 + col) * 256 + kb + quad * 8);
#pragma unroll
    for (int ts = 0; ts < 4; ++ts)
#pragma unroll
      for (int tf = 0; tf < 4; ++tf)
        accV[ts][tf] = __builtin_amdgcn_mfma_f32_16x16x32_bf16(
            aV[tf], bop[ts], accV[ts][tf], 0, 0, 0);
  }
#pragma unroll
  for (int ts = 0; ts < 4; ++ts) {
    int m = m0 + ts * 16 + col;
    int h = m / 400;            // h2
    int w = m - h * 400;        // w2
    size_t obase = (size_t)(w * 64 + h) * 256;
#pragma unroll
    for (int tf = 0; tf < 4; ++tf) {
      int f = fw + tf * 16 + quad * 4;
      float4 bvK = *(const float4*)(biasK + h * 256 + f);
      ushort4 ovK;
      ovK.x = f2b(accK[ts][tf][0] + bvK.x);
      ovK.y = f2b(accK[ts][tf][1] + bvK.y);
      ovK.z = f2b(accK[ts][tf][2] + bvK.z);
      ovK.w = f2b(accK[ts][tf][3] + bvK.w);
      *(ushort4*)(kh + obase + f) = ovK;
      float4 bvV = *(const float4*)(biasV + h * 256 + f);
      ushort4 ovV;
      ovV.x = f2b(accV[ts][tf][0] + bvV.x);
      ovV.y = f2b(accV[ts][tf][1] + bvV.y);
      ovV.z = f2b(accV[ts][tf][2] + bvV.z);
      ovV.w = f2b(accV[ts][tf][3] + bvV.w);
      *(ushort4*)(vh + obase + f) = ovV;
    }
  }
}

// ===================== MFMA flash attention (barrier-free, per-wave LDS) ===
#define VP 72
#define PP 72
__global__ __launch_bounds__(256) void attn_mfma_kernel(
    const ushort* __restrict__ qh, const ushort* __restrict__ kh,
    const ushort* __restrict__ vh, ushort* __restrict__ obuf)
{
  __shared__ ushort lV[4][32 * VP];
  __shared__ ushort lP[4][16 * PP];
  int b = blockIdx.x;
  int wave = threadIdx.x >> 6;
  int lane = threadIdx.x & 63;
  int head = blockIdx.y * 4 + wave;
  int col = lane & 15, quad = lane >> 4;
  ushort* Vw = lV[wave];
  ushort* Pw = lP[wave];

  // K fragments direct from global (qt-invariant)
  short8 bk0 = *(const short8*)(kh + ((size_t)(b * 64 +  0 + col)) * 256 + head * 32 + quad * 8);
  short8 bk1 = *(const short8*)(kh + ((size_t)(b * 64 + 16 + col)) * 256 + head * 32 + quad * 8);
  short8 bk2 = *(const short8*)(kh + ((size_t)(b * 64 + 32 + col)) * 256 + head * 32 + quad * 8);
  short8 bk3 = *(const short8*)(kh + ((size_t)(b * 64 + 48 + col)) * 256 + head * 32 + quad * 8);

  // V staged to LDS (d-major transpose), then hoist the 4 qt-invariant fragments
  {
    const ushort* vsrc = vh + ((size_t)(b * 64 + lane)) * 256 + head * 32;
    ushort vr[32];
    *(uint4*)(vr) = *(const uint4*)(vsrc);
    *(uint4*)(vr + 8) = *(const uint4*)(vsrc + 8);
    *(uint4*)(vr + 16) = *(const uint4*)(vsrc + 16);
    *(uint4*)(vr + 24) = *(const uint4*)(vsrc + 24);
#pragma unroll
    for (int d = 0; d < 32; ++d) Vw[d * VP + lane] = vr[d];
  }
  short8 vA0 = *(const short8*)(Vw + (col) * VP + 0 * 32 + quad * 8);
  short8 vB0 = *(const short8*)(Vw + (16 + col) * VP + 0 * 32 + quad * 8);
  short8 vA1 = *(const short8*)(Vw + (col) * VP + 1 * 32 + quad * 8);
  short8 vB1 = *(const short8*)(Vw + (16 + col) * VP + 1 * 32 + quad * 8);

  const float scl = 0.17677669529663687f;   // 1/sqrt(32)
  for (int qt = 0; qt < 8; ++qt) {
    short8 aq = *(const short8*)(qh +
        ((size_t)(b * 128 + qt * 16 + col)) * 256 + head * 32 + quad * 8);
    floatx4 s0 = {0.f,0.f,0.f,0.f}, s1 = s0, s2 = s0, s3 = s0;
    s0 = __builtin_amdgcn_mfma_f32_16x16x32_bf16(aq, bk0, s0, 0, 0, 0);
    s1 = __builtin_amdgcn_mfma_f32_16x16x32_bf16(aq, bk1, s1, 0, 0, 0);
    s2 = __builtin_amdgcn_mfma_f32_16x16x32_bf16(aq, bk2, s2, 0, 0, 0);
    s3 = __builtin_amdgcn_mfma_f32_16x16x32_bf16(aq, bk3, s3, 0, 0, 0);
    float e[4][4], mr[4], sm[4];
#pragma unroll
    for (int r = 0; r < 4; ++r) {
      float v0 = s0[r] * scl, v1 = s1[r] * scl;
      float v2 = s2[r] * scl, v3 = s3[r] * scl;
      e[0][r] = v0; e[1][r] = v1; e[2][r] = v2; e[3][r] = v3;
      mr[r] = fmaxf(fmaxf(v0, v1), fmaxf(v2, v3));
    }
#pragma unroll
    for (int mask = 1; mask <= 8; mask <<= 1)
#pragma unroll
      for (int r = 0; r < 4; ++r)
        mr[r] = fmaxf(mr[r], __shfl_xor(mr[r], mask, 64));
#pragma unroll
    for (int r = 0; r < 4; ++r) {
      float acc = 0.f;
#pragma unroll
      for (int t = 0; t < 4; ++t) {
        float ev = __expf(e[t][r] - mr[r]);
        e[t][r] = ev;
        acc += ev;
      }
      sm[r] = acc;
    }
#pragma unroll
    for (int mask = 1; mask <= 8; mask <<= 1)
#pragma unroll
      for (int r = 0; r < 4; ++r)
        sm[r] += __shfl_xor(sm[r], mask, 64);
#pragma unroll
    for (int t = 0; t < 4; ++t)
#pragma unroll
      for (int r = 0; r < 4; ++r)
        Pw[(quad * 4 + r) * PP + t * 16 + col] = f2b(e[t][r]);
    // per-wave in-order DS pipe: reads below see the writes above
    floatx4 o0 = {0.f,0.f,0.f,0.f}, o1 = o0;
    {
      short8 ap0 = *(const short8*)(Pw + col * PP + 0 * 32 + quad * 8);
      o0 = __builtin_amdgcn_mfma_f32_16x16x32_bf16(ap0, vA0, o0, 0, 0, 0);
      o1 = __builtin_amdgcn_mfma_f32_16x16x32_bf16(ap0, vB0, o1, 0, 0, 0);
      short8 ap1 = *(const short8*)(Pw + col * PP + 1 * 32 + quad * 8);
      o0 = __builtin_amdgcn_mfma_f32_16x16x32_bf16(ap1, vA1, o0, 0, 0, 0);
      o1 = __builtin_amdgcn_mfma_f32_16x16x32_bf16(ap1, vB1, o1, 0, 0, 0);
    }
#pragma unroll
    for (int r = 0; r < 4; ++r) {
      float iv = 1.0f / sm[r];
      size_t row = (size_t)(b * 128 + qt * 16 + quad * 4 + r) * 256 + head * 32;
      obuf[row + col] = f2b(o0[r] * iv);
      obuf[row + 16 + col] = f2b(o1[r] * iv);
    }
  }
}

// ===================== merged positional GEMMs (z = q/k/v) =================
__global__ __launch_bounds__(256) void gemmN3_kernel(
    const float* __restrict__ pos_a, const float* __restrict__ pos_b,
    const float* __restrict__ weff, const float* __restrict__ beff,
    float* __restrict__ qpos, float* __restrict__ kpos, float* __restrict__ vpos)
{
  int z = blockIdx.z;
  if (z > 0 && blockIdx.x > 0) return;
  const float* A = (z == 0) ? pos_a : pos_b;
  const float* Wt = weff + (size_t)z * 65536;
  const float* biasf = beff + z * 256;
  float* Cout = (z == 0) ? qpos : ((z == 1) ? kpos : vpos);
  __shared__ float As[64][17];
  __shared__ float Ws[16][65];
  int m0 = blockIdx.x * 64;
  int n0 = blockIdx.y * 64;
  int tid = threadIdx.x;
  int tx = tid & 15, ty = tid >> 4;
  float acc[4][4] = {};
  for (int k0 = 0; k0 < 256; k0 += 16) {
    {
      int m = tid >> 2;
      int kq = (tid & 3) << 2;
      float4 v = *(const float4*)(A + (size_t)(m0 + m) * 256 + k0 + kq);
      As[m][kq + 0] = v.x; As[m][kq + 1] = v.y;
      As[m][kq + 2] = v.z; As[m][kq + 3] = v.w;
    }
    {
      int f = tid >> 2;
      int kq = (tid & 3) << 2;
      float4 v = *(const float4*)(Wt + (size_t)(n0 + f) * 256 + k0 + kq);
      Ws[kq + 0][f] = v.x; Ws[kq + 1][f] = v.y;
      Ws[kq + 2][f] = v.z; Ws[kq + 3][f] = v.w;
    }
    __syncthreads();
#pragma unroll
    for (int kk = 0; kk < 16; ++kk) {
      float a[4], b[4];
#pragma unroll
      for (int i = 0; i < 4; ++i) a[i] = As[ty * 4 + i][kk];
#pragma unroll
      for (int jj = 0; jj < 4; ++jj) b[jj] = Ws[kk][tx * 4 + jj];
#pragma unroll
      for (int i = 0; i < 4; ++i)
#pragma unroll
        for (int jj = 0; jj < 4; ++jj) acc[i][jj] += a[i] * b[jj];
    }
    __syncthreads();
  }
#pragma unroll
  for (int i = 0; i < 4; ++i) {
    int m = m0 + ty * 4 + i;
    int f = n0 + tx * 4;
    float4 bv = *(const float4*)(biasf + f);
    float4 ov;
    ov.x = acc[i][0] + bv.x; ov.y = acc[i][1] + bv.y;
    ov.z = acc[i][2] + bv.z; ov.w = acc[i][3] + bv.w;
    *(float4*)(Cout + (size_t)m * 256 + f) = ov;
  }
}

// ===================== GEMM A[m][k] * B[k][n] + bf16 copy ==================
__global__ __launch_bounds__(256) void gemm_ab_kernel(
    const float* __restrict__ in_w, const float* __restrict__ Wq,
    const float* __restrict__ Wk, const float* __restrict__ Wv,
    float* __restrict__ weff, ushort* __restrict__ weffh)
{
  int z = blockIdx.z;
  const float* A = in_w + (size_t)z * 65536;
  const float* B = (z == 0) ? Wq : ((z == 1) ? Wk : Wv);
  float* C = weff + (size_t)z * 65536;
  ushort* Ch = weffh + (size_t)z * 65536;
  __shared__ float As[64][17];
  __shared__ float Bs[16][64];
  int m0 = blockIdx.x * 64;
  int n0 = blockIdx.y * 64;
  int tid = threadIdx.x;
  int tx = tid & 15, ty = tid >> 4;
  float acc[4][4] = {};
  for (int k0 = 0; k0 < 256; k0 += 16) {
    {
      int m = tid >> 2;
      int kq = (tid & 3) << 2;
      float4 v = *(const float4*)(A + (size_t)(m0 + m) * 256 + k0 + kq);
      As[m][kq + 0] = v.x; As[m][kq + 1] = v.y;
      As[m][kq + 2] = v.z; As[m][kq + 3] = v.w;
    }
    {
      int k = tid >> 4;
      int nq = (tid & 15) << 2;
      float4 v = *(const float4*)(B + (size_t)(k0 + k) * 256 + n0 + nq);
      *(float4*)(&Bs[k][nq]) = v;
    }
    __syncthreads();
#pragma unroll
    for (int kk = 0; kk < 16; ++kk) {
      float a[4], b[4];
#pragma unroll
      for (int i = 0; i < 4; ++i) a[i] = As[ty * 4 + i][kk];
#pragma unroll
      for (int jj = 0; jj < 4; ++jj) b[jj] = Bs[kk][tx * 4 + jj];
#pragma unroll
      for (int i = 0; i < 4; ++i)
#pragma unroll
        for (int jj = 0; jj < 4; ++jj) acc[i][jj] += a[i] * b[jj];
    }
    __syncthreads();
  }
#pragma unroll
  for (int i = 0; i < 4; ++i) {
    int m = m0 + ty * 4 + i;
    *(float4*)(C + (size_t)m * 256 + n0 + tx * 4) = *(float4*)&acc[i][0];
    ushort4 hv;
    hv.x = f2b(acc[i][0]); hv.y = f2b(acc[i][1]);
    hv.z = f2b(acc[i][2]); hv.w = f2b(acc[i][3]);
    *(ushort4*)(Ch + (size_t)m * 256 + n0 + tx * 4) = hv;
  }
}

// ===================== effective biases =====================
__global__ void beff_kernel(const float* __restrict__ in_w, const float* __restrict__ in_b,
                            const float* __restrict__ bq, const float* __restrict__ bk,
                            const float* __restrict__ bv, float* __restrict__ beff)
{
  int z = blockIdx.x;
  int f = threadIdx.x;
  const float* bsrc = (z == 0) ? bq : ((z == 1) ? bk : bv);
  const float* row = in_w + (size_t)(z * 256 + f) * 256;
  float acc = in_b[z * 256 + f];
  for (int e = 0; e < 256; ++e) acc += row[e] * bsrc[e];
  beff[z * 256 + f] = acc;
}

// ===================== segmented reduction over sorted samples =============
#define CH 64
__global__ __launch_bounds__(256) void segred_kernel(
    const ushort* __restrict__ obuf, const int* __restrict__ order,
    const int* __restrict__ pixs, float* __restrict__ osum)
{
  __shared__ int lm[CH];
  __shared__ int lp[CH + 2];
  int s0 = blockIdx.x * CH;
  int t = threadIdx.x;
  if (t < CH) {
    lm[t] = order[s0 + t];
    lp[t + 1] = pixs[s0 + t];
  } else if (t == CH) {
    lp[0] = (s0 > 0) ? pixs[s0 - 1] : -1;
  } else if (t == CH + 1) {
    lp[CH + 1] = (s0 + CH < MS) ? pixs[s0 + CH] : -2;
  }
  __syncthreads();
  int c = t;
  float va[8];
#pragma unroll
  for (int k = 0; k < 8; ++k)
    va[k] = b2f(obuf[(size_t)lm[k] * 256 + c]);
  float acc = 0.0f;
  int runBegin = 0;
#pragma unroll
  for (int i = 0; i < CH; ++i) {
    float v = va[i & 7];
    if (i + 8 < CH) va[i & 7] = b2f(obuf[(size_t)lm[i + 8] * 256 + c]);
    acc += v;
    int p = lp[i + 1];
    bool last = (i == CH - 1);
    if (last || p != lp[i + 2]) {
      bool pBeg = (runBegin == 0) && (p == lp[0]);
      bool pEnd = last && (p == lp[CH + 1]);
      float* dst = osum + (size_t)p * 256 + c;
      if (pBeg || pEnd) atomicAdd(dst, acc);
      else *dst = acc;
      acc = 0.0f;
      runBegin = i + 1;
    }
  }
}

// ===================== fused out-proj + residual update (+aT emit) =========
__global__ __launch_bounds__(256) void outproj_update_kernel(
    const float* __restrict__ osum, const ushort* __restrict__ out_wh,
    const float* __restrict__ asrc, float* __restrict__ adst,
    const float* __restrict__ cnt, const float* __restrict__ out_b,
    float scale, ushort* __restrict__ aTout, int writeAT)
{
  int p0 = blockIdx.x * 64;
  int lane = threadIdx.x & 63;
  int wave = threadIdx.x >> 6;
  int col = lane & 15, quad = lane >> 4;
  int fw = wave * 64;
  floatx4 acc[4][4];
#pragma unroll
  for (int i = 0; i < 4; ++i)
#pragma unroll
    for (int jx = 0; jx < 4; ++jx) acc[i][jx] = (floatx4){0.f, 0.f, 0.f, 0.f};

  for (int kb = 0; kb < 256; kb += 32) {
    short8 aop[4], bop[4];
#pragma unroll
    for (int tf = 0; tf < 4; ++tf)
      aop[tf] = *(const short8*)(out_wh +
          (size_t)(fw + tf * 16 + col) * 256 + kb + quad * 8);
#pragma unroll
    for (int ts = 0; ts < 4; ++ts) {
      const float* brow = osum + (size_t)(p0 + ts * 16 + col) * 256 + kb + quad * 8;
      float4 f0 = *(const float4*)brow;
      float4 f1 = *(const float4*)(brow + 4);
      short8 bv;
      bv[0] = (short)f2b(f0.x); bv[1] = (short)f2b(f0.y);
      bv[2] = (short)f2b(f0.z); bv[3] = (short)f2b(f0.w);
      bv[4] = (short)f2b(f1.x); bv[5] = (short)f2b(f1.y);
      bv[6] = (short)f2b(f1.z); bv[7] = (short)f2b(f1.w);
      bop[ts] = bv;
    }
#pragma unroll
    for (int ts = 0; ts < 4; ++ts)
#pragma unroll
      for (int tf = 0; tf < 4; ++tf)
        acc[ts][tf] = __builtin_amdgcn_mfma_f32_16x16x32_bf16(
            aop[tf], bop[ts], acc[ts][tf], 0, 0, 0);
  }
  // epilogue: acc[ts][tf][r] = enh(f=fw+tf*16+quad*4+r, p=p0+ts*16+col)
#pragma unroll
  for (int ts = 0; ts < 4; ++ts) {
    int p = p0 + ts * 16 + col;
    float cn = cnt[p];
    float rs = scale / fmaxf(cn, 1.0f);
#pragma unroll
    for (int tf = 0; tf < 4; ++tf) {
      int f = fw + tf * 16 + quad * 4;
      float4 ob = *(const float4*)(out_b + f);
      float r0 = asrc[(size_t)(f + 0) * PIX + p] + (acc[ts][tf][0] + cn * ob.x) * rs;
      float r1 = asrc[(size_t)(f + 1) * PIX + p] + (acc[ts][tf][1] + cn * ob.y) * rs;
      float r2 = asrc[(size_t)(f + 2) * PIX + p] + (acc[ts][tf][2] + cn * ob.z) * rs;
      float r3 = asrc[(size_t)(f + 3) * PIX + p] + (acc[ts][tf][3] + cn * ob.w) * rs;
      adst[(size_t)(f + 0) * PIX + p] = r0;
      adst[(size_t)(f + 1) * PIX + p] = r1;
      adst[(size_t)(f + 2) * PIX + p] = r2;
      adst[(size_t)(f + 3) * PIX + p] = r3;
      if (writeAT) {
        ushort4 hv;
        hv.x = f2b(r0); hv.y = f2b(r1); hv.z = f2b(r2); hv.w = f2b(r3);
        *(ushort4*)(aTout + (size_t)p * 256 + f) = hv;
      }
    }
  }
}

// ===================== launch =====================
extern "C" void kernel_launch(void* const* d_in, const int* in_sizes, int n_in,
                              void* d_out, int out_size, void* d_ws, size_t ws_size,
                              hipStream_t stream) {
  const float* list_a = (const float*)d_in[0];
  const float* list_b = (const float*)d_in[1];
  const float* rots   = (const float*)d_in[3];
  const float* fxs    = (const float*)d_in[5];
  const float* cxs    = (const float*)d_in[6];
  const float* pos_a  = (const float*)d_in[7];
  const float* pos_b  = (const float*)d_in[8];
  const float* Wq     = (const float*)d_in[9];
  const float* bq     = (const float*)d_in[10];
  const float* Wk     = (const float*)d_in[11];
  const float* bk     = (const float*)d_in[12];
  const float* Wv     = (const float*)d_in[13];
  const float* bv     = (const float*)d_in[14];
  const float* in_w   = (const float*)d_in[15];
  const float* in_b   = (const float*)d_in[16];
  const float* out_w  = (const float*)d_in[17];
  const float* out_b  = (const float*)d_in[18];

  float* ws      = (float*)d_ws;
  float* weff    = ws;                          // 196608 f
  float* beff    = weff + 196608;               // 768 f
  float* qpos    = beff + 768;                  // 32768 f
  float* kpos    = qpos + 32768;                // 16384 f
  float* vpos    = kpos + 16384;                // 16384 f
  float* a_cur   = vpos + 16384;                // 4194304 f
  float* xarr    = a_cur + 4194304;             // 2*51200 f
  float* yarr    = xarr + 102400;               // 2*51200 f
  int*   idxarr  = (int*)(yarr + 102400);       // 2*51200
  int*   offs    = idxarr + 102400;             // 2*16384
  int*   order   = offs + 32768;                // 2*51200
  int*   pixs    = order + 102400;              // 2*51200
  float* cnt     = (float*)(pixs + 102400);     // 2*16384 f   <- zero region A
  int*   cursor  = (int*)(cnt + 32768);         // 2*16384     <- zero region A
  float* osum    = (float*)(cursor + 32768);    // 4194304 f   <- zero region B
  ushort* weffh  = (ushort*)(osum + 4194304);   // 196608 h
  ushort* out_wh = weffh + 196608;              // 65536 h
  ushort* obufh  = out_wh + 65536;              // 13107200 h
  ushort* qh     = obufh + 13107200;            // 13107200 h
  ushort* kh     = qh + 13107200;               // 6553600 h
  ushort* vh     = kh + 6553600;                // 6553600 h
  ushort* aT     = vh + 6553600;                // 4194304 h

  // prologue: weights, biases, positional tables, both cams' index prep
  gemm_ab_kernel<<<dim3(4, 4, 3), 256, 0, stream>>>(in_w, Wq, Wk, Wv, weff, weffh);
  beff_kernel<<<3, 256, 0, stream>>>(in_w, in_b, bq, bk, bv, beff);
  f2b_kernel<<<64, 256, 0, stream>>>(out_w, out_wh);
  gemmN3_kernel<<<dim3(2, 4, 3), 256, 0, stream>>>(pos_a, pos_b, weff, beff,
                                                   qpos, kpos, vpos);
  hipMemsetAsync(cnt, 0, (size_t)(32768 + 32768) * sizeof(float), stream); // cnt+cursor both cams
  coords_kernel<<<dim3(200, 2), 256, 0, stream>>>(rots, fxs, cxs, xarr, yarr, idxarr, cnt);
  prefix_kernel<<<2, 256, 0, stream>>>(cnt, offs);
  fill_kernel<<<dim3(200, 2), 256, 0, stream>>>(idxarr, offs, cursor, order, pixs);

  for (int jj = 0; jj < 2; ++jj) {
    int j = jj ? 3 : 0;
    const float* asrc = jj ? a_cur : list_a;
    hipMemsetAsync(osum, 0, (size_t)4194304 * sizeof(float), stream);
    if (jj == 0)
      transpose_kernel<<<dim3(256, 4), 256, 0, stream>>>(list_a, aT);
    // fused bilinear sample + Q projection
    sampleproj_kernel<<<800, 256, 0, stream>>>(aT, xarr + jj * MS, yarr + jj * MS,
                                               weffh, qpos, qh);
    // fused b-transpose + K+V projections
    projKV_kernel<<<400, 256, 0, stream>>>(list_b + (size_t)j * 6553600,
                                           weffh + 65536, weffh + 131072,
                                           kpos, vpos, kh, vh);
    // MFMA flash attention (barrier-free)
    attn_mfma_kernel<<<dim3(400, 2), 256, 0, stream>>>(qh, kh, vh, obufh);
    // segmented reduction of O over sorted samples -> osum fp32
    segred_kernel<<<800, 256, 0, stream>>>(obufh, order + jj * MS, pixs + jj * MS, osum);
    // fused out-proj + residual update (+ emit next iter's aT)
    outproj_update_kernel<<<256, 256, 0, stream>>>(osum, out_wh, asrc,
                                                   jj ? (float*)d_out : a_cur,
                                                   cnt + jj * PIX, out_b,
                                                   jj ? 2.0f : 1.0f,
                                                   aT, jj == 0 ? 1 : 0);
  }
}

// Round 5
// 557.941 us; speedup vs baseline: 1.2909x; 1.0049x over previous
//
#include <hip/hip_runtime.h>

// Problem constants
// a: (256,128,128)  b: (4,256,64,400)  E=256 NH=8 DH=32  B=400 Lq=128 Lk=64
#define PIX 16384          // 128*128
#define MS 51200           // H1*W2 samples
#define MB 25600           // H2*W2

typedef __attribute__((ext_vector_type(8))) short short8;
typedef __attribute__((ext_vector_type(4))) float floatx4;

__device__ inline ushort f2b(float x) {
  uint u = __float_as_uint(x);
  return (ushort)((u + 0x7fffu + ((u >> 16) & 1u)) >> 16);
}
__device__ inline float b2f(ushort u) {
  return __uint_as_float(((uint)u) << 16);
}

// ===================== coords: x,y, scatter idx, counts (both cams) ========
__global__ __launch_bounds__(256) void coords_kernel(
    const float* __restrict__ rots, const float* __restrict__ fxs,
    const float* __restrict__ cxs,
    float* __restrict__ xarr, float* __restrict__ yarr,
    int* __restrict__ idxarr, float* __restrict__ cnt)
{
  int jz = blockIdx.y;
  int j = jz ? 3 : 0;
  int s = blockIdx.x * 256 + threadIdx.x;      // 0..51199, s = h*400 + w
  int h = s / 400;
  int w = s - h * 400;
  float fx = fxs[j], cx = cxs[j];
  const float* R = rots + j * 9;
  float cr = R[3];        // rots[1][0]
  float sr = -R[0];       // -rots[0][0]
  float t = (2.0f * (float)w + 1.0f - cx) / fx;      // tan(ang)
  float inv = 1.0f / sqrtf(1.0f + t * t);            // cos(ang)
  float ca = (cr + sr * t) * inv;                    // cr*cos + sr*sin
  float sa = (cr * t - sr) * inv;                    // -sr*cos + cr*sin
  float rad = ((float)h * (1.0f / 127.0f)) * 90.50966799187808f;
  float x = 64.0f + rad * ca;
  float y = 64.0f - rad * sa;
  xarr[jz * MS + s] = x;
  yarr[jz * MS + s] = y;
  int xi = (int)fminf(fmaxf(rintf(x), 0.0f), 127.0f);
  int yi = (int)fminf(fmaxf(rintf(y), 0.0f), 127.0f);
  int pix = yi * 128 + xi;
  idxarr[jz * MS + s] = pix;
  atomicAdd(&cnt[jz * PIX + pix], 1.0f);
}

// ===================== prefix scan over pixel counts (per cam) =============
__global__ __launch_bounds__(256) void prefix_kernel(
    const float* __restrict__ cntg, int* __restrict__ offsetsg)
{
  const float* cnt = cntg + blockIdx.x * PIX;
  int* offsets = offsetsg + blockIdx.x * PIX;
  __shared__ int sh[256];
  int t = threadIdx.x;
  int base = t * 64;
  const float4* cp = (const float4*)(cnt + base);
  int sum = 0;
#pragma unroll
  for (int i = 0; i < 16; ++i) {
    float4 v = cp[i];
    sum += (int)v.x + (int)v.y + (int)v.z + (int)v.w;
  }
  sh[t] = sum;
  __syncthreads();
  for (int d = 1; d < 256; d <<= 1) {
    int v = (t >= d) ? sh[t - d] : 0;
    __syncthreads();
    sh[t] += v;
    __syncthreads();
  }
  int run = sh[t] - sum;   // exclusive prefix for this thread's chunk
  int4* op = (int4*)(offsets + base);
#pragma unroll
  for (int i = 0; i < 16; ++i) {
    float4 v = cp[i];
    int a0 = (int)v.x, a1 = (int)v.y, a2 = (int)v.z, a3 = (int)v.w;
    int4 o;
    o.x = run; o.y = run + a0; o.z = run + a0 + a1; o.w = run + a0 + a1 + a2;
    op[i] = o;
    run += a0 + a1 + a2 + a3;
  }
}

// ===================== fill sorted sample lists (both cams) ================
__global__ __launch_bounds__(256) void fill_kernel(
    const int* __restrict__ idxarr, const int* __restrict__ offsets,
    int* __restrict__ cursor, int* __restrict__ order, int* __restrict__ pixs)
{
  int jz = blockIdx.y;
  int s = blockIdx.x * 256 + threadIdx.x;
  int pix = idxarr[jz * MS + s];
  int pos = offsets[jz * PIX + pix] + atomicAdd(&cursor[jz * PIX + pix], 1);
  // store the attention-output row index m = w*128 + h  (s = h*400 + w)
  order[jz * MS + pos] = (s % 400) * 128 + (s / 400);
  pixs[jz * MS + pos] = pix;
}

// ===================== transpose: fp32 [256][PIX] -> bf16 [PIX][256] =======
__global__ __launch_bounds__(256) void transpose_kernel(
    const float* __restrict__ src, ushort* __restrict__ dst)
{
  __shared__ float tile[64][65];   // [p_local][c_local]
  int p0 = blockIdx.x * 64;
  int c0 = blockIdx.y * 64;
  int t = threadIdx.x;
  int pr = (t & 15) * 4;           // p offset
  int cr = t >> 4;                 // c row 0..15
#pragma unroll
  for (int q = 0; q < 4; ++q) {
    int c = cr + q * 16;
    float4 v = *(const float4*)(src + (size_t)(c0 + c) * PIX + p0 + pr);
    tile[pr + 0][c] = v.x;
    tile[pr + 1][c] = v.y;
    tile[pr + 2][c] = v.z;
    tile[pr + 3][c] = v.w;
  }
  __syncthreads();
  int p = t >> 2;
  int ch = (t & 3) * 16;
  ushort tmp[16];
#pragma unroll
  for (int i = 0; i < 16; ++i) tmp[i] = f2b(tile[p][ch + i]);
  ushort* d = dst + (size_t)(p0 + p) * 256 + c0 + ch;
  *(uint4*)(d) = *(uint4*)tmp;
  *(uint4*)(d + 8) = *(uint4*)(tmp + 8);
}

// ===================== misc: f2b(out_w) + beff =====================
__global__ __launch_bounds__(256) void misc_kernel(
    const float* __restrict__ out_w, ushort* __restrict__ out_wh,
    const float* __restrict__ in_w, const float* __restrict__ in_b,
    const float* __restrict__ bq, const float* __restrict__ bk,
    const float* __restrict__ bv, float* __restrict__ beff)
{
  if (blockIdx.x < 64) {
    int t = blockIdx.x * 256 + threadIdx.x;
    float4 v = ((const float4*)out_w)[t];
    ushort4 o;
    o.x = f2b(v.x); o.y = f2b(v.y); o.z = f2b(v.z); o.w = f2b(v.w);
    ((ushort4*)out_wh)[t] = o;
  } else {
    int z = blockIdx.x - 64;
    int f = threadIdx.x;
    const float* bsrc = (z == 0) ? bq : ((z == 1) ? bk : bv);
    const float* row = in_w + (size_t)(z * 256 + f) * 256;
    float acc = in_b[z * 256 + f];
    for (int e = 0; e < 256; ++e) acc += row[e] * bsrc[e];
    beff[z * 256 + f] = acc;
  }
}

// ===================== merged Q-proj (sample) + K/V-proj ===================
#define LFP 264   // LDS feat row stride in halfs
__device__ __forceinline__ void sampleproj_body(
    ushort* lf, int bx,
    const ushort* __restrict__ aT, const float* __restrict__ xarr,
    const float* __restrict__ yarr, const ushort* __restrict__ Wh,
    const float* __restrict__ bias, ushort* __restrict__ qh)
{
  int s0 = bx * 64;
  int tid = threadIdx.x;
  int lane = tid & 63;
  int wave = tid >> 6;
  int col = lane & 15, quad = lane >> 4;
  int c0 = lane * 4;

  // gather phase: each wave computes 16 samples (all 256 channels)
#pragma unroll 4
  for (int i = 0; i < 16; ++i) {
    int sl = wave * 16 + i;
    int s = s0 + sl;
    float x = fminf(fmaxf(xarr[s], 0.0f), 127.0f);
    float y = fminf(fmaxf(yarr[s], 0.0f), 127.0f);
    float x0f = floorf(x), y0f = floorf(y);
    int x0 = (int)x0f, y0 = (int)y0f;
    int x1 = min(x0 + 1, 127), y1 = min(y0 + 1, 127);
    float wx = x - x0f, wy = y - y0f;
    float w00 = (1.0f - wx) * (1.0f - wy);
    float w01 = wx * (1.0f - wy);
    float w10 = (1.0f - wx) * wy;
    float w11 = wx * wy;
    ushort4 v00 = *(const ushort4*)(aT + (size_t)(y0 * 128 + x0) * 256 + c0);
    ushort4 v01 = *(const ushort4*)(aT + (size_t)(y0 * 128 + x1) * 256 + c0);
    ushort4 v10 = *(const ushort4*)(aT + (size_t)(y1 * 128 + x0) * 256 + c0);
    ushort4 v11 = *(const ushort4*)(aT + (size_t)(y1 * 128 + x1) * 256 + c0);
    ushort4 o;
    o.x = f2b(w00 * b2f(v00.x) + w01 * b2f(v01.x) + w10 * b2f(v10.x) + w11 * b2f(v11.x));
    o.y = f2b(w00 * b2f(v00.y) + w01 * b2f(v01.y) + w10 * b2f(v10.y) + w11 * b2f(v11.y));
    o.z = f2b(w00 * b2f(v00.z) + w01 * b2f(v01.z) + w10 * b2f(v10.z) + w11 * b2f(v11.z));
    o.w = f2b(w00 * b2f(v00.w) + w01 * b2f(v01.w) + w10 * b2f(v10.w) + w11 * b2f(v11.w));
    *(ushort4*)&lf[sl * LFP + c0] = o;
  }
  __syncthreads();

  int fw = wave * 64;
  floatx4 acc[4][4];
#pragma unroll
  for (int i = 0; i < 4; ++i)
#pragma unroll
    for (int jx = 0; jx < 4; ++jx) acc[i][jx] = (floatx4){0.f, 0.f, 0.f, 0.f};

  for (int kb = 0; kb < 256; kb += 32) {
    short8 aop[4], bop[4];
#pragma unroll
    for (int tf = 0; tf < 4; ++tf)
      aop[tf] = *(const short8*)(Wh + (size_t)(fw + tf * 16 + col) * 256 + kb + quad * 8);
#pragma unroll
    for (int ts = 0; ts < 4; ++ts)
      bop[ts] = *(const short8*)&lf[(ts * 16 + col) * LFP + kb + quad * 8];
#pragma unroll
    for (int ts = 0; ts < 4; ++ts)
#pragma unroll
      for (int tf = 0; tf < 4; ++tf)
        acc[ts][tf] = __builtin_amdgcn_mfma_f32_16x16x32_bf16(
            aop[tf], bop[ts], acc[ts][tf], 0, 0, 0);
  }
#pragma unroll
  for (int ts = 0; ts < 4; ++ts) {
    int s = s0 + ts * 16 + col;
    int h = s / 400;
    int w = s - h * 400;
    size_t obase = (size_t)(w * 128 + h) * 256;
#pragma unroll
    for (int tf = 0; tf < 4; ++tf) {
      int f = fw + tf * 16 + quad * 4;
      float4 bv = *(const float4*)(bias + h * 256 + f);
      ushort4 ov;
      ov.x = f2b(acc[ts][tf][0] + bv.x);
      ov.y = f2b(acc[ts][tf][1] + bv.y);
      ov.z = f2b(acc[ts][tf][2] + bv.z);
      ov.w = f2b(acc[ts][tf][3] + bv.w);
      *(ushort4*)(qh + obase + f) = ov;
    }
  }
}

__device__ __forceinline__ void projKV_body(
    ushort* lb, int bx,
    const float* __restrict__ bsrc,
    const ushort* __restrict__ WhK, const ushort* __restrict__ WhV,
    const float* __restrict__ biasK, const float* __restrict__ biasV,
    ushort* __restrict__ kh, ushort* __restrict__ vh)
{
  int m0 = bx * 64;
  int tid = threadIdx.x;
  int lane = tid & 63;
  int wave = tid >> 6;
  int col = lane & 15, quad = lane >> 4;
  int fw = wave * 64;

  // stage: fp32 [c][m] tile -> LDS bf16 [m][c]
  int pr = (tid & 15) * 4;
  int cb = tid >> 4;               // 0..15
#pragma unroll 4
  for (int q = 0; q < 16; ++q) {
    int c = cb + q * 16;
    float4 v = *(const float4*)(bsrc + (size_t)c * MB + m0 + pr);
    lb[(pr + 0) * LFP + c] = f2b(v.x);
    lb[(pr + 1) * LFP + c] = f2b(v.y);
    lb[(pr + 2) * LFP + c] = f2b(v.z);
    lb[(pr + 3) * LFP + c] = f2b(v.w);
  }
  __syncthreads();

  floatx4 accK[4][4], accV[4][4];
#pragma unroll
  for (int i = 0; i < 4; ++i)
#pragma unroll
    for (int jx = 0; jx < 4; ++jx) {
      accK[i][jx] = (floatx4){0.f, 0.f, 0.f, 0.f};
      accV[i][jx] = (floatx4){0.f, 0.f, 0.f, 0.f};
    }

  for (int kb = 0; kb < 256; kb += 32) {
    short8 bop[4];
#pragma unroll
    for (int ts = 0; ts < 4; ++ts)
      bop[ts] = *(const short8*)&lb[(ts * 16 + col) * LFP + kb + quad * 8];
    short8 aK[4];
#pragma unroll
    for (int tf = 0; tf < 4; ++tf)
      aK[tf] = *(const short8*)(WhK + (size_t)(fw + tf * 16 + col) * 256 + kb + quad * 8);
#pragma unroll
    for (int ts = 0; ts < 4; ++ts)
#pragma unroll
      for (int tf = 0; tf < 4; ++tf)
        accK[ts][tf] = __builtin_amdgcn_mfma_f32_16x16x32_bf16(
            aK[tf], bop[ts], accK[ts][tf], 0, 0, 0);
    short8 aV[4];
#pragma unroll
    for (int tf = 0; tf < 4; ++tf)
      aV[tf] = *(const short8*)(WhV + (size_t)(fw + tf * 16 + col) * 256 + kb + quad * 8);
#pragma unroll
    for (int ts = 0; ts < 4; ++ts)
#pragma unroll
      for (int tf = 0; tf < 4; ++tf)
        accV[ts][tf] = __builtin_amdgcn_mfma_f32_16x16x32_bf16(
            aV[tf], bop[ts], accV[ts][tf], 0, 0, 0);
  }
#pragma unroll
  for (int ts = 0; ts < 4; ++ts) {
    int m = m0 + ts * 16 + col;
    int h = m / 400;            // h2
    int w = m - h * 400;        // w2
    size_t obase = (size_t)(w * 64 + h) * 256;
#pragma unroll
    for (int tf = 0; tf < 4; ++tf) {
      int f = fw + tf * 16 + quad * 4;
      float4 bvK = *(const float4*)(biasK + h * 256 + f);
      ushort4 ovK;
      ovK.x = f2b(accK[ts][tf][0] + bvK.x);
      ovK.y = f2b(accK[ts][tf][1] + bvK.y);
      ovK.z = f2b(accK[ts][tf][2] + bvK.z);
      ovK.w = f2b(accK[ts][tf][3] + bvK.w);
      *(ushort4*)(kh + obase + f) = ovK;
      float4 bvV = *(const float4*)(biasV + h * 256 + f);
      ushort4 ovV;
      ovV.x = f2b(accV[ts][tf][0] + bvV.x);
      ovV.y = f2b(accV[ts][tf][1] + bvV.y);
      ovV.z = f2b(accV[ts][tf][2] + bvV.z);
      ovV.w = f2b(accV[ts][tf][3] + bvV.w);
      *(ushort4*)(vh + obase + f) = ovV;
    }
  }
}

__global__ __launch_bounds__(256) void proj_kernel(
    const ushort* __restrict__ aT, const float* __restrict__ xarr,
    const float* __restrict__ yarr, const ushort* __restrict__ weffh,
    const float* __restrict__ qpos, ushort* __restrict__ qh,
    const float* __restrict__ bsrc,
    const float* __restrict__ kpos, const float* __restrict__ vpos,
    ushort* __restrict__ kh, ushort* __restrict__ vh)
{
  __shared__ ushort lf[64 * LFP];
  if (blockIdx.x < 800)
    sampleproj_body(lf, blockIdx.x, aT, xarr, yarr, weffh, qpos, qh);
  else
    projKV_body(lf, blockIdx.x - 800, bsrc, weffh + 65536, weffh + 131072,
                kpos, vpos, kh, vh);
}

// ===================== MFMA flash attention (qt-split, vector stores) ======
#define VP 72
#define PP 72
__global__ __launch_bounds__(256) void attn_mfma_kernel(
    const ushort* __restrict__ qh, const ushort* __restrict__ kh,
    const ushort* __restrict__ vh, ushort* __restrict__ obuf)
{
  __shared__ ushort lV[4][32 * VP];
  __shared__ ushort lP[4][16 * PP];
  int b = blockIdx.x;
  int hg = blockIdx.y & 1;          // head group
  int qb = blockIdx.y >> 1;         // qt half
  int wave = threadIdx.x >> 6;
  int lane = threadIdx.x & 63;
  int head = hg * 4 + wave;
  int col = lane & 15, quad = lane >> 4;
  ushort* Vw = lV[wave];
  ushort* Pw = lP[wave];

  // K fragments direct from global (qt-invariant)
  short8 bk0 = *(const short8*)(kh + ((size_t)(b * 64 +  0 + col)) * 256 + head * 32 + quad * 8);
  short8 bk1 = *(const short8*)(kh + ((size_t)(b * 64 + 16 + col)) * 256 + head * 32 + quad * 8);
  short8 bk2 = *(const short8*)(kh + ((size_t)(b * 64 + 32 + col)) * 256 + head * 32 + quad * 8);
  short8 bk3 = *(const short8*)(kh + ((size_t)(b * 64 + 48 + col)) * 256 + head * 32 + quad * 8);

  // V staged to LDS (d-major transpose), then hoist the 4 qt-invariant fragments
  {
    const ushort* vsrc = vh + ((size_t)(b * 64 + lane)) * 256 + head * 32;
    ushort vr[32];
    *(uint4*)(vr) = *(const uint4*)(vsrc);
    *(uint4*)(vr + 8) = *(const uint4*)(vsrc + 8);
    *(uint4*)(vr + 16) = *(const uint4*)(vsrc + 16);
    *(uint4*)(vr + 24) = *(const uint4*)(vsrc + 24);
#pragma unroll
    for (int d = 0; d < 32; ++d) Vw[d * VP + lane] = vr[d];
  }
  short8 vA0 = *(const short8*)(Vw + (col) * VP + 0 * 32 + quad * 8);
  short8 vB0 = *(const short8*)(Vw + (16 + col) * VP + 0 * 32 + quad * 8);
  short8 vA1 = *(const short8*)(Vw + (col) * VP + 1 * 32 + quad * 8);
  short8 vB1 = *(const short8*)(Vw + (16 + col) * VP + 1 * 32 + quad * 8);

  const float scl = 0.17677669529663687f;   // 1/sqrt(32)
  for (int qt = qb * 4; qt < qb * 4 + 4; ++qt) {
    short8 aq = *(const short8*)(qh +
        ((size_t)(b * 128 + qt * 16 + col)) * 256 + head * 32 + quad * 8);
    floatx4 s0 = {0.f,0.f,0.f,0.f}, s1 = s0, s2 = s0, s3 = s0;
    s0 = __builtin_amdgcn_mfma_f32_16x16x32_bf16(aq, bk0, s0, 0, 0, 0);
    s1 = __builtin_amdgcn_mfma_f32_16x16x32_bf16(aq, bk1, s1, 0, 0, 0);
    s2 = __builtin_amdgcn_mfma_f32_16x16x32_bf16(aq, bk2, s2, 0, 0, 0);
    s3 = __builtin_amdgcn_mfma_f32_16x16x32_bf16(aq, bk3, s3, 0, 0, 0);
    float e[4][4], mr[4], sm[4];
#pragma unroll
    for (int r = 0; r < 4; ++r) {
      float v0 = s0[r] * scl, v1 = s1[r] * scl;
      float v2 = s2[r] * scl, v3 = s3[r] * scl;
      e[0][r] = v0; e[1][r] = v1; e[2][r] = v2; e[3][r] = v3;
      mr[r] = fmaxf(fmaxf(v0, v1), fmaxf(v2, v3));
    }
#pragma unroll
    for (int mask = 1; mask <= 8; mask <<= 1)
#pragma unroll
      for (int r = 0; r < 4; ++r)
        mr[r] = fmaxf(mr[r], __shfl_xor(mr[r], mask, 64));
#pragma unroll
    for (int r = 0; r < 4; ++r) {
      float acc = 0.f;
#pragma unroll
      for (int t = 0; t < 4; ++t) {
        float ev = __expf(e[t][r] - mr[r]);
        e[t][r] = ev;
        acc += ev;
      }
      sm[r] = acc;
    }
#pragma unroll
    for (int mask = 1; mask <= 8; mask <<= 1)
#pragma unroll
      for (int r = 0; r < 4; ++r)
        sm[r] += __shfl_xor(sm[r], mask, 64);
#pragma unroll
    for (int t = 0; t < 4; ++t)
#pragma unroll
      for (int r = 0; r < 4; ++r)
        Pw[(quad * 4 + r) * PP + t * 16 + col] = f2b(e[t][r]);
    // per-wave in-order DS pipe: reads below see the writes above
    floatx4 o0 = {0.f,0.f,0.f,0.f}, o1 = o0;
    {
      short8 ap0 = *(const short8*)(Pw + col * PP + 0 * 32 + quad * 8);
      o0 = __builtin_amdgcn_mfma_f32_16x16x32_bf16(ap0, vA0, o0, 0, 0, 0);
      o1 = __builtin_amdgcn_mfma_f32_16x16x32_bf16(ap0, vB0, o1, 0, 0, 0);
      short8 ap1 = *(const short8*)(Pw + col * PP + 1 * 32 + quad * 8);
      o0 = __builtin_amdgcn_mfma_f32_16x16x32_bf16(ap1, vA1, o0, 0, 0, 0);
      o1 = __builtin_amdgcn_mfma_f32_16x16x32_bf16(ap1, vB1, o1, 0, 0, 0);
    }
    // repack O through Pw (P already consumed), one 16B store per lane
#pragma unroll
    for (int r = 0; r < 4; ++r) {
      float iv = 1.0f / sm[r];
      Pw[(quad * 4 + r) * PP + col] = f2b(o0[r] * iv);
      Pw[(quad * 4 + r) * PP + 16 + col] = f2b(o1[r] * iv);
    }
    int orow = lane >> 2, ochunk = lane & 3;
    uint4 ov = *(const uint4*)(Pw + orow * PP + ochunk * 8);
    *(uint4*)(obuf + (size_t)(b * 128 + qt * 16 + orow) * 256 + head * 32 + ochunk * 8) = ov;
  }
}

// ===================== merged positional GEMMs (z = q/k/v) =================
__global__ __launch_bounds__(256) void gemmN3_kernel(
    const float* __restrict__ pos_a, const float* __restrict__ pos_b,
    const float* __restrict__ weff, const float* __restrict__ beff,
    float* __restrict__ qpos, float* __restrict__ kpos, float* __restrict__ vpos)
{
  int z = blockIdx.z;
  if (z > 0 && blockIdx.x > 0) return;
  const float* A = (z == 0) ? pos_a : pos_b;
  const float* Wt = weff + (size_t)z * 65536;
  const float* biasf = beff + z * 256;
  float* Cout = (z == 0) ? qpos : ((z == 1) ? kpos : vpos);
  __shared__ float As[64][17];
  __shared__ float Ws[16][65];
  int m0 = blockIdx.x * 64;
  int n0 = blockIdx.y * 64;
  int tid = threadIdx.x;
  int tx = tid & 15, ty = tid >> 4;
  float acc[4][4] = {};
  for (int k0 = 0; k0 < 256; k0 += 16) {
    {
      int m = tid >> 2;
      int kq = (tid & 3) << 2;
      float4 v = *(const float4*)(A + (size_t)(m0 + m) * 256 + k0 + kq);
      As[m][kq + 0] = v.x; As[m][kq + 1] = v.y;
      As[m][kq + 2] = v.z; As[m][kq + 3] = v.w;
    }
    {
      int f = tid >> 2;
      int kq = (tid & 3) << 2;
      float4 v = *(const float4*)(Wt + (size_t)(n0 + f) * 256 + k0 + kq);
      Ws[kq + 0][f] = v.x; Ws[kq + 1][f] = v.y;
      Ws[kq + 2][f] = v.z; Ws[kq + 3][f] = v.w;
    }
    __syncthreads();
#pragma unroll
    for (int kk = 0; kk < 16; ++kk) {
      float a[4], b[4];
#pragma unroll
      for (int i = 0; i < 4; ++i) a[i] = As[ty * 4 + i][kk];
#pragma unroll
      for (int jj = 0; jj < 4; ++jj) b[jj] = Ws[kk][tx * 4 + jj];
#pragma unroll
      for (int i = 0; i < 4; ++i)
#pragma unroll
        for (int jj = 0; jj < 4; ++jj) acc[i][jj] += a[i] * b[jj];
    }
    __syncthreads();
  }
#pragma unroll
  for (int i = 0; i < 4; ++i) {
    int m = m0 + ty * 4 + i;
    int f = n0 + tx * 4;
    float4 bv = *(const float4*)(biasf + f);
    float4 ov;
    ov.x = acc[i][0] + bv.x; ov.y = acc[i][1] + bv.y;
    ov.z = acc[i][2] + bv.z; ov.w = acc[i][3] + bv.w;
    *(float4*)(Cout + (size_t)m * 256 + f) = ov;
  }
}

// ===================== GEMM A[m][k] * B[k][n] + bf16 copy ==================
__global__ __launch_bounds__(256) void gemm_ab_kernel(
    const float* __restrict__ in_w, const float* __restrict__ Wq,
    const float* __restrict__ Wk, const float* __restrict__ Wv,
    float* __restrict__ weff, ushort* __restrict__ weffh)
{
  int z = blockIdx.z;
  const float* A = in_w + (size_t)z * 65536;
  const float* B = (z == 0) ? Wq : ((z == 1) ? Wk : Wv);
  float* C = weff + (size_t)z * 65536;
  ushort* Ch = weffh + (size_t)z * 65536;
  __shared__ float As[64][17];
  __shared__ float Bs[16][64];
  int m0 = blockIdx.x * 64;
  int n0 = blockIdx.y * 64;
  int tid = threadIdx.x;
  int tx = tid & 15, ty = tid >> 4;
  float acc[4][4] = {};
  for (int k0 = 0; k0 < 256; k0 += 16) {
    {
      int m = tid >> 2;
      int kq = (tid & 3) << 2;
      float4 v = *(const float4*)(A + (size_t)(m0 + m) * 256 + k0 + kq);
      As[m][kq + 0] = v.x; As[m][kq + 1] = v.y;
      As[m][kq + 2] = v.z; As[m][kq + 3] = v.w;
    }
    {
      int k = tid >> 4;
      int nq = (tid & 15) << 2;
      float4 v = *(const float4*)(B + (size_t)(k0 + k) * 256 + n0 + nq);
      *(float4*)(&Bs[k][nq]) = v;
    }
    __syncthreads();
#pragma unroll
    for (int kk = 0; kk < 16; ++kk) {
      float a[4], b[4];
#pragma unroll
      for (int i = 0; i < 4; ++i) a[i] = As[ty * 4 + i][kk];
#pragma unroll
      for (int jj = 0; jj < 4; ++jj) b[jj] = Bs[kk][tx * 4 + jj];
#pragma unroll
      for (int i = 0; i < 4; ++i)
#pragma unroll
        for (int jj = 0; jj < 4; ++jj) acc[i][jj] += a[i] * b[jj];
    }
    __syncthreads();
  }
#pragma unroll
  for (int i = 0; i < 4; ++i) {
    int m = m0 + ty * 4 + i;
    *(float4*)(C + (size_t)m * 256 + n0 + tx * 4) = *(float4*)&acc[i][0];
    ushort4 hv;
    hv.x = f2b(acc[i][0]); hv.y = f2b(acc[i][1]);
    hv.z = f2b(acc[i][2]); hv.w = f2b(acc[i][3]);
    *(ushort4*)(Ch + (size_t)m * 256 + n0 + tx * 4) = hv;
  }
}

// ===================== segmented reduction over sorted samples =============
#define CH 64
__global__ __launch_bounds__(256) void segred_kernel(
    const ushort* __restrict__ obuf, const int* __restrict__ order,
    const int* __restrict__ pixs, float* __restrict__ osum)
{
  __shared__ int lm[CH];
  __shared__ int lp[CH + 2];
  int s0 = blockIdx.x * CH;
  int t = threadIdx.x;
  if (t < CH) {
    lm[t] = order[s0 + t];
    lp[t + 1] = pixs[s0 + t];
  } else if (t == CH) {
    lp[0] = (s0 > 0) ? pixs[s0 - 1] : -1;
  } else if (t == CH + 1) {
    lp[CH + 1] = (s0 + CH < MS) ? pixs[s0 + CH] : -2;
  }
  __syncthreads();
  int c = t;
  float va[8];
#pragma unroll
  for (int k = 0; k < 8; ++k)
    va[k] = b2f(obuf[(size_t)lm[k] * 256 + c]);
  float acc = 0.0f;
  int runBegin = 0;
#pragma unroll
  for (int i = 0; i < CH; ++i) {
    float v = va[i & 7];
    if (i + 8 < CH) va[i & 7] = b2f(obuf[(size_t)lm[i + 8] * 256 + c]);
    acc += v;
    int p = lp[i + 1];
    bool last = (i == CH - 1);
    if (last || p != lp[i + 2]) {
      bool pBeg = (runBegin == 0) && (p == lp[0]);
      bool pEnd = last && (p == lp[CH + 1]);
      float* dst = osum + (size_t)p * 256 + c;
      if (pBeg || pEnd) atomicAdd(dst, acc);
      else *dst = acc;
      acc = 0.0f;
      runBegin = i + 1;
    }
  }
}

// ===================== fused out-proj + residual update (+aT emit) =========
__global__ __launch_bounds__(256) void outproj_update_kernel(
    const float* __restrict__ osum, const ushort* __restrict__ out_wh,
    const float* __restrict__ asrc, float* __restrict__ adst,
    const float* __restrict__ cnt, const float* __restrict__ out_b,
    float scale, ushort* __restrict__ aTout, int writeAT)
{
  int p0 = blockIdx.x * 32;
  int lane = threadIdx.x & 63;
  int wave = threadIdx.x >> 6;
  int col = lane & 15, quad = lane >> 4;
  int fw = wave * 64;
  floatx4 acc[2][4];
#pragma unroll
  for (int i = 0; i < 2; ++i)
#pragma unroll
    for (int jx = 0; jx < 4; ++jx) acc[i][jx] = (floatx4){0.f, 0.f, 0.f, 0.f};

  for (int kb = 0; kb < 256; kb += 32) {
    short8 aop[4], bop[2];
#pragma unroll
    for (int tf = 0; tf < 4; ++tf)
      aop[tf] = *(const short8*)(out_wh +
          (size_t)(fw + tf * 16 + col) * 256 + kb + quad * 8);
#pragma unroll
    for (int ts = 0; ts < 2; ++ts) {
      const float* brow = osum + (size_t)(p0 + ts * 16 + col) * 256 + kb + quad * 8;
      float4 f0 = *(const float4*)brow;
      float4 f1 = *(const float4*)(brow + 4);
      short8 bv;
      bv[0] = (short)f2b(f0.x); bv[1] = (short)f2b(f0.y);
      bv[2] = (short)f2b(f0.z); bv[3] = (short)f2b(f0.w);
      bv[4] = (short)f2b(f1.x); bv[5] = (short)f2b(f1.y);
      bv[6] = (short)f2b(f1.z); bv[7] = (short)f2b(f1.w);
      bop[ts] = bv;
    }
#pragma unroll
    for (int ts = 0; ts < 2; ++ts)
#pragma unroll
      for (int tf = 0; tf < 4; ++tf)
        acc[ts][tf] = __builtin_amdgcn_mfma_f32_16x16x32_bf16(
            aop[tf], bop[ts], acc[ts][tf], 0, 0, 0);
  }
  // epilogue: acc[ts][tf][r] = enh(f=fw+tf*16+quad*4+r, p=p0+ts*16+col)
#pragma unroll
  for (int ts = 0; ts < 2; ++ts) {
    int p = p0 + ts * 16 + col;
    float cn = cnt[p];
    float rs = scale / fmaxf(cn, 1.0f);
#pragma unroll
    for (int tf = 0; tf < 4; ++tf) {
      int f = fw + tf * 16 + quad * 4;
      float4 ob = *(const float4*)(out_b + f);
      float r0 = asrc[(size_t)(f + 0) * PIX + p] + (acc[ts][tf][0] + cn * ob.x) * rs;
      float r1 = asrc[(size_t)(f + 1) * PIX + p] + (acc[ts][tf][1] + cn * ob.y) * rs;
      float r2 = asrc[(size_t)(f + 2) * PIX + p] + (acc[ts][tf][2] + cn * ob.z) * rs;
      float r3 = asrc[(size_t)(f + 3) * PIX + p] + (acc[ts][tf][3] + cn * ob.w) * rs;
      adst[(size_t)(f + 0) * PIX + p] = r0;
      adst[(size_t)(f + 1) * PIX + p] = r1;
      adst[(size_t)(f + 2) * PIX + p] = r2;
      adst[(size_t)(f + 3) * PIX + p] = r3;
      if (writeAT) {
        ushort4 hv;
        hv.x = f2b(r0); hv.y = f2b(r1); hv.z = f2b(r2); hv.w = f2b(r3);
        *(ushort4*)(aTout + (size_t)p * 256 + f) = hv;
      }
    }
  }
}

// ===================== launch =====================
extern "C" void kernel_launch(void* const* d_in, const int* in_sizes, int n_in,
                              void* d_out, int out_size, void* d_ws, size_t ws_size,
                              hipStream_t stream) {
  const float* list_a = (const float*)d_in[0];
  const float* list_b = (const float*)d_in[1];
  const float* rots   = (const float*)d_in[3];
  const float* fxs    = (const float*)d_in[5];
  const float* cxs    = (const float*)d_in[6];
  const float* pos_a  = (const float*)d_in[7];
  const float* pos_b  = (const float*)d_in[8];
  const float* Wq     = (const float*)d_in[9];
  const float* bq     = (const float*)d_in[10];
  const float* Wk     = (const float*)d_in[11];
  const float* bk     = (const float*)d_in[12];
  const float* Wv     = (const float*)d_in[13];
  const float* bv     = (const float*)d_in[14];
  const float* in_w   = (const float*)d_in[15];
  const float* in_b   = (const float*)d_in[16];
  const float* out_w  = (const float*)d_in[17];
  const float* out_b  = (const float*)d_in[18];

  float* ws      = (float*)d_ws;
  float* weff    = ws;                          // 196608 f
  float* beff    = weff + 196608;               // 768 f
  float* qpos    = beff + 768;                  // 32768 f
  float* kpos    = qpos + 32768;                // 16384 f
  float* vpos    = kpos + 16384;                // 16384 f
  float* a_cur   = vpos + 16384;                // 4194304 f
  float* xarr    = a_cur + 4194304;             // 2*51200 f
  float* yarr    = xarr + 102400;               // 2*51200 f
  int*   idxarr  = (int*)(yarr + 102400);       // 2*51200
  int*   offs    = idxarr + 102400;             // 2*16384
  int*   order   = offs + 32768;                // 2*51200
  int*   pixs    = order + 102400;              // 2*51200
  float* cnt     = (float*)(pixs + 102400);     // 2*16384 f   <- zero region A
  int*   cursor  = (int*)(cnt + 32768);         // 2*16384     <- zero region A
  float* osum    = (float*)(cursor + 32768);    // 4194304 f   <- zero region B
  ushort* weffh  = (ushort*)(osum + 4194304);   // 196608 h
  ushort* out_wh = weffh + 196608;              // 65536 h
  ushort* obufh  = out_wh + 65536;              // 13107200 h
  ushort* qh     = obufh + 13107200;            // 13107200 h
  ushort* kh     = qh + 13107200;               // 6553600 h
  ushort* vh     = kh + 6553600;                // 6553600 h
  ushort* aT     = vh + 6553600;                // 4194304 h

  // prologue: weights, biases, positional tables, both cams' index prep
  gemm_ab_kernel<<<dim3(4, 4, 3), 256, 0, stream>>>(in_w, Wq, Wk, Wv, weff, weffh);
  misc_kernel<<<67, 256, 0, stream>>>(out_w, out_wh, in_w, in_b, bq, bk, bv, beff);
  gemmN3_kernel<<<dim3(2, 4, 3), 256, 0, stream>>>(pos_a, pos_b, weff, beff,
                                                   qpos, kpos, vpos);
  hipMemsetAsync(cnt, 0, (size_t)(32768 + 32768) * sizeof(float), stream); // cnt+cursor both cams
  coords_kernel<<<dim3(200, 2), 256, 0, stream>>>(rots, fxs, cxs, xarr, yarr, idxarr, cnt);
  prefix_kernel<<<2, 256, 0, stream>>>(cnt, offs);
  fill_kernel<<<dim3(200, 2), 256, 0, stream>>>(idxarr, offs, cursor, order, pixs);

  for (int jj = 0; jj < 2; ++jj) {
    int j = jj ? 3 : 0;
    const float* asrc = jj ? a_cur : list_a;
    hipMemsetAsync(osum, 0, (size_t)4194304 * sizeof(float), stream);
    if (jj == 0)
      transpose_kernel<<<dim3(256, 4), 256, 0, stream>>>(list_a, aT);
    // merged Q-proj (bilinear sample) + K/V-proj, one dispatch
    proj_kernel<<<1200, 256, 0, stream>>>(aT, xarr + jj * MS, yarr + jj * MS,
                                          weffh, qpos, qh,
                                          list_b + (size_t)j * 6553600,
                                          kpos, vpos, kh, vh);
    // MFMA flash attention (qt-split, vectorized stores)
    attn_mfma_kernel<<<dim3(400, 4), 256, 0, stream>>>(qh, kh, vh, obufh);
    // segmented reduction of O over sorted samples -> osum fp32
    segred_kernel<<<800, 256, 0, stream>>>(obufh, order + jj * MS, pixs + jj * MS, osum);
    // fused out-proj + residual update (+ emit next iter's aT)
    outproj_update_kernel<<<512, 256, 0, stream>>>(osum, out_wh, asrc,
                                                   jj ? (float*)d_out : a_cur,
                                                   cnt + jj * PIX, out_b,
                                                   jj ? 2.0f : 1.0f,
                                                   aT, jj == 0 ? 1 : 0);
  }
}

// Round 6
// 545.136 us; speedup vs baseline: 1.3213x; 1.0235x over previous
//
#include <hip/hip_runtime.h>

// Problem constants
// a: (256,128,128)  b: (4,256,64,400)  E=256 NH=8 DH=32  B=400 Lq=128 Lk=64
#define PIX 16384          // 128*128
#define MS 51200           // H1*W2 samples
#define MB 25600           // H2*W2

typedef __attribute__((ext_vector_type(8))) short short8;
typedef __attribute__((ext_vector_type(4))) float floatx4;

__device__ inline ushort f2b(float x) {
  uint u = __float_as_uint(x);
  return (ushort)((u + 0x7fffu + ((u >> 16) & 1u)) >> 16);
}
__device__ inline float b2f(ushort u) {
  return __uint_as_float(((uint)u) << 16);
}

// ===================== coords: x,y, scatter idx, counts (both cams) ========
__global__ __launch_bounds__(256) void coords_kernel(
    const float* __restrict__ rots, const float* __restrict__ fxs,
    const float* __restrict__ cxs,
    float* __restrict__ xarr, float* __restrict__ yarr,
    int* __restrict__ idxarr, float* __restrict__ cnt)
{
  int jz = blockIdx.y;
  int j = jz ? 3 : 0;
  int s = blockIdx.x * 256 + threadIdx.x;      // 0..51199, s = h*400 + w
  int h = s / 400;
  int w = s - h * 400;
  float fx = fxs[j], cx = cxs[j];
  const float* R = rots + j * 9;
  float cr = R[3];        // rots[1][0]
  float sr = -R[0];       // -rots[0][0]
  float t = (2.0f * (float)w + 1.0f - cx) / fx;      // tan(ang)
  float inv = 1.0f / sqrtf(1.0f + t * t);            // cos(ang)
  float ca = (cr + sr * t) * inv;                    // cr*cos + sr*sin
  float sa = (cr * t - sr) * inv;                    // -sr*cos + cr*sin
  float rad = ((float)h * (1.0f / 127.0f)) * 90.50966799187808f;
  float x = 64.0f + rad * ca;
  float y = 64.0f - rad * sa;
  xarr[jz * MS + s] = x;
  yarr[jz * MS + s] = y;
  int xi = (int)fminf(fmaxf(rintf(x), 0.0f), 127.0f);
  int yi = (int)fminf(fmaxf(rintf(y), 0.0f), 127.0f);
  int pix = yi * 128 + xi;
  idxarr[jz * MS + s] = pix;
  atomicAdd(&cnt[jz * PIX + pix], 1.0f);
}

// ===================== prefix scan over pixel counts (per cam) =============
__global__ __launch_bounds__(256) void prefix_kernel(
    const float* __restrict__ cntg, int* __restrict__ offsetsg)
{
  const float* cnt = cntg + blockIdx.x * PIX;
  int* offsets = offsetsg + blockIdx.x * PIX;
  __shared__ int sh[256];
  int t = threadIdx.x;
  int base = t * 64;
  const float4* cp = (const float4*)(cnt + base);
  int sum = 0;
#pragma unroll
  for (int i = 0; i < 16; ++i) {
    float4 v = cp[i];
    sum += (int)v.x + (int)v.y + (int)v.z + (int)v.w;
  }
  sh[t] = sum;
  __syncthreads();
  for (int d = 1; d < 256; d <<= 1) {
    int v = (t >= d) ? sh[t - d] : 0;
    __syncthreads();
    sh[t] += v;
    __syncthreads();
  }
  int run = sh[t] - sum;   // exclusive prefix for this thread's chunk
  int4* op = (int4*)(offsets + base);
#pragma unroll
  for (int i = 0; i < 16; ++i) {
    float4 v = cp[i];
    int a0 = (int)v.x, a1 = (int)v.y, a2 = (int)v.z, a3 = (int)v.w;
    int4 o;
    o.x = run; o.y = run + a0; o.z = run + a0 + a1; o.w = run + a0 + a1 + a2;
    op[i] = o;
    run += a0 + a1 + a2 + a3;
  }
}

// ===================== fill sorted sample lists (both cams) ================
__global__ __launch_bounds__(256) void fill_kernel(
    const int* __restrict__ idxarr, const int* __restrict__ offsets,
    int* __restrict__ cursor, int* __restrict__ order, int* __restrict__ pixs)
{
  int jz = blockIdx.y;
  int s = blockIdx.x * 256 + threadIdx.x;
  int pix = idxarr[jz * MS + s];
  int pos = offsets[jz * PIX + pix] + atomicAdd(&cursor[jz * PIX + pix], 1);
  // store the attention-output row index m = w*128 + h  (s = h*400 + w)
  order[jz * MS + pos] = (s % 400) * 128 + (s / 400);
  pixs[jz * MS + pos] = pix;
}

// ===================== transpose: fp32 [256][PIX] -> bf16 [PIX][256] =======
__global__ __launch_bounds__(256) void transpose_kernel(
    const float* __restrict__ src, ushort* __restrict__ dst)
{
  __shared__ float tile[64][65];   // [p_local][c_local]
  int p0 = blockIdx.x * 64;
  int c0 = blockIdx.y * 64;
  int t = threadIdx.x;
  int pr = (t & 15) * 4;           // p offset
  int cr = t >> 4;                 // c row 0..15
#pragma unroll
  for (int q = 0; q < 4; ++q) {
    int c = cr + q * 16;
    float4 v = *(const float4*)(src + (size_t)(c0 + c) * PIX + p0 + pr);
    tile[pr + 0][c] = v.x;
    tile[pr + 1][c] = v.y;
    tile[pr + 2][c] = v.z;
    tile[pr + 3][c] = v.w;
  }
  __syncthreads();
  int p = t >> 2;
  int ch = (t & 3) * 16;
  ushort tmp[16];
#pragma unroll
  for (int i = 0; i < 16; ++i) tmp[i] = f2b(tile[p][ch + i]);
  ushort* d = dst + (size_t)(p0 + p) * 256 + c0 + ch;
  *(uint4*)(d) = *(uint4*)tmp;
  *(uint4*)(d + 8) = *(uint4*)(tmp + 8);
}

// ===================== misc: f2b(out_w) + beff =====================
__global__ __launch_bounds__(256) void misc_kernel(
    const float* __restrict__ out_w, ushort* __restrict__ out_wh,
    const float* __restrict__ in_w, const float* __restrict__ in_b,
    const float* __restrict__ bq, const float* __restrict__ bk,
    const float* __restrict__ bv, float* __restrict__ beff)
{
  if (blockIdx.x < 64) {
    int t = blockIdx.x * 256 + threadIdx.x;
    float4 v = ((const float4*)out_w)[t];
    ushort4 o;
    o.x = f2b(v.x); o.y = f2b(v.y); o.z = f2b(v.z); o.w = f2b(v.w);
    ((ushort4*)out_wh)[t] = o;
  } else {
    int z = blockIdx.x - 64;
    int f = threadIdx.x;
    const float* bsrc = (z == 0) ? bq : ((z == 1) ? bk : bv);
    const float* row = in_w + (size_t)(z * 256 + f) * 256;
    float acc = in_b[z * 256 + f];
    for (int e = 0; e < 256; ++e) acc += row[e] * bsrc[e];
    beff[z * 256 + f] = acc;
  }
}

// ===================== merged Q-proj (sample) + K/V-proj ===================
#define LFP 264   // LDS feat row stride in halfs
__device__ __forceinline__ void sampleproj_body(
    ushort* lf, int bx,
    const ushort* __restrict__ aT, const float* __restrict__ xarr,
    const float* __restrict__ yarr, const ushort* __restrict__ Wh,
    const float* __restrict__ bias, ushort* __restrict__ qh)
{
  int s0 = bx * 64;
  int tid = threadIdx.x;
  int lane = tid & 63;
  int wave = tid >> 6;
  int col = lane & 15, quad = lane >> 4;
  int c0 = lane * 4;

  // gather phase: each wave computes 16 samples (all 256 channels)
#pragma unroll 4
  for (int i = 0; i < 16; ++i) {
    int sl = wave * 16 + i;
    int s = s0 + sl;
    float x = fminf(fmaxf(xarr[s], 0.0f), 127.0f);
    float y = fminf(fmaxf(yarr[s], 0.0f), 127.0f);
    float x0f = floorf(x), y0f = floorf(y);
    int x0 = (int)x0f, y0 = (int)y0f;
    int x1 = min(x0 + 1, 127), y1 = min(y0 + 1, 127);
    float wx = x - x0f, wy = y - y0f;
    float w00 = (1.0f - wx) * (1.0f - wy);
    float w01 = wx * (1.0f - wy);
    float w10 = (1.0f - wx) * wy;
    float w11 = wx * wy;
    ushort4 v00 = *(const ushort4*)(aT + (size_t)(y0 * 128 + x0) * 256 + c0);
    ushort4 v01 = *(const ushort4*)(aT + (size_t)(y0 * 128 + x1) * 256 + c0);
    ushort4 v10 = *(const ushort4*)(aT + (size_t)(y1 * 128 + x0) * 256 + c0);
    ushort4 v11 = *(const ushort4*)(aT + (size_t)(y1 * 128 + x1) * 256 + c0);
    ushort4 o;
    o.x = f2b(w00 * b2f(v00.x) + w01 * b2f(v01.x) + w10 * b2f(v10.x) + w11 * b2f(v11.x));
    o.y = f2b(w00 * b2f(v00.y) + w01 * b2f(v01.y) + w10 * b2f(v10.y) + w11 * b2f(v11.y));
    o.z = f2b(w00 * b2f(v00.z) + w01 * b2f(v01.z) + w10 * b2f(v10.z) + w11 * b2f(v11.z));
    o.w = f2b(w00 * b2f(v00.w) + w01 * b2f(v01.w) + w10 * b2f(v10.w) + w11 * b2f(v11.w));
    *(ushort4*)&lf[sl * LFP + c0] = o;
  }
  __syncthreads();

  int fw = wave * 64;
  floatx4 acc[4][4];
#pragma unroll
  for (int i = 0; i < 4; ++i)
#pragma unroll
    for (int jx = 0; jx < 4; ++jx) acc[i][jx] = (floatx4){0.f, 0.f, 0.f, 0.f};

  for (int kb = 0; kb < 256; kb += 32) {
    short8 aop[4], bop[4];
#pragma unroll
    for (int tf = 0; tf < 4; ++tf)
      aop[tf] = *(const short8*)(Wh + (size_t)(fw + tf * 16 + col) * 256 + kb + quad * 8);
#pragma unroll
    for (int ts = 0; ts < 4; ++ts)
      bop[ts] = *(const short8*)&lf[(ts * 16 + col) * LFP + kb + quad * 8];
#pragma unroll
    for (int ts = 0; ts < 4; ++ts)
#pragma unroll
      for (int tf = 0; tf < 4; ++tf)
        acc[ts][tf] = __builtin_amdgcn_mfma_f32_16x16x32_bf16(
            aop[tf], bop[ts], acc[ts][tf], 0, 0, 0);
  }
#pragma unroll
  for (int ts = 0; ts < 4; ++ts) {
    int s = s0 + ts * 16 + col;
    int h = s / 400;
    int w = s - h * 400;
    size_t obase = (size_t)(w * 128 + h) * 256;
#pragma unroll
    for (int tf = 0; tf < 4; ++tf) {
      int f = fw + tf * 16 + quad * 4;
      float4 bv = *(const float4*)(bias + h * 256 + f);
      ushort4 ov;
      ov.x = f2b(acc[ts][tf][0] + bv.x);
      ov.y = f2b(acc[ts][tf][1] + bv.y);
      ov.z = f2b(acc[ts][tf][2] + bv.z);
      ov.w = f2b(acc[ts][tf][3] + bv.w);
      *(ushort4*)(qh + obase + f) = ov;
    }
  }
}

// z-loop over K then V: one LDS staging pass, one acc set alive at a time
__device__ __forceinline__ void projKV_body(
    ushort* lb, int bx,
    const float* __restrict__ bsrc,
    const ushort* __restrict__ WhK, const ushort* __restrict__ WhV,
    const float* __restrict__ biasK, const float* __restrict__ biasV,
    ushort* __restrict__ kh, ushort* __restrict__ vh)
{
  int m0 = bx * 64;
  int tid = threadIdx.x;
  int lane = tid & 63;
  int wave = tid >> 6;
  int col = lane & 15, quad = lane >> 4;
  int fw = wave * 64;

  // stage: fp32 [c][m] tile -> LDS bf16 [m][c]
  int pr = (tid & 15) * 4;
  int cb = tid >> 4;               // 0..15
#pragma unroll 4
  for (int q = 0; q < 16; ++q) {
    int c = cb + q * 16;
    float4 v = *(const float4*)(bsrc + (size_t)c * MB + m0 + pr);
    lb[(pr + 0) * LFP + c] = f2b(v.x);
    lb[(pr + 1) * LFP + c] = f2b(v.y);
    lb[(pr + 2) * LFP + c] = f2b(v.z);
    lb[(pr + 3) * LFP + c] = f2b(v.w);
  }
  __syncthreads();

  for (int z = 0; z < 2; ++z) {
    const ushort* Wh = z ? WhV : WhK;
    const float* bias = z ? biasV : biasK;
    ushort* out = z ? vh : kh;
    floatx4 acc[4][4];
#pragma unroll
    for (int i = 0; i < 4; ++i)
#pragma unroll
      for (int jx = 0; jx < 4; ++jx) acc[i][jx] = (floatx4){0.f, 0.f, 0.f, 0.f};

    for (int kb = 0; kb < 256; kb += 32) {
      short8 bop[4], aop[4];
#pragma unroll
      for (int ts = 0; ts < 4; ++ts)
        bop[ts] = *(const short8*)&lb[(ts * 16 + col) * LFP + kb + quad * 8];
#pragma unroll
      for (int tf = 0; tf < 4; ++tf)
        aop[tf] = *(const short8*)(Wh + (size_t)(fw + tf * 16 + col) * 256 + kb + quad * 8);
#pragma unroll
      for (int ts = 0; ts < 4; ++ts)
#pragma unroll
        for (int tf = 0; tf < 4; ++tf)
          acc[ts][tf] = __builtin_amdgcn_mfma_f32_16x16x32_bf16(
              aop[tf], bop[ts], acc[ts][tf], 0, 0, 0);
    }
#pragma unroll
    for (int ts = 0; ts < 4; ++ts) {
      int m = m0 + ts * 16 + col;
      int h = m / 400;            // h2
      int w = m - h * 400;        // w2
      size_t obase = (size_t)(w * 64 + h) * 256;
#pragma unroll
      for (int tf = 0; tf < 4; ++tf) {
        int f = fw + tf * 16 + quad * 4;
        float4 bv = *(const float4*)(bias + h * 256 + f);
        ushort4 ov;
        ov.x = f2b(acc[ts][tf][0] + bv.x);
        ov.y = f2b(acc[ts][tf][1] + bv.y);
        ov.z = f2b(acc[ts][tf][2] + bv.z);
        ov.w = f2b(acc[ts][tf][3] + bv.w);
        *(ushort4*)(out + obase + f) = ov;
      }
    }
  }
}

__global__ __launch_bounds__(256, 3) void proj_kernel(
    const ushort* __restrict__ aT, const float* __restrict__ xarr,
    const float* __restrict__ yarr, const ushort* __restrict__ weffh,
    const float* __restrict__ qpos, ushort* __restrict__ qh,
    const float* __restrict__ bsrc,
    const float* __restrict__ kpos, const float* __restrict__ vpos,
    ushort* __restrict__ kh, ushort* __restrict__ vh)
{
  __shared__ ushort lf[64 * LFP];
  // long KV blocks first (tail-balance), then Q blocks
  if (blockIdx.x < 400)
    projKV_body(lf, blockIdx.x, bsrc, weffh + 65536, weffh + 131072,
                kpos, vpos, kh, vh);
  else
    sampleproj_body(lf, blockIdx.x - 400, aT, xarr, yarr, weffh, qpos, qh);
}

// ===================== MFMA flash attention (qt-split, vector stores) ======
#define VP 72
#define PP 72
__global__ __launch_bounds__(256) void attn_mfma_kernel(
    const ushort* __restrict__ qh, const ushort* __restrict__ kh,
    const ushort* __restrict__ vh, ushort* __restrict__ obuf)
{
  __shared__ ushort lV[4][32 * VP];
  __shared__ ushort lP[4][16 * PP];
  int b = blockIdx.x;
  int hg = blockIdx.y & 1;          // head group
  int qb = blockIdx.y >> 1;         // qt half
  int wave = threadIdx.x >> 6;
  int lane = threadIdx.x & 63;
  int head = hg * 4 + wave;
  int col = lane & 15, quad = lane >> 4;
  ushort* Vw = lV[wave];
  ushort* Pw = lP[wave];

  // K fragments direct from global (qt-invariant)
  short8 bk0 = *(const short8*)(kh + ((size_t)(b * 64 +  0 + col)) * 256 + head * 32 + quad * 8);
  short8 bk1 = *(const short8*)(kh + ((size_t)(b * 64 + 16 + col)) * 256 + head * 32 + quad * 8);
  short8 bk2 = *(const short8*)(kh + ((size_t)(b * 64 + 32 + col)) * 256 + head * 32 + quad * 8);
  short8 bk3 = *(const short8*)(kh + ((size_t)(b * 64 + 48 + col)) * 256 + head * 32 + quad * 8);

  // V staged to LDS (d-major transpose), then hoist the 4 qt-invariant fragments
  {
    const ushort* vsrc = vh + ((size_t)(b * 64 + lane)) * 256 + head * 32;
    ushort vr[32];
    *(uint4*)(vr) = *(const uint4*)(vsrc);
    *(uint4*)(vr + 8) = *(const uint4*)(vsrc + 8);
    *(uint4*)(vr + 16) = *(const uint4*)(vsrc + 16);
    *(uint4*)(vr + 24) = *(const uint4*)(vsrc + 24);
#pragma unroll
    for (int d = 0; d < 32; ++d) Vw[d * VP + lane] = vr[d];
  }
  short8 vA0 = *(const short8*)(Vw + (col) * VP + 0 * 32 + quad * 8);
  short8 vB0 = *(const short8*)(Vw + (16 + col) * VP + 0 * 32 + quad * 8);
  short8 vA1 = *(const short8*)(Vw + (col) * VP + 1 * 32 + quad * 8);
  short8 vB1 = *(const short8*)(Vw + (16 + col) * VP + 1 * 32 + quad * 8);

  const float scl = 0.17677669529663687f;   // 1/sqrt(32)
  for (int qt = qb * 4; qt < qb * 4 + 4; ++qt) {
    short8 aq = *(const short8*)(qh +
        ((size_t)(b * 128 + qt * 16 + col)) * 256 + head * 32 + quad * 8);
    floatx4 s0 = {0.f,0.f,0.f,0.f}, s1 = s0, s2 = s0, s3 = s0;
    s0 = __builtin_amdgcn_mfma_f32_16x16x32_bf16(aq, bk0, s0, 0, 0, 0);
    s1 = __builtin_amdgcn_mfma_f32_16x16x32_bf16(aq, bk1, s1, 0, 0, 0);
    s2 = __builtin_amdgcn_mfma_f32_16x16x32_bf16(aq, bk2, s2, 0, 0, 0);
    s3 = __builtin_amdgcn_mfma_f32_16x16x32_bf16(aq, bk3, s3, 0, 0, 0);
    float e[4][4], mr[4], sm[4];
#pragma unroll
    for (int r = 0; r < 4; ++r) {
      float v0 = s0[r] * scl, v1 = s1[r] * scl;
      float v2 = s2[r] * scl, v3 = s3[r] * scl;
      e[0][r] = v0; e[1][r] = v1; e[2][r] = v2; e[3][r] = v3;
      mr[r] = fmaxf(fmaxf(v0, v1), fmaxf(v2, v3));
    }
#pragma unroll
    for (int mask = 1; mask <= 8; mask <<= 1)
#pragma unroll
      for (int r = 0; r < 4; ++r)
        mr[r] = fmaxf(mr[r], __shfl_xor(mr[r], mask, 64));
#pragma unroll
    for (int r = 0; r < 4; ++r) {
      float acc = 0.f;
#pragma unroll
      for (int t = 0; t < 4; ++t) {
        float ev = __expf(e[t][r] - mr[r]);
        e[t][r] = ev;
        acc += ev;
      }
      sm[r] = acc;
    }
#pragma unroll
    for (int mask = 1; mask <= 8; mask <<= 1)
#pragma unroll
      for (int r = 0; r < 4; ++r)
        sm[r] += __shfl_xor(sm[r], mask, 64);
#pragma unroll
    for (int t = 0; t < 4; ++t)
#pragma unroll
      for (int r = 0; r < 4; ++r)
        Pw[(quad * 4 + r) * PP + t * 16 + col] = f2b(e[t][r]);
    // per-wave in-order DS pipe: reads below see the writes above
    floatx4 o0 = {0.f,0.f,0.f,0.f}, o1 = o0;
    {
      short8 ap0 = *(const short8*)(Pw + col * PP + 0 * 32 + quad * 8);
      o0 = __builtin_amdgcn_mfma_f32_16x16x32_bf16(ap0, vA0, o0, 0, 0, 0);
      o1 = __builtin_amdgcn_mfma_f32_16x16x32_bf16(ap0, vB0, o1, 0, 0, 0);
      short8 ap1 = *(const short8*)(Pw + col * PP + 1 * 32 + quad * 8);
      o0 = __builtin_amdgcn_mfma_f32_16x16x32_bf16(ap1, vA1, o0, 0, 0, 0);
      o1 = __builtin_amdgcn_mfma_f32_16x16x32_bf16(ap1, vB1, o1, 0, 0, 0);
    }
    // repack O through Pw (P already consumed), one 16B store per lane
#pragma unroll
    for (int r = 0; r < 4; ++r) {
      float iv = 1.0f / sm[r];
      Pw[(quad * 4 + r) * PP + col] = f2b(o0[r] * iv);
      Pw[(quad * 4 + r) * PP + 16 + col] = f2b(o1[r] * iv);
    }
    int orow = lane >> 2, ochunk = lane & 3;
    uint4 ov = *(const uint4*)(Pw + orow * PP + ochunk * 8);
    *(uint4*)(obuf + (size_t)(b * 128 + qt * 16 + orow) * 256 + head * 32 + ochunk * 8) = ov;
  }
}

// ===================== merged positional GEMMs (z = q/k/v) =================
__global__ __launch_bounds__(256) void gemmN3_kernel(
    const float* __restrict__ pos_a, const float* __restrict__ pos_b,
    const float* __restrict__ weff, const float* __restrict__ beff,
    float* __restrict__ qpos, float* __restrict__ kpos, float* __restrict__ vpos)
{
  int z = blockIdx.z;
  if (z > 0 && blockIdx.x > 0) return;
  const float* A = (z == 0) ? pos_a : pos_b;
  const float* Wt = weff + (size_t)z * 65536;
  const float* biasf = beff + z * 256;
  float* Cout = (z == 0) ? qpos : ((z == 1) ? kpos : vpos);
  __shared__ float As[64][17];
  __shared__ float Ws[16][65];
  int m0 = blockIdx.x * 64;
  int n0 = blockIdx.y * 64;
  int tid = threadIdx.x;
  int tx = tid & 15, ty = tid >> 4;
  float acc[4][4] = {};
  for (int k0 = 0; k0 < 256; k0 += 16) {
    {
      int m = tid >> 2;
      int kq = (tid & 3) << 2;
      float4 v = *(const float4*)(A + (size_t)(m0 + m) * 256 + k0 + kq);
      As[m][kq + 0] = v.x; As[m][kq + 1] = v.y;
      As[m][kq + 2] = v.z; As[m][kq + 3] = v.w;
    }
    {
      int f = tid >> 2;
      int kq = (tid & 3) << 2;
      float4 v = *(const float4*)(Wt + (size_t)(n0 + f) * 256 + k0 + kq);
      Ws[kq + 0][f] = v.x; Ws[kq + 1][f] = v.y;
      Ws[kq + 2][f] = v.z; Ws[kq + 3][f] = v.w;
    }
    __syncthreads();
#pragma unroll
    for (int kk = 0; kk < 16; ++kk) {
      float a[4], b[4];
#pragma unroll
      for (int i = 0; i < 4; ++i) a[i] = As[ty * 4 + i][kk];
#pragma unroll
      for (int jj = 0; jj < 4; ++jj) b[jj] = Ws[kk][tx * 4 + jj];
#pragma unroll
      for (int i = 0; i < 4; ++i)
#pragma unroll
        for (int jj = 0; jj < 4; ++jj) acc[i][jj] += a[i] * b[jj];
    }
    __syncthreads();
  }
#pragma unroll
  for (int i = 0; i < 4; ++i) {
    int m = m0 + ty * 4 + i;
    int f = n0 + tx * 4;
    float4 bv = *(const float4*)(biasf + f);
    float4 ov;
    ov.x = acc[i][0] + bv.x; ov.y = acc[i][1] + bv.y;
    ov.z = acc[i][2] + bv.z; ov.w = acc[i][3] + bv.w;
    *(float4*)(Cout + (size_t)m * 256 + f) = ov;
  }
}

// ===================== GEMM A[m][k] * B[k][n] + bf16 copy ==================
__global__ __launch_bounds__(256) void gemm_ab_kernel(
    const float* __restrict__ in_w, const float* __restrict__ Wq,
    const float* __restrict__ Wk, const float* __restrict__ Wv,
    float* __restrict__ weff, ushort* __restrict__ weffh)
{
  int z = blockIdx.z;
  const float* A = in_w + (size_t)z * 65536;
  const float* B = (z == 0) ? Wq : ((z == 1) ? Wk : Wv);
  float* C = weff + (size_t)z * 65536;
  ushort* Ch = weffh + (size_t)z * 65536;
  __shared__ float As[64][17];
  __shared__ float Bs[16][64];
  int m0 = blockIdx.x * 64;
  int n0 = blockIdx.y * 64;
  int tid = threadIdx.x;
  int tx = tid & 15, ty = tid >> 4;
  float acc[4][4] = {};
  for (int k0 = 0; k0 < 256; k0 += 16) {
    {
      int m = tid >> 2;
      int kq = (tid & 3) << 2;
      float4 v = *(const float4*)(A + (size_t)(m0 + m) * 256 + k0 + kq);
      As[m][kq + 0] = v.x; As[m][kq + 1] = v.y;
      As[m][kq + 2] = v.z; As[m][kq + 3] = v.w;
    }
    {
      int k = tid >> 4;
      int nq = (tid & 15) << 2;
      float4 v = *(const float4*)(B + (size_t)(k0 + k) * 256 + n0 + nq);
      *(float4*)(&Bs[k][nq]) = v;
    }
    __syncthreads();
#pragma unroll
    for (int kk = 0; kk < 16; ++kk) {
      float a[4], b[4];
#pragma unroll
      for (int i = 0; i < 4; ++i) a[i] = As[ty * 4 + i][kk];
#pragma unroll
      for (int jj = 0; jj < 4; ++jj) b[jj] = Bs[kk][tx * 4 + jj];
#pragma unroll
      for (int i = 0; i < 4; ++i)
#pragma unroll
        for (int jj = 0; jj < 4; ++jj) acc[i][jj] += a[i] * b[jj];
    }
    __syncthreads();
  }
#pragma unroll
  for (int i = 0; i < 4; ++i) {
    int m = m0 + ty * 4 + i;
    *(float4*)(C + (size_t)m * 256 + n0 + tx * 4) = *(float4*)&acc[i][0];
    ushort4 hv;
    hv.x = f2b(acc[i][0]); hv.y = f2b(acc[i][1]);
    hv.z = f2b(acc[i][2]); hv.w = f2b(acc[i][3]);
    *(ushort4*)(Ch + (size_t)m * 256 + n0 + tx * 4) = hv;
  }
}

// ===================== segmented reduction over sorted samples =============
#define CH 64
__global__ __launch_bounds__(256) void segred_kernel(
    const ushort* __restrict__ obuf, const int* __restrict__ order,
    const int* __restrict__ pixs, float* __restrict__ osum)
{
  __shared__ int lm[CH];
  __shared__ int lp[CH + 2];
  int s0 = blockIdx.x * CH;
  int t = threadIdx.x;
  if (t < CH) {
    lm[t] = order[s0 + t];
    lp[t + 1] = pixs[s0 + t];
  } else if (t == CH) {
    lp[0] = (s0 > 0) ? pixs[s0 - 1] : -1;
  } else if (t == CH + 1) {
    lp[CH + 1] = (s0 + CH < MS) ? pixs[s0 + CH] : -2;
  }
  __syncthreads();
  int c = t;
  float va[8];
#pragma unroll
  for (int k = 0; k < 8; ++k)
    va[k] = b2f(obuf[(size_t)lm[k] * 256 + c]);
  float acc = 0.0f;
  int runBegin = 0;
#pragma unroll
  for (int i = 0; i < CH; ++i) {
    float v = va[i & 7];
    if (i + 8 < CH) va[i & 7] = b2f(obuf[(size_t)lm[i + 8] * 256 + c]);
    acc += v;
    int p = lp[i + 1];
    bool last = (i == CH - 1);
    if (last || p != lp[i + 2]) {
      bool pBeg = (runBegin == 0) && (p == lp[0]);
      bool pEnd = last && (p == lp[CH + 1]);
      float* dst = osum + (size_t)p * 256 + c;
      if (pBeg || pEnd) atomicAdd(dst, acc);
      else *dst = acc;
      acc = 0.0f;
      runBegin = i + 1;
    }
  }
}

// ===================== fused out-proj + residual update (+aT emit) =========
__global__ __launch_bounds__(256) void outproj_update_kernel(
    const float* __restrict__ osum, const ushort* __restrict__ out_wh,
    const float* __restrict__ asrc, float* __restrict__ adst,
    const float* __restrict__ cnt, const float* __restrict__ out_b,
    float scale, ushort* __restrict__ aTout, int writeAT)
{
  int p0 = blockIdx.x * 32;
  int lane = threadIdx.x & 63;
  int wave = threadIdx.x >> 6;
  int col = lane & 15, quad = lane >> 4;
  int fw = wave * 64;
  floatx4 acc[2][4];
#pragma unroll
  for (int i = 0; i < 2; ++i)
#pragma unroll
    for (int jx = 0; jx < 4; ++jx) acc[i][jx] = (floatx4){0.f, 0.f, 0.f, 0.f};

  for (int kb = 0; kb < 256; kb += 32) {
    short8 aop[4], bop[2];
#pragma unroll
    for (int tf = 0; tf < 4; ++tf)
      aop[tf] = *(const short8*)(out_wh +
          (size_t)(fw + tf * 16 + col) * 256 + kb + quad * 8);
#pragma unroll
    for (int ts = 0; ts < 2; ++ts) {
      const float* brow = osum + (size_t)(p0 + ts * 16 + col) * 256 + kb + quad * 8;
      float4 f0 = *(const float4*)brow;
      float4 f1 = *(const float4*)(brow + 4);
      short8 bv;
      bv[0] = (short)f2b(f0.x); bv[1] = (short)f2b(f0.y);
      bv[2] = (short)f2b(f0.z); bv[3] = (short)f2b(f0.w);
      bv[4] = (short)f2b(f1.x); bv[5] = (short)f2b(f1.y);
      bv[6] = (short)f2b(f1.z); bv[7] = (short)f2b(f1.w);
      bop[ts] = bv;
    }
#pragma unroll
    for (int ts = 0; ts < 2; ++ts)
#pragma unroll
      for (int tf = 0; tf < 4; ++tf)
        acc[ts][tf] = __builtin_amdgcn_mfma_f32_16x16x32_bf16(
            aop[tf], bop[ts], acc[ts][tf], 0, 0, 0);
  }
  // epilogue: acc[ts][tf][r] = enh(f=fw+tf*16+quad*4+r, p=p0+ts*16+col)
#pragma unroll
  for (int ts = 0; ts < 2; ++ts) {
    int p = p0 + ts * 16 + col;
    float cn = cnt[p];
    float rs = scale / fmaxf(cn, 1.0f);
#pragma unroll
    for (int tf = 0; tf < 4; ++tf) {
      int f = fw + tf * 16 + quad * 4;
      float4 ob = *(const float4*)(out_b + f);
      float r0 = asrc[(size_t)(f + 0) * PIX + p] + (acc[ts][tf][0] + cn * ob.x) * rs;
      float r1 = asrc[(size_t)(f + 1) * PIX + p] + (acc[ts][tf][1] + cn * ob.y) * rs;
      float r2 = asrc[(size_t)(f + 2) * PIX + p] + (acc[ts][tf][2] + cn * ob.z) * rs;
      float r3 = asrc[(size_t)(f + 3) * PIX + p] + (acc[ts][tf][3] + cn * ob.w) * rs;
      adst[(size_t)(f + 0) * PIX + p] = r0;
      adst[(size_t)(f + 1) * PIX + p] = r1;
      adst[(size_t)(f + 2) * PIX + p] = r2;
      adst[(size_t)(f + 3) * PIX + p] = r3;
      if (writeAT) {
        ushort4 hv;
        hv.x = f2b(r0); hv.y = f2b(r1); hv.z = f2b(r2); hv.w = f2b(r3);
        *(ushort4*)(aTout + (size_t)p * 256 + f) = hv;
      }
    }
  }
}

// ===================== launch =====================
extern "C" void kernel_launch(void* const* d_in, const int* in_sizes, int n_in,
                              void* d_out, int out_size, void* d_ws, size_t ws_size,
                              hipStream_t stream) {
  const float* list_a = (const float*)d_in[0];
  const float* list_b = (const float*)d_in[1];
  const float* rots   = (const float*)d_in[3];
  const float* fxs    = (const float*)d_in[5];
  const float* cxs    = (const float*)d_in[6];
  const float* pos_a  = (const float*)d_in[7];
  const float* pos_b  = (const float*)d_in[8];
  const float* Wq     = (const float*)d_in[9];
  const float* bq     = (const float*)d_in[10];
  const float* Wk     = (const float*)d_in[11];
  const float* bk     = (const float*)d_in[12];
  const float* Wv     = (const float*)d_in[13];
  const float* bv     = (const float*)d_in[14];
  const float* in_w   = (const float*)d_in[15];
  const float* in_b   = (const float*)d_in[16];
  const float* out_w  = (const float*)d_in[17];
  const float* out_b  = (const float*)d_in[18];

  float* ws      = (float*)d_ws;
  float* weff    = ws;                          // 196608 f
  float* beff    = weff + 196608;               // 768 f
  float* qpos    = beff + 768;                  // 32768 f
  float* kpos    = qpos + 32768;                // 16384 f
  float* vpos    = kpos + 16384;                // 16384 f
  float* a_cur   = vpos + 16384;                // 4194304 f
  float* xarr    = a_cur + 4194304;             // 2*51200 f
  float* yarr    = xarr + 102400;               // 2*51200 f
  int*   idxarr  = (int*)(yarr + 102400);       // 2*51200
  int*   offs    = idxarr + 102400;             // 2*16384
  int*   order   = offs + 32768;                // 2*51200
  int*   pixs    = order + 102400;              // 2*51200
  float* cnt     = (float*)(pixs + 102400);     // 2*16384 f   <- zero region A
  int*   cursor  = (int*)(cnt + 32768);         // 2*16384     <- zero region A
  float* osum    = (float*)(cursor + 32768);    // 4194304 f   <- zero region B
  ushort* weffh  = (ushort*)(osum + 4194304);   // 196608 h
  ushort* out_wh = weffh + 196608;              // 65536 h
  ushort* obufh  = out_wh + 65536;              // 13107200 h
  ushort* qh     = obufh + 13107200;            // 13107200 h
  ushort* kh     = qh + 13107200;               // 6553600 h
  ushort* vh     = kh + 6553600;                // 6553600 h
  ushort* aT     = vh + 6553600;                // 4194304 h

  // prologue: weights, biases, positional tables, both cams' index prep
  gemm_ab_kernel<<<dim3(4, 4, 3), 256, 0, stream>>>(in_w, Wq, Wk, Wv, weff, weffh);
  misc_kernel<<<67, 256, 0, stream>>>(out_w, out_wh, in_w, in_b, bq, bk, bv, beff);
  gemmN3_kernel<<<dim3(2, 4, 3), 256, 0, stream>>>(pos_a, pos_b, weff, beff,
                                                   qpos, kpos, vpos);
  hipMemsetAsync(cnt, 0, (size_t)(32768 + 32768) * sizeof(float), stream); // cnt+cursor both cams
  coords_kernel<<<dim3(200, 2), 256, 0, stream>>>(rots, fxs, cxs, xarr, yarr, idxarr, cnt);
  prefix_kernel<<<2, 256, 0, stream>>>(cnt, offs);
  fill_kernel<<<dim3(200, 2), 256, 0, stream>>>(idxarr, offs, cursor, order, pixs);

  for (int jj = 0; jj < 2; ++jj) {
    int j = jj ? 3 : 0;
    const float* asrc = jj ? a_cur : list_a;
    hipMemsetAsync(osum, 0, (size_t)4194304 * sizeof(float), stream);
    if (jj == 0)
      transpose_kernel<<<dim3(256, 4), 256, 0, stream>>>(list_a, aT);
    // merged K/V-proj (first, long) + Q-proj (bilinear sample), one dispatch
    proj_kernel<<<1200, 256, 0, stream>>>(aT, xarr + jj * MS, yarr + jj * MS,
                                          weffh, qpos, qh,
                                          list_b + (size_t)j * 6553600,
                                          kpos, vpos, kh, vh);
    // MFMA flash attention (qt-split, vectorized stores)
    attn_mfma_kernel<<<dim3(400, 4), 256, 0, stream>>>(qh, kh, vh, obufh);
    // segmented reduction of O over sorted samples -> osum fp32
    segred_kernel<<<800, 256, 0, stream>>>(obufh, order + jj * MS, pixs + jj * MS, osum);
    // fused out-proj + residual update (+ emit next iter's aT)
    outproj_update_kernel<<<512, 256, 0, stream>>>(osum, out_wh, asrc,
                                                   jj ? (float*)d_out : a_cur,
                                                   cnt + jj * PIX, out_b,
                                                   jj ? 2.0f : 1.0f,
                                                   aT, jj == 0 ? 1 : 0);
  }
}